// Round 3
// baseline (1819.910 us; speedup 1.0000x reference)
//
#include <hip/hip_runtime.h>
#include <hip/hip_bf16.h>
#include <math.h>

// ---------------------------------------------------------------------------
// IMPGNN on MI355X. fp32 accumulate; bf16 storage for streamed/gathered
// intermediates. Tol = 2% of output absmax (measured margin ~7x).
// R10 vs R9:
//   - k_fill_part: edge-list reads are now NON-TEMPORAL
//     (__builtin_nontemporal_load). R9 kept WRITE_SIZE at 209MB because the
//     8x streaming rescans of the 12.8MB edge list evicted the dirty
//     scatter lines from the 4MB per-XCD L2 before they filled. nt reads
//     allocate at lowest LRU priority -> the ~3.2MB per-range scatter
//     slice stays L2-resident and lines accumulate ~8-16 writes before a
//     single writeback. Same for node fill + k_count.
// ---------------------------------------------------------------------------

#define POOL_BLOCKS 400
#define SCAN_NB 256
#define ELL_CAP 64
#define PR_ITERS 48   // even: result ends in c_a
#define EF_BLOCKS 2048
#define FILL_NR 8     // ranges (XCD-affine)

typedef unsigned short ushort_t;
typedef unsigned int uint_t;

__device__ __forceinline__ float eluf(float x) { return x > 0.f ? x : expm1f(x); }
__device__ __forceinline__ float eluf_fast(float x) { return x > 0.f ? x : __expf(x) - 1.f; }
__device__ __forceinline__ float bf2f(ushort_t v) {
    return __uint_as_float(((unsigned int)v) << 16);
}
__device__ __forceinline__ ushort_t f2bf(float f) {
    unsigned int u = __float_as_uint(f);
    unsigned int lsb = (u >> 16) & 1u;
    u += 0x7fffu + lsb;           // round-to-nearest-even
    return (ushort_t)(u >> 16);
}
__device__ __forceinline__ float bflo(uint_t v) { return __uint_as_float(v << 16); }
__device__ __forceinline__ float bfhi(uint_t v) { return __uint_as_float(v & 0xffff0000u); }
__device__ __forceinline__ uint_t packbf(float a, float b) {
    return (uint_t)f2bf(a) | ((uint_t)f2bf(b) << 16);
}

// ---------------- CSR build ----------------
__global__ void k_count(const int* __restrict__ a, const int* __restrict__ b,
                        int E, int* __restrict__ deg) {
    int e = blockIdx.x * blockDim.x + threadIdx.x;
    if (e < E) {
        int s = __builtin_nontemporal_load(a + e);
        int d = __builtin_nontemporal_load(b + e);
        atomicAdd(&deg[s], 1); atomicAdd(&deg[d], 1);
    }
}

__global__ void k_scan1(const int* __restrict__ deg, int n, int C, int* __restrict__ bsum) {
    __shared__ int red[256];
    int b = blockIdx.x, tid = threadIdx.x;
    int base = b * C, end = min(base + C, n);
    int s = 0;
    for (int i = base + tid; i < end; i += 256) s += deg[i];
    red[tid] = s;
    __syncthreads();
    for (int off = 128; off > 0; off >>= 1) {
        if (tid < off) red[tid] += red[tid + off];
        __syncthreads();
    }
    if (tid == 0) bsum[b] = red[0];
}

__global__ void k_scan2(int* __restrict__ bsum, int NB, int* __restrict__ total_out) {
    __shared__ int s[256];
    int tid = threadIdx.x;
    int v = (tid < NB) ? bsum[tid] : 0;
    s[tid] = v;
    __syncthreads();
    for (int off = 1; off < 256; off <<= 1) {
        int w = (tid >= off) ? s[tid - off] : 0;
        __syncthreads();
        s[tid] += w;
        __syncthreads();
    }
    if (tid < NB) bsum[tid] = s[tid] - v;
    if (tid == 255) *total_out = s[255];
}

__global__ void k_scan3(const int* __restrict__ deg, const int* __restrict__ boff,
                        int n, int C, int* __restrict__ ptr, int* __restrict__ cur) {
    __shared__ int s[256];
    __shared__ int carry;
    int b = blockIdx.x, tid = threadIdx.x;
    int base = b * C, end = min(base + C, n);
    if (tid == 0) carry = boff[b];
    __syncthreads();
    for (int t = base; t < end; t += 256) {
        int i = t + tid;
        int v = (i < end) ? deg[i] : 0;
        s[tid] = v;
        __syncthreads();
        for (int off = 1; off < 256; off <<= 1) {
            int w = (tid >= off) ? s[tid - off] : 0;
            __syncthreads();
            s[tid] += w;
            __syncthreads();
        }
        int p = carry + s[tid] - v;
        if (i < end) { ptr[i] = p; cur[i] = p; }
        __syncthreads();
        if (tid == 0) carry += s[255];
        __syncthreads();
    }
}

// Range-partitioned CSR fill. Block b: range r = b & 7 (XCD-affine under
// round-robin dispatch), edge chunk = b >> 3. Only endpoints with
// node-id in [r*rngsize, (r+1)*rngsize) are inserted by this block, so
// each range's scattered stores stay in a small L2-hot slice of nbr/eid.
// Edge-list reads are non-temporal so the streaming rescans do not evict
// the dirty scatter lines from L2 (R10: this was the 16x write amp).
template <int WITH_EID>
__global__ void k_fill_part(const int* __restrict__ a, const int* __restrict__ b,
                            int E, int* __restrict__ cur, int* __restrict__ nbr,
                            int* __restrict__ eid, int rngsize, int nchunk) {
    int r = blockIdx.x & (FILL_NR - 1);
    int chunk = blockIdx.x >> 3;
    int lo = r * rngsize, hi = lo + rngsize;
    int per = (E + nchunk - 1) / nchunk;
    int e0 = chunk * per;
    int e1 = min(e0 + per, E);
    for (int e = e0 + threadIdx.x; e < e1; e += blockDim.x) {
        int s = __builtin_nontemporal_load(a + e);
        int d = __builtin_nontemporal_load(b + e);
        if (s >= lo && s < hi) {
            int p = atomicAdd(&cur[s], 1);
            nbr[p] = d;
            if (WITH_EID) eid[p] = e;
        }
        if (d >= lo && d < hi) {
            int p = atomicAdd(&cur[d], 1);
            nbr[p] = s;
            if (WITH_EID) eid[p] = e;
        }
    }
}

// ---------------- encoders (bf16 out) ----------------
__global__ void k_encoder(const int* __restrict__ x, const float* __restrict__ metafeat,
                          const float* __restrict__ atom_emb, const float* __restrict__ meta_W,
                          const float* __restrict__ meta_b, uint_t* __restrict__ nf0,
                          uint_t* __restrict__ mf0, int N) {
    __shared__ float W[16 * 128];
    __shared__ float bsh[128];
    for (int i = threadIdx.x; i < 16 * 128; i += blockDim.x) W[i] = meta_W[i];
    if (threadIdx.x < 128) bsh[threadIdx.x] = meta_b[threadIdx.x];
    __syncthreads();
    int idx = blockIdx.x * blockDim.x + threadIdx.x;
    if (idx < N * 64) {
        int i = idx >> 6, j2 = idx & 63;
        float2 av = *reinterpret_cast<const float2*>(atom_emb + (size_t)x[i] * 128 + j2 * 2);
        nf0[idx] = packbf(av.x, av.y);
        const float* mrow = metafeat + (size_t)i * 16;
        float a0 = bsh[j2 * 2], a1 = bsh[j2 * 2 + 1];
#pragma unroll
        for (int k = 0; k < 16; k++) {
            float m = mrow[k];
            a0 = fmaf(m, W[k * 128 + j2 * 2], a0);
            a1 = fmaf(m, W[k * 128 + j2 * 2 + 1], a1);
        }
        mf0[idx] = packbf(a0, a1);
    }
}

__global__ void k_gate_node(const int* __restrict__ ptr, const int* __restrict__ eid_arr,
                            const int* __restrict__ edge_attr, const float* __restrict__ bond_emb,
                            uint_t* __restrict__ gate, int N) {
    __shared__ float bond[8 * 128];
    for (int i = threadIdx.x; i < 8 * 128; i += blockDim.x) bond[i] = bond_emb[i];
    __syncthreads();
    int l = threadIdx.x & 63, li = threadIdx.x >> 6;
    int node = blockIdx.x * 4 + li;
    if (node >= N) return;
    int p0 = ptr[node], p1 = ptr[node + 1];
    float g0 = 0.f, g1 = 0.f;
    for (int p = p0; p < p1; p++) {
        int a = edge_attr[eid_arr[p]];
        float2 bv = *reinterpret_cast<const float2*>(&bond[a * 128 + l * 2]);
        g0 += bv.x; g1 += bv.y;
    }
    gate[(size_t)node * 64 + l] = packbf(g0, g1);
}

// ---------------- GEMM ----------------
// GATED: A = elu(X*G). IBF16: X packed bf16 pitch 64 (G always bf16 pitch 64).
// EPI 0: out = rsqrt(deg+1)*acc   EPI 1: out = acc + deg*bias
// OBF16: bf16 out. OILV: interleaved m01 layout (pitch 128 uints, slot offset
// baked into out pointer; lane writes uint2 at r*128 + tx*4 and +64).
template <int GATED, int EPI, int IBF16, int OBF16, int OILV>
__global__ __launch_bounds__(256, 4) void k_gemm(
    const void* __restrict__ Xv, const void* __restrict__ Gv,
    const float* __restrict__ W, const float* __restrict__ bias,
    const int* __restrict__ deg, void* __restrict__ outv, int M) {
    __shared__ float As[128][33];
    __shared__ float Bs[32][128];
    int tid = threadIdx.x;
    int tx = tid & 15, ty = tid >> 4;
    int row0 = blockIdx.x * 128;

    float acc[8][8];
#pragma unroll
    for (int i = 0; i < 8; i++)
#pragma unroll
        for (int j = 0; j < 8; j++) acc[i][j] = 0.f;

    for (int h = 0; h < 4; h++) {
#pragma unroll
        for (int p = 0; p < 4; p++) {
            int idx = p * 256 + tid;
            int kk = idx >> 5, cg = idx & 31;
            float4 w = *reinterpret_cast<const float4*>(W + (h * 32 + kk) * 128 + cg * 4);
            *reinterpret_cast<float4*>(&Bs[kk][cg * 4]) = w;
        }
        int kg = tid & 7, rr = tid >> 3;
#pragma unroll
        for (int p = 0; p < 4; p++) {
            int r = p * 32 + rr;
            int grow = row0 + r;
            float4 av;
            if (grow < M) {
                float x0, x1, x2, x3;
                if (IBF16) {
                    const uint_t* Xb = (const uint_t*)Xv;
                    uint2 xu = *reinterpret_cast<const uint2*>(
                        Xb + (size_t)grow * 64 + h * 16 + kg * 2);
                    x0 = bflo(xu.x); x1 = bfhi(xu.x); x2 = bflo(xu.y); x3 = bfhi(xu.y);
                } else {
                    const float* Xf = (const float*)Xv;
                    float4 xv = *reinterpret_cast<const float4*>(
                        Xf + (size_t)grow * 128 + h * 32 + kg * 4);
                    x0 = xv.x; x1 = xv.y; x2 = xv.z; x3 = xv.w;
                }
                if (GATED) {
                    const uint_t* Gb = (const uint_t*)Gv;
                    uint2 gu = *reinterpret_cast<const uint2*>(
                        Gb + (size_t)grow * 64 + h * 16 + kg * 2);
                    av.x = eluf(x0 * bflo(gu.x)); av.y = eluf(x1 * bfhi(gu.x));
                    av.z = eluf(x2 * bflo(gu.y)); av.w = eluf(x3 * bfhi(gu.y));
                } else {
                    av = make_float4(x0, x1, x2, x3);
                }
            } else av = make_float4(0.f, 0.f, 0.f, 0.f);
            As[r][kg * 4 + 0] = av.x; As[r][kg * 4 + 1] = av.y;
            As[r][kg * 4 + 2] = av.z; As[r][kg * 4 + 3] = av.w;
        }
        __syncthreads();
#pragma unroll 8
        for (int k = 0; k < 32; k++) {
            float a[8], b[8];
#pragma unroll
            for (int i = 0; i < 8; i++) a[i] = As[ty * 8 + i][k];
            float4 b0 = *reinterpret_cast<const float4*>(&Bs[k][tx * 4]);
            float4 b1 = *reinterpret_cast<const float4*>(&Bs[k][64 + tx * 4]);
            b[0] = b0.x; b[1] = b0.y; b[2] = b0.z; b[3] = b0.w;
            b[4] = b1.x; b[5] = b1.y; b[6] = b1.z; b[7] = b1.w;
#pragma unroll
            for (int i = 0; i < 8; i++)
#pragma unroll
                for (int j = 0; j < 8; j++) acc[i][j] = fmaf(a[i], b[j], acc[i][j]);
        }
        __syncthreads();
    }
#pragma unroll
    for (int i = 0; i < 8; i++) {
        int r = row0 + ty * 8 + i;
        if (r < M) {
            float o[8];
            if (EPI == 0) {
                float sc = rsqrtf((float)deg[r] + 1.0f);
#pragma unroll
                for (int j = 0; j < 8; j++) o[j] = acc[i][j] * sc;
            } else {
                float dg = (float)deg[r];
                float4 ba = *reinterpret_cast<const float4*>(bias + tx * 4);
                float4 bb = *reinterpret_cast<const float4*>(bias + 64 + tx * 4);
                o[0] = acc[i][0] + dg * ba.x; o[1] = acc[i][1] + dg * ba.y;
                o[2] = acc[i][2] + dg * ba.z; o[3] = acc[i][3] + dg * ba.w;
                o[4] = acc[i][4] + dg * bb.x; o[5] = acc[i][5] + dg * bb.y;
                o[6] = acc[i][6] + dg * bb.z; o[7] = acc[i][7] + dg * bb.w;
            }
            if (OBF16) {
                uint_t* ob = (uint_t*)outv;
                uint2 q0, q1;
                q0.x = packbf(o[0], o[1]); q0.y = packbf(o[2], o[3]);
                q1.x = packbf(o[4], o[5]); q1.y = packbf(o[6], o[7]);
                if (OILV) {
                    *reinterpret_cast<uint2*>(ob + (size_t)r * 128 + tx * 4) = q0;
                    *reinterpret_cast<uint2*>(ob + (size_t)r * 128 + 64 + tx * 4) = q1;
                } else {
                    *reinterpret_cast<uint2*>(ob + (size_t)r * 64 + tx * 2) = q0;
                    *reinterpret_cast<uint2*>(ob + (size_t)r * 64 + 32 + tx * 2) = q1;
                }
            } else {
                float* out = (float*)outv;
                *reinterpret_cast<float4*>(out + (size_t)r * 128 + tx * 4) =
                    make_float4(o[0], o[1], o[2], o[3]);
                *reinterpret_cast<float4*>(out + (size_t)r * 128 + 64 + tx * 4) =
                    make_float4(o[4], o[5], o[6], o[7]);
            }
        }
    }
}

// ---------------- node aggregations on interleaved m01 ----------------
// m01 layout: uint4 at [node*128 + c*4]: .xy = m0 dims 4c..4c+3, .zw = m1 same.
__global__ void k_agg_dual(const int* __restrict__ ptr, const int* __restrict__ nbr,
                           const uint_t* __restrict__ m01,
                           const float* __restrict__ b0, const float* __restrict__ b1,
                           const int* __restrict__ deg, uint_t* __restrict__ h0,
                           uint_t* __restrict__ h1, int n) {
    int c = threadIdx.x & 31, li = threadIdx.x >> 5;
    int node = blockIdx.x * 8 + li;
    if (node >= n) return;
    int p0 = ptr[node], p1 = ptr[node + 1];
    uint4 s = *reinterpret_cast<const uint4*>(m01 + (size_t)node * 128 + c * 4);
    float a00 = bflo(s.x), a01 = bfhi(s.x), a02 = bflo(s.y), a03 = bfhi(s.y);
    float a10 = bflo(s.z), a11 = bfhi(s.z), a12 = bflo(s.w), a13 = bfhi(s.w);
    int p = p0;
    for (; p + 4 <= p1; p += 4) {
        int i0 = nbr[p], i1 = nbr[p + 1], i2 = nbr[p + 2], i3 = nbr[p + 3];
        uint4 v0 = *reinterpret_cast<const uint4*>(m01 + (size_t)i0 * 128 + c * 4);
        uint4 v1 = *reinterpret_cast<const uint4*>(m01 + (size_t)i1 * 128 + c * 4);
        uint4 v2 = *reinterpret_cast<const uint4*>(m01 + (size_t)i2 * 128 + c * 4);
        uint4 v3 = *reinterpret_cast<const uint4*>(m01 + (size_t)i3 * 128 + c * 4);
        a00 += bflo(v0.x) + bflo(v1.x) + bflo(v2.x) + bflo(v3.x);
        a01 += bfhi(v0.x) + bfhi(v1.x) + bfhi(v2.x) + bfhi(v3.x);
        a02 += bflo(v0.y) + bflo(v1.y) + bflo(v2.y) + bflo(v3.y);
        a03 += bfhi(v0.y) + bfhi(v1.y) + bfhi(v2.y) + bfhi(v3.y);
        a10 += bflo(v0.z) + bflo(v1.z) + bflo(v2.z) + bflo(v3.z);
        a11 += bfhi(v0.z) + bfhi(v1.z) + bfhi(v2.z) + bfhi(v3.z);
        a12 += bflo(v0.w) + bflo(v1.w) + bflo(v2.w) + bflo(v3.w);
        a13 += bfhi(v0.w) + bfhi(v1.w) + bfhi(v2.w) + bfhi(v3.w);
    }
    for (; p < p1; p++) {
        uint4 v = *reinterpret_cast<const uint4*>(m01 + (size_t)nbr[p] * 128 + c * 4);
        a00 += bflo(v.x); a01 += bfhi(v.x); a02 += bflo(v.y); a03 += bfhi(v.y);
        a10 += bflo(v.z); a11 += bfhi(v.z); a12 += bflo(v.w); a13 += bfhi(v.w);
    }
    float sc = rsqrtf((float)deg[node] + 1.f);
    float4 bb0 = *reinterpret_cast<const float4*>(b0 + c * 4);
    float4 bb1 = *reinterpret_cast<const float4*>(b1 + c * 4);
    uint2 o0, o1;
    o0.x = packbf(sc * a00 + bb0.x, sc * a01 + bb0.y);
    o0.y = packbf(sc * a02 + bb0.z, sc * a03 + bb0.w);
    o1.x = packbf(sc * a10 + bb1.x, sc * a11 + bb1.y);
    o1.y = packbf(sc * a12 + bb1.z, sc * a13 + bb1.w);
    size_t idx = (size_t)node * 64 + c * 2;
    *reinterpret_cast<uint2*>(h0 + idx) = o0;
    *reinterpret_cast<uint2*>(h1 + idx) = o1;
}

// final agg: m01 slot0 = org (out_org), slot1 = meta (out_meta), + pr scale
__global__ void k_agg_hat(const int* __restrict__ ptr, const int* __restrict__ nbr,
                          const uint_t* __restrict__ m01,
                          const float* __restrict__ b_org, const float* __restrict__ b_meta,
                          const int* __restrict__ deg, const float* __restrict__ c_pr,
                          float* __restrict__ out_meta, float* __restrict__ out_org, int n) {
    int c = threadIdx.x & 31, li = threadIdx.x >> 5;
    int node = blockIdx.x * 8 + li;
    if (node >= n) return;
    int p0 = ptr[node], p1 = ptr[node + 1];
    uint4 s = *reinterpret_cast<const uint4*>(m01 + (size_t)node * 128 + c * 4);
    float a00 = bflo(s.x), a01 = bfhi(s.x), a02 = bflo(s.y), a03 = bfhi(s.y);
    float a10 = bflo(s.z), a11 = bfhi(s.z), a12 = bflo(s.w), a13 = bfhi(s.w);
    int p = p0;
    for (; p + 4 <= p1; p += 4) {
        int i0 = nbr[p], i1 = nbr[p + 1], i2 = nbr[p + 2], i3 = nbr[p + 3];
        uint4 v0 = *reinterpret_cast<const uint4*>(m01 + (size_t)i0 * 128 + c * 4);
        uint4 v1 = *reinterpret_cast<const uint4*>(m01 + (size_t)i1 * 128 + c * 4);
        uint4 v2 = *reinterpret_cast<const uint4*>(m01 + (size_t)i2 * 128 + c * 4);
        uint4 v3 = *reinterpret_cast<const uint4*>(m01 + (size_t)i3 * 128 + c * 4);
        a00 += bflo(v0.x) + bflo(v1.x) + bflo(v2.x) + bflo(v3.x);
        a01 += bfhi(v0.x) + bfhi(v1.x) + bfhi(v2.x) + bfhi(v3.x);
        a02 += bflo(v0.y) + bflo(v1.y) + bflo(v2.y) + bflo(v3.y);
        a03 += bfhi(v0.y) + bfhi(v1.y) + bfhi(v2.y) + bfhi(v3.y);
        a10 += bflo(v0.z) + bflo(v1.z) + bflo(v2.z) + bflo(v3.z);
        a11 += bfhi(v0.z) + bfhi(v1.z) + bfhi(v2.z) + bfhi(v3.z);
        a12 += bflo(v0.w) + bflo(v1.w) + bflo(v2.w) + bflo(v3.w);
        a13 += bfhi(v0.w) + bfhi(v1.w) + bfhi(v2.w) + bfhi(v3.w);
    }
    for (; p < p1; p++) {
        uint4 v = *reinterpret_cast<const uint4*>(m01 + (size_t)nbr[p] * 128 + c * 4);
        a00 += bflo(v.x); a01 += bfhi(v.x); a02 += bflo(v.y); a03 += bfhi(v.y);
        a10 += bflo(v.z); a11 += bfhi(v.z); a12 += bflo(v.w); a13 += bfhi(v.w);
    }
    int dg = deg[node];
    float sc = rsqrtf((float)dg + 1.f);
    float pr = c_pr[node] * fmaxf((float)dg, 1.f);
    float4 bo = *reinterpret_cast<const float4*>(b_org + c * 4);
    float4 bm = *reinterpret_cast<const float4*>(b_meta + c * 4);
    size_t o = (size_t)node * 128 + c * 4;
    *reinterpret_cast<float4*>(out_org + o) =
        make_float4((sc * a00 + bo.x) * pr, (sc * a01 + bo.y) * pr,
                    (sc * a02 + bo.z) * pr, (sc * a03 + bo.w) * pr);
    *reinterpret_cast<float4*>(out_meta + o) =
        make_float4((sc * a10 + bm.x) * pr, (sc * a11 + bm.y) * pr,
                    (sc * a12 + bm.z) * pr, (sc * a13 + bm.w) * pr);
}

// ---------------- line-graph path ----------------
// Grid-stride, one wave per edge. e is wave-uniform -> src/dst/eattr/
// deg_lg and the two 64B metafeat rows become scalar loads, done once per
// wave instead of once per lane. Each lane produces 2 output columns.
__global__ __launch_bounds__(256) void k_ef(
    const int* __restrict__ src, const int* __restrict__ dst,
    const int* __restrict__ eattr, const int* __restrict__ x,
    const float* __restrict__ metafeat, const float* __restrict__ atom_emb,
    const float* __restrict__ bond_emb, const float* __restrict__ meta_W,
    const float* __restrict__ meta_b, const int* __restrict__ deg_lg,
    ushort_t* __restrict__ u, int E) {
    __shared__ float W[16 * 128];
    __shared__ float bond[8 * 128];
    __shared__ float mb[128];
    for (int i = threadIdx.x; i < 16 * 128; i += 256) W[i] = meta_W[i];
    for (int i = threadIdx.x; i < 8 * 128; i += 256) bond[i] = bond_emb[i];
    if (threadIdx.x < 128) mb[threadIdx.x] = meta_b[threadIdx.x];
    __syncthreads();

    int l = threadIdx.x & 63;
    int j0 = l * 2;
    int wv = __builtin_amdgcn_readfirstlane(threadIdx.x >> 6);  // wave id in block (SGPR)
    int estep = gridDim.x * 4;

    for (int e = blockIdx.x * 4 + wv; e < E; e += estep) {
        int s = src[e], d = dst[e], at = eattr[e];
        int xs = x[s], xd = x[d];
        // metafeat rows: wave-uniform 64B each -> scalar (SMEM) loads
        const float4* ms4 = reinterpret_cast<const float4*>(metafeat + (size_t)s * 16);
        const float4* md4 = reinterpret_cast<const float4*>(metafeat + (size_t)d * 16);
        float mk[16];
#pragma unroll
        for (int q = 0; q < 4; q++) {
            float4 a = ms4[q], b = md4[q];
            mk[q * 4 + 0] = a.x + b.x;
            mk[q * 4 + 1] = a.y + b.y;
            mk[q * 4 + 2] = a.z + b.z;
            mk[q * 4 + 3] = a.w + b.w;
        }
        float2 av = *reinterpret_cast<const float2*>(atom_emb + (size_t)xs * 128 + j0);
        float2 bv = *reinterpret_cast<const float2*>(atom_emb + (size_t)xd * 128 + j0);
        float n0 = av.x + bv.x, n1 = av.y + bv.y;
        float2 mbv = *reinterpret_cast<const float2*>(&mb[j0]);
        float m0 = 2.f * mbv.x, m1 = 2.f * mbv.y;
#pragma unroll
        for (int k = 0; k < 16; k++) {
            float2 wv2 = *reinterpret_cast<const float2*>(&W[k * 128 + j0]);
            m0 = fmaf(mk[k], wv2.x, m0);
            m1 = fmaf(mk[k], wv2.y, m1);
        }
        float2 bo = *reinterpret_cast<const float2*>(&bond[at * 128 + j0]);
        float sc = rsqrtf((float)deg_lg[e] + 1.f);
        float v0 = sc * eluf_fast(bo.x * n0 * m0);
        float v1 = sc * eluf_fast(bo.y * n1 * m1);
        *reinterpret_cast<uint_t*>(u + (size_t)e * 128 + j0) = packbf(v0, v1);
    }
}

// v[e] = sc_e*(u[e] + sum u[e']) bf16, chunk [e0,e1) -> vout (row e-e0)
__global__ void k_lg_v(const int* __restrict__ ptr_lg, const int* __restrict__ adj_lg,
                       const int* __restrict__ deg_lg, const uint_t* __restrict__ u32,
                       uint_t* __restrict__ vout, int e0, int e1) {
    int l = threadIdx.x & 63, li = threadIdx.x >> 6;
    int e = e0 + blockIdx.x * 4 + li;
    if (e >= e1) return;
    int p0 = ptr_lg[e], p1 = ptr_lg[e + 1];
    uint_t self = u32[(size_t)e * 64 + l];
    float s0 = bflo(self), s1 = bfhi(self);
    int p = p0;
    for (; p + 4 <= p1; p += 4) {
        int i0 = adj_lg[p], i1 = adj_lg[p + 1], i2 = adj_lg[p + 2], i3 = adj_lg[p + 3];
        uint_t w0 = u32[(size_t)i0 * 64 + l];
        uint_t w1 = u32[(size_t)i1 * 64 + l];
        uint_t w2 = u32[(size_t)i2 * 64 + l];
        uint_t w3 = u32[(size_t)i3 * 64 + l];
        s0 += bflo(w0) + bflo(w1) + bflo(w2) + bflo(w3);
        s1 += bfhi(w0) + bfhi(w1) + bfhi(w2) + bfhi(w3);
    }
    for (; p < p1; p++) {
        uint_t w = u32[(size_t)adj_lg[p] * 64 + l];
        s0 += bflo(w); s1 += bfhi(w);
    }
    float sc = rsqrtf((float)deg_lg[e] + 1.f);
    vout[(size_t)(e - e0) * 64 + l] = packbf(sc * s0, sc * s1);
}

// g0f[n] (+)= sum over incident eids in [e0,e1) of v[eid-e0]; wave-uniform branch
template <int FIRST>
__global__ void k_gate_pass(const int* __restrict__ ptr, const int* __restrict__ eid,
                            const uint_t* __restrict__ v32, float* __restrict__ g0f,
                            int n, int e0, int e1) {
    int l = threadIdx.x & 63, li = threadIdx.x >> 6;
    int node = blockIdx.x * 4 + li;
    if (node >= n) return;
    int p0 = ptr[node], p1 = ptr[node + 1];
    float s0 = 0.f, s1 = 0.f;
    for (int p = p0; p < p1; p++) {
        int e = eid[p];
        if (e >= e0 && e < e1) {
            uint_t w = v32[(size_t)(e - e0) * 64 + l];
            s0 += bflo(w); s1 += bfhi(w);
        }
    }
    float2* out = reinterpret_cast<float2*>(g0f + (size_t)node * 128 + l * 2);
    if (FIRST) {
        *out = make_float2(s0, s1);
    } else {
        float2 c = *out;
        *out = make_float2(c.x + s0, c.y + s1);
    }
}

// ---------------- pagerank: ELL, 4 lanes/node ----------------
__global__ void k_pr_init(const int* __restrict__ deg, float* __restrict__ c,
                          float* __restrict__ invdeg, int n, float invN) {
    int i = blockIdx.x * blockDim.x + threadIdx.x;
    if (i < n) {
        float iv = 1.f / fmaxf((float)deg[i], 1.f);
        invdeg[i] = iv;
        c[i] = invN * iv;
    }
}

__global__ void k_ell_build(const int* __restrict__ ptr, const int* __restrict__ nbr,
                            int* __restrict__ ell, int N) {
    int tid = blockIdx.x * blockDim.x + threadIdx.x;
    int node = tid >> 2, t = tid & 3;
    if (node >= N) return;
    int p0 = ptr[node];
    int dg = ptr[node + 1] - p0;
    if (dg > ELL_CAP) dg = ELL_CAP;
    int stride = N * 4;
    for (int k = 0; 4 * k + t < dg; k++)
        ell[k * stride + tid] = nbr[p0 + 4 * k + t];
}

__global__ void k_pr_ell(const int* __restrict__ ell, const int* __restrict__ ptr,
                         const int* __restrict__ nbr, const float* __restrict__ invdeg,
                         const float* __restrict__ cin, float* __restrict__ cout,
                         int N, float base, float damp) {
    int tid = blockIdx.x * blockDim.x + threadIdx.x;
    int node = tid >> 2, t = tid & 3;
    if (node >= N) return;
    int p0 = ptr[node], p1 = ptr[node + 1];
    int dg = p1 - p0;
    int dgc = dg > ELL_CAP ? ELL_CAP : dg;
    int stride = N * 4;
    float s = 0.f;
    for (int k = 0; 4 * k + t < dgc; k++) s += cin[ell[k * stride + tid]];
    for (int p = p0 + ELL_CAP + t; p < p1; p += 4) s += cin[nbr[p]];
    s += __shfl_xor(s, 1);
    s += __shfl_xor(s, 2);
    if (t == 0) cout[node] = (base + damp * s) * invdeg[node];
}

// ---------------- pooling + heads ----------------
__global__ void k_pool(const float* __restrict__ out_meta, const float* __restrict__ out_org,
                       float* __restrict__ partial, int n) {
    int tid = threadIdx.x;
    const float* basep = (tid < 128) ? out_meta : out_org;
    int dim = tid & 127;
    float acc = 0.f;
    for (int i = blockIdx.x; i < n; i += gridDim.x) acc += basep[(size_t)i * 128 + dim];
    partial[blockIdx.x * 256 + tid] = acc;
}

__global__ void k_final(const float* __restrict__ partial, int nblocks,
                        const float* __restrict__ cat2_W, const float* __restrict__ cat2_b,
                        const float* __restrict__ pred_W, const float* __restrict__ pred_b,
                        float* __restrict__ out) {
    __shared__ float z[256];
    __shared__ float Z[128];
    int tid = threadIdx.x;
    float acc = 0.f;
    for (int p = 0; p < nblocks; p++) acc += partial[p * 256 + tid];
    z[tid] = acc;
    __syncthreads();
    if (tid < 128) {
        float s = cat2_b[tid];
        for (int k = 0; k < 256; k++) s = fmaf(z[k], cat2_W[k * 128 + tid], s);
        Z[tid] = s;
    }
    __syncthreads();
    if (tid < 12) {
        float s = pred_b[tid];
        for (int k = 0; k < 128; k++) s = fmaf(Z[k], pred_W[k * 12 + tid], s);
        out[tid] = s;
    }
}

// ---------------------------------------------------------------------------
extern "C" void kernel_launch(void* const* d_in, const int* in_sizes, int n_in,
                              void* d_out, int out_size, void* d_ws, size_t ws_size,
                              hipStream_t stream) {
    const int* x            = (const int*)d_in[0];
    const float* metafeat   = (const float*)d_in[1];
    const int* edge_attr    = (const int*)d_in[2];
    const int* edge_index   = (const int*)d_in[3];
    const int* lg_edge_index= (const int*)d_in[4];
    const float* atom_emb   = (const float*)d_in[5];
    const float* bond_emb   = (const float*)d_in[6];
    const float* meta_W     = (const float*)d_in[7];
    const float* meta_b     = (const float*)d_in[8];
    const float* org_W      = (const float*)d_in[9];
    const float* org_b      = (const float*)d_in[10];
    const float* org1_W     = (const float*)d_in[11];
    const float* org1_b     = (const float*)d_in[12];
    const float* mconv_W    = (const float*)d_in[13];
    const float* mconv_b    = (const float*)d_in[14];
    const float* mconv1_W   = (const float*)d_in[15];
    const float* mconv1_b   = (const float*)d_in[16];
    const float* lg_W       = (const float*)d_in[17];
    const float* lg_b       = (const float*)d_in[18];
    const float* cat2_W     = (const float*)d_in[21];
    const float* cat2_b     = (const float*)d_in[22];
    const float* pred_W     = (const float*)d_in[23];
    const float* pred_b     = (const float*)d_in[24];

    const int N = in_sizes[0];
    const int E = in_sizes[2];
    const int ELG = in_sizes[4] / 2;
    const int* src = edge_index;
    const int* dst = edge_index + E;
    const int* ls = lg_edge_index;
    const int* ld = lg_edge_index + ELG;

    // ---- workspace carve (~193 MB, proven R6 footprint) ----
    char* w = (char*)d_ws;
    auto alloc = [&](size_t bytes) -> void* {
        void* p = (void*)w;
        w += (bytes + 255) & ~(size_t)255;
        return p;
    };
    int* deg_n   = (int*)alloc((size_t)N * 4);
    int* ptr_n   = (int*)alloc((size_t)(N + 1) * 4);
    int* cur_n   = (int*)alloc((size_t)N * 4);
    int* adj_nbr = (int*)alloc((size_t)2 * E * 4);
    int* adj_eid = (int*)alloc((size_t)2 * E * 4);
    int* deg_lg  = (int*)alloc((size_t)E * 4);
    int* ptr_lg  = (int*)alloc((size_t)(E + 1) * 4);
    int* cur_lg  = (int*)alloc((size_t)E * 4);
    int* adj_lg  = (int*)alloc((size_t)2 * ELG * 4);
    int* bsum    = (int*)alloc((size_t)SCAN_NB * 4);
    float* c_a   = (float*)alloc((size_t)N * 4);
    float* c_b   = (float*)alloc((size_t)N * 4);
    float* invdg = (float*)alloc((size_t)N * 4);
    float* partial = (float*)alloc((size_t)POOL_BLOCKS * 256 * 4);
    uint_t* gateA = (uint_t*)alloc((size_t)N * 64 * 4);   // bf16: gate_n then gate_l
    float* g0f   = (float*)alloc((size_t)N * 128 * 4);    // fp32 gate accumulator
    uint_t* h_orgb  = (uint_t*)alloc((size_t)N * 64 * 4); // bf16
    uint_t* h_metab = (uint_t*)alloc((size_t)N * 64 * 4); // bf16
    size_t nodeB = (size_t)N * 64;                         // uints per bf16 node array
    size_t u_bytes = (size_t)E * 64 * 4;                   // E x 128 bf16
    size_t reg_bytes = 4 * nodeB * 4;
    uint_t* reg = (uint_t*)alloc(reg_bytes > u_bytes ? reg_bytes : u_bytes);
    uint_t* nf0b = reg;
    uint_t* mf0b = reg + nodeB;
    uint_t* m01  = reg + 2 * nodeB;  // interleaved m0/m1, pitch 128 uints/node
    ushort_t* u  = (ushort_t*)reg;   // overlays nf0b..m01 (all dead by then)
    int* ell     = (int*)reg;        // overlays nf0b quarter after u dies
    (void)n_in; (void)ws_size;

    float* out_pred = (float*)d_out;
    float* out_meta = out_pred + 12;
    float* out_org  = out_pred + 12 + (size_t)N * 128;
    // d_out doubles as the v-chunk scratch during the lg path (dead until agg_hat)
    uint_t* vhalf = (uint_t*)d_out;   // capacity: out_size*4 >= (E/2)*256 bytes
    (void)out_size;

    // ---- CSR build ----
    hipMemsetAsync(deg_n, 0, (size_t)N * 4, stream);
    hipMemsetAsync(deg_lg, 0, (size_t)E * 4, stream);
    k_count<<<(E + 255) / 256, 256, 0, stream>>>(src, dst, E, deg_n);
    {
        int C = (N + SCAN_NB - 1) / SCAN_NB;
        k_scan1<<<SCAN_NB, 256, 0, stream>>>(deg_n, N, C, bsum);
        k_scan2<<<1, 256, 0, stream>>>(bsum, SCAN_NB, ptr_n + N);
        k_scan3<<<SCAN_NB, 256, 0, stream>>>(deg_n, bsum, N, C, ptr_n, cur_n);
    }
    {
        int rngN = (N + FILL_NR - 1) / FILL_NR;
        int nchunkN = 96;
        k_fill_part<1><<<FILL_NR * nchunkN, 256, 0, stream>>>(src, dst, E, cur_n,
                                                              adj_nbr, adj_eid, rngN, nchunkN);
    }
    k_count<<<(ELG + 255) / 256, 256, 0, stream>>>(ls, ld, ELG, deg_lg);
    {
        int C = (E + SCAN_NB - 1) / SCAN_NB;
        k_scan1<<<SCAN_NB, 256, 0, stream>>>(deg_lg, E, C, bsum);
        k_scan2<<<1, 256, 0, stream>>>(bsum, SCAN_NB, ptr_lg + E);
        k_scan3<<<SCAN_NB, 256, 0, stream>>>(deg_lg, bsum, E, C, ptr_lg, cur_lg);
    }
    {
        int rngE = (E + FILL_NR - 1) / FILL_NR;
        int nchunkE = 192;
        k_fill_part<0><<<FILL_NR * nchunkE, 256, 0, stream>>>(ls, ld, ELG, cur_lg,
                                                              adj_lg, nullptr, rngE, nchunkE);
    }

    // ---- encoders + gate_n (bf16) ----
    k_encoder<<<(N * 64 + 255) / 256, 256, 0, stream>>>(x, metafeat, atom_emb, meta_W, meta_b,
                                                        nf0b, mf0b, N);
    k_gate_node<<<(N + 3) / 4, 256, 0, stream>>>(ptr_n, adj_eid, edge_attr, bond_emb, gateA, N);

    const int gb_n = (N + 127) / 128;

    // ---- GCN layer 1 (bf16 in, interleaved bf16 out) ----
    k_gemm<1, 0, 1, 1, 1><<<gb_n, 256, 0, stream>>>(nf0b, gateA, org_W, nullptr, deg_n,
                                                    m01 + 0, N);   // slot 0 = org
    k_gemm<1, 0, 1, 1, 1><<<gb_n, 256, 0, stream>>>(mf0b, gateA, mconv_W, nullptr, deg_n,
                                                    m01 + 2, N);   // slot 1 = meta
    k_agg_dual<<<(N + 7) / 8, 256, 0, stream>>>(ptr_n, adj_nbr, m01, org_b, mconv_b,
                                                deg_n, h_orgb, h_metab, N);
    // reg region becomes u (bf16)

    // ---- line-graph path: u -> v (2 chunks via d_out scratch) -> g0f fp32 ----
    k_ef<<<EF_BLOCKS, 256, 0, stream>>>(src, dst, edge_attr, x, metafeat, atom_emb,
                                        bond_emb, meta_W, meta_b, deg_lg, u, E);
    {
        int eh = (E + 1) / 2;
        k_lg_v<<<(eh + 3) / 4, 256, 0, stream>>>(ptr_lg, adj_lg, deg_lg, (const uint_t*)u,
                                                 vhalf, 0, eh);
        k_gate_pass<1><<<(N + 3) / 4, 256, 0, stream>>>(ptr_n, adj_eid, vhalf, g0f, N, 0, eh);
        k_lg_v<<<(E - eh + 3) / 4, 256, 0, stream>>>(ptr_lg, adj_lg, deg_lg, (const uint_t*)u,
                                                     vhalf, eh, E);
        k_gate_pass<0><<<(N + 3) / 4, 256, 0, stream>>>(ptr_n, adj_eid, vhalf, g0f, N, eh, E);
    }
    k_gemm<0, 1, 0, 1, 0><<<gb_n, 256, 0, stream>>>(g0f, nullptr, lg_W, lg_b, deg_n,
                                                    gateA, N);   // gate_l bf16

    // ---- GCN layer 2 (gated, bf16 in, interleaved out) ----
    k_gemm<1, 0, 1, 1, 1><<<gb_n, 256, 0, stream>>>(h_orgb, gateA, org1_W, nullptr, deg_n,
                                                    m01 + 0, N);
    k_gemm<1, 0, 1, 1, 1><<<gb_n, 256, 0, stream>>>(h_metab, gateA, mconv1_W, nullptr, deg_n,
                                                    m01 + 2, N);
    // u dead; nf0b quarter free -> ELL

    // ---- pagerank: ELL build + PR_ITERS graph-captured launches ----
    float invN = (float)(1.0 / (double)N);
    float base = (float)((1.0 - 0.85) / (double)N);
    k_pr_init<<<(N + 255) / 256, 256, 0, stream>>>(deg_n, c_a, invdg, N, invN);
    int prb = (4 * N + 255) / 256;
    k_ell_build<<<prb, 256, 0, stream>>>(ptr_n, adj_nbr, ell, N);
    float* pin = c_a;
    float* pout = c_b;
    for (int it = 0; it < PR_ITERS; ++it) {
        k_pr_ell<<<prb, 256, 0, stream>>>(ell, ptr_n, adj_nbr, invdg, pin, pout, N,
                                          base, 0.85f);
        float* t = pin; pin = pout; pout = t;
    }

    // ---- final agg + pagerank scale -> d_out (vhalf scratch now dead) ----
    k_agg_hat<<<(N + 7) / 8, 256, 0, stream>>>(ptr_n, adj_nbr, m01, org1_b, mconv1_b,
                                               deg_n, pin, out_meta, out_org, N);
    k_pool<<<POOL_BLOCKS, 256, 0, stream>>>(out_meta, out_org, partial, N);
    k_final<<<1, 256, 0, stream>>>(partial, POOL_BLOCKS, cat2_W, cat2_b, pred_W, pred_b, out_pred);
}

// Round 4
// 1629.979 us; speedup vs baseline: 1.1165x; 1.1165x over previous
//
#include <hip/hip_runtime.h>
#include <hip/hip_bf16.h>
#include <math.h>

// ---------------------------------------------------------------------------
// IMPGNN on MI355X. fp32 accumulate; bf16 storage for streamed/gathered
// intermediates. Tol = 2% of output absmax (measured margin >>10x).
// R11 vs R10:
//   - GEMM: tile 128x128 -> 64x128 (2x grid), and org/meta pairs batched
//     into ONE launch (they share the gate operand). 5 gemm launches -> 3;
//     391 blocks (1.5/CU, latency-bound; R10 showed a 160us dispatch at
//     0.41% occupancy) -> 1564 blocks (~6/CU).
//   - PR_ITERS 48 -> 32. Error model validated: 0.85^48 x pr-scale
//     predicted ~8e-9 abs err, measured 6e-8 absmax; at 32 iters ~1e-6
//     vs tol ~2e-5 -> >=20x margin.
//   - Fills left alone: R9/R10 established each scatter store costs a
//     full 64B line regardless of L2 residency (208->181MB across two
//     mechanism-targeted fixes). Further gains need coalesced-by-
//     construction scatter (sort/bin) - not attempted.
// ---------------------------------------------------------------------------

#define POOL_BLOCKS 400
#define SCAN_NB 256
#define ELL_CAP 64
#define PR_ITERS 32   // even: result ends in c_a
#define EF_BLOCKS 2048
#define FILL_NR 8     // ranges (XCD-affine)

typedef unsigned short ushort_t;
typedef unsigned int uint_t;

__device__ __forceinline__ float eluf(float x) { return x > 0.f ? x : expm1f(x); }
__device__ __forceinline__ float eluf_fast(float x) { return x > 0.f ? x : __expf(x) - 1.f; }
__device__ __forceinline__ float bf2f(ushort_t v) {
    return __uint_as_float(((unsigned int)v) << 16);
}
__device__ __forceinline__ ushort_t f2bf(float f) {
    unsigned int u = __float_as_uint(f);
    unsigned int lsb = (u >> 16) & 1u;
    u += 0x7fffu + lsb;           // round-to-nearest-even
    return (ushort_t)(u >> 16);
}
__device__ __forceinline__ float bflo(uint_t v) { return __uint_as_float(v << 16); }
__device__ __forceinline__ float bfhi(uint_t v) { return __uint_as_float(v & 0xffff0000u); }
__device__ __forceinline__ uint_t packbf(float a, float b) {
    return (uint_t)f2bf(a) | ((uint_t)f2bf(b) << 16);
}

// ---------------- CSR build ----------------
__global__ void k_count(const int* __restrict__ a, const int* __restrict__ b,
                        int E, int* __restrict__ deg) {
    int e = blockIdx.x * blockDim.x + threadIdx.x;
    if (e < E) {
        int s = __builtin_nontemporal_load(a + e);
        int d = __builtin_nontemporal_load(b + e);
        atomicAdd(&deg[s], 1); atomicAdd(&deg[d], 1);
    }
}

__global__ void k_scan1(const int* __restrict__ deg, int n, int C, int* __restrict__ bsum) {
    __shared__ int red[256];
    int b = blockIdx.x, tid = threadIdx.x;
    int base = b * C, end = min(base + C, n);
    int s = 0;
    for (int i = base + tid; i < end; i += 256) s += deg[i];
    red[tid] = s;
    __syncthreads();
    for (int off = 128; off > 0; off >>= 1) {
        if (tid < off) red[tid] += red[tid + off];
        __syncthreads();
    }
    if (tid == 0) bsum[b] = red[0];
}

__global__ void k_scan2(int* __restrict__ bsum, int NB, int* __restrict__ total_out) {
    __shared__ int s[256];
    int tid = threadIdx.x;
    int v = (tid < NB) ? bsum[tid] : 0;
    s[tid] = v;
    __syncthreads();
    for (int off = 1; off < 256; off <<= 1) {
        int w = (tid >= off) ? s[tid - off] : 0;
        __syncthreads();
        s[tid] += w;
        __syncthreads();
    }
    if (tid < NB) bsum[tid] = s[tid] - v;
    if (tid == 255) *total_out = s[255];
}

__global__ void k_scan3(const int* __restrict__ deg, const int* __restrict__ boff,
                        int n, int C, int* __restrict__ ptr, int* __restrict__ cur) {
    __shared__ int s[256];
    __shared__ int carry;
    int b = blockIdx.x, tid = threadIdx.x;
    int base = b * C, end = min(base + C, n);
    if (tid == 0) carry = boff[b];
    __syncthreads();
    for (int t = base; t < end; t += 256) {
        int i = t + tid;
        int v = (i < end) ? deg[i] : 0;
        s[tid] = v;
        __syncthreads();
        for (int off = 1; off < 256; off <<= 1) {
            int w = (tid >= off) ? s[tid - off] : 0;
            __syncthreads();
            s[tid] += w;
            __syncthreads();
        }
        int p = carry + s[tid] - v;
        if (i < end) { ptr[i] = p; cur[i] = p; }
        __syncthreads();
        if (tid == 0) carry += s[255];
        __syncthreads();
    }
}

// Range-partitioned CSR fill (see R9/R10 notes above).
template <int WITH_EID>
__global__ void k_fill_part(const int* __restrict__ a, const int* __restrict__ b,
                            int E, int* __restrict__ cur, int* __restrict__ nbr,
                            int* __restrict__ eid, int rngsize, int nchunk) {
    int r = blockIdx.x & (FILL_NR - 1);
    int chunk = blockIdx.x >> 3;
    int lo = r * rngsize, hi = lo + rngsize;
    int per = (E + nchunk - 1) / nchunk;
    int e0 = chunk * per;
    int e1 = min(e0 + per, E);
    for (int e = e0 + threadIdx.x; e < e1; e += blockDim.x) {
        int s = __builtin_nontemporal_load(a + e);
        int d = __builtin_nontemporal_load(b + e);
        if (s >= lo && s < hi) {
            int p = atomicAdd(&cur[s], 1);
            nbr[p] = d;
            if (WITH_EID) eid[p] = e;
        }
        if (d >= lo && d < hi) {
            int p = atomicAdd(&cur[d], 1);
            nbr[p] = s;
            if (WITH_EID) eid[p] = e;
        }
    }
}

// ---------------- encoders (bf16 out) ----------------
__global__ void k_encoder(const int* __restrict__ x, const float* __restrict__ metafeat,
                          const float* __restrict__ atom_emb, const float* __restrict__ meta_W,
                          const float* __restrict__ meta_b, uint_t* __restrict__ nf0,
                          uint_t* __restrict__ mf0, int N) {
    __shared__ float W[16 * 128];
    __shared__ float bsh[128];
    for (int i = threadIdx.x; i < 16 * 128; i += blockDim.x) W[i] = meta_W[i];
    if (threadIdx.x < 128) bsh[threadIdx.x] = meta_b[threadIdx.x];
    __syncthreads();
    int idx = blockIdx.x * blockDim.x + threadIdx.x;
    if (idx < N * 64) {
        int i = idx >> 6, j2 = idx & 63;
        float2 av = *reinterpret_cast<const float2*>(atom_emb + (size_t)x[i] * 128 + j2 * 2);
        nf0[idx] = packbf(av.x, av.y);
        const float* mrow = metafeat + (size_t)i * 16;
        float a0 = bsh[j2 * 2], a1 = bsh[j2 * 2 + 1];
#pragma unroll
        for (int k = 0; k < 16; k++) {
            float m = mrow[k];
            a0 = fmaf(m, W[k * 128 + j2 * 2], a0);
            a1 = fmaf(m, W[k * 128 + j2 * 2 + 1], a1);
        }
        mf0[idx] = packbf(a0, a1);
    }
}

__global__ void k_gate_node(const int* __restrict__ ptr, const int* __restrict__ eid_arr,
                            const int* __restrict__ edge_attr, const float* __restrict__ bond_emb,
                            uint_t* __restrict__ gate, int N) {
    __shared__ float bond[8 * 128];
    for (int i = threadIdx.x; i < 8 * 128; i += blockDim.x) bond[i] = bond_emb[i];
    __syncthreads();
    int l = threadIdx.x & 63, li = threadIdx.x >> 6;
    int node = blockIdx.x * 4 + li;
    if (node >= N) return;
    int p0 = ptr[node], p1 = ptr[node + 1];
    float g0 = 0.f, g1 = 0.f;
    for (int p = p0; p < p1; p++) {
        int a = edge_attr[eid_arr[p]];
        float2 bv = *reinterpret_cast<const float2*>(&bond[a * 128 + l * 2]);
        g0 += bv.x; g1 += bv.y;
    }
    gate[(size_t)node * 64 + l] = packbf(g0, g1);
}

// ---------------- GEMM (64-row tile, optional 2-batch) ----------------
// GATED: A = elu(X*G). IBF16: X packed bf16 pitch 64 (G always bf16 pitch 64).
// EPI 0: out = rsqrt(deg+1)*acc   EPI 1: out = acc + deg*bias
// OBF16: bf16 out. OILV: interleaved m01 layout (pitch 128 uints).
// BATCH: blocks >= gb handle (Xv2, W2, outv2) with the SAME gate/deg.
template <int GATED, int EPI, int IBF16, int OBF16, int OILV, int BATCH>
__global__ __launch_bounds__(256, 4) void k_gemm64(
    const void* __restrict__ Xv, const void* __restrict__ Gv,
    const float* __restrict__ W, const float* __restrict__ bias,
    const int* __restrict__ deg, void* __restrict__ outv,
    const void* __restrict__ Xv2, const float* __restrict__ W2,
    void* __restrict__ outv2, int gb, int M) {
    __shared__ float As[64][33];
    __shared__ float Bs[32][128];
    int tid = threadIdx.x;
    int tx = tid & 15, ty = tid >> 4;

    int bid = blockIdx.x;
    const void* Xp = Xv;
    const float* Wp = W;
    void* outp = outv;
    if (BATCH && bid >= gb) { bid -= gb; Xp = Xv2; Wp = W2; outp = outv2; }
    int row0 = bid * 64;

    float acc[4][8];
#pragma unroll
    for (int i = 0; i < 4; i++)
#pragma unroll
        for (int j = 0; j < 8; j++) acc[i][j] = 0.f;

    for (int h = 0; h < 4; h++) {
#pragma unroll
        for (int p = 0; p < 4; p++) {
            int idx = p * 256 + tid;
            int kk = idx >> 5, cg = idx & 31;
            float4 w = *reinterpret_cast<const float4*>(Wp + (h * 32 + kk) * 128 + cg * 4);
            *reinterpret_cast<float4*>(&Bs[kk][cg * 4]) = w;
        }
        int kg = tid & 7, rr = tid >> 3;
#pragma unroll
        for (int p = 0; p < 2; p++) {
            int r = p * 32 + rr;
            int grow = row0 + r;
            float4 av;
            if (grow < M) {
                float x0, x1, x2, x3;
                if (IBF16) {
                    const uint_t* Xb = (const uint_t*)Xp;
                    uint2 xu = *reinterpret_cast<const uint2*>(
                        Xb + (size_t)grow * 64 + h * 16 + kg * 2);
                    x0 = bflo(xu.x); x1 = bfhi(xu.x); x2 = bflo(xu.y); x3 = bfhi(xu.y);
                } else {
                    const float* Xf = (const float*)Xp;
                    float4 xv = *reinterpret_cast<const float4*>(
                        Xf + (size_t)grow * 128 + h * 32 + kg * 4);
                    x0 = xv.x; x1 = xv.y; x2 = xv.z; x3 = xv.w;
                }
                if (GATED) {
                    const uint_t* Gb = (const uint_t*)Gv;
                    uint2 gu = *reinterpret_cast<const uint2*>(
                        Gb + (size_t)grow * 64 + h * 16 + kg * 2);
                    av.x = eluf(x0 * bflo(gu.x)); av.y = eluf(x1 * bfhi(gu.x));
                    av.z = eluf(x2 * bflo(gu.y)); av.w = eluf(x3 * bfhi(gu.y));
                } else {
                    av = make_float4(x0, x1, x2, x3);
                }
            } else av = make_float4(0.f, 0.f, 0.f, 0.f);
            As[r][kg * 4 + 0] = av.x; As[r][kg * 4 + 1] = av.y;
            As[r][kg * 4 + 2] = av.z; As[r][kg * 4 + 3] = av.w;
        }
        __syncthreads();
#pragma unroll 8
        for (int k = 0; k < 32; k++) {
            float a[4], b[8];
#pragma unroll
            for (int i = 0; i < 4; i++) a[i] = As[ty * 4 + i][k];
            float4 b0 = *reinterpret_cast<const float4*>(&Bs[k][tx * 4]);
            float4 b1 = *reinterpret_cast<const float4*>(&Bs[k][64 + tx * 4]);
            b[0] = b0.x; b[1] = b0.y; b[2] = b0.z; b[3] = b0.w;
            b[4] = b1.x; b[5] = b1.y; b[6] = b1.z; b[7] = b1.w;
#pragma unroll
            for (int i = 0; i < 4; i++)
#pragma unroll
                for (int j = 0; j < 8; j++) acc[i][j] = fmaf(a[i], b[j], acc[i][j]);
        }
        __syncthreads();
    }
#pragma unroll
    for (int i = 0; i < 4; i++) {
        int r = row0 + ty * 4 + i;
        if (r < M) {
            float o[8];
            if (EPI == 0) {
                float sc = rsqrtf((float)deg[r] + 1.0f);
#pragma unroll
                for (int j = 0; j < 8; j++) o[j] = acc[i][j] * sc;
            } else {
                float dg = (float)deg[r];
                float4 ba = *reinterpret_cast<const float4*>(bias + tx * 4);
                float4 bb = *reinterpret_cast<const float4*>(bias + 64 + tx * 4);
                o[0] = acc[i][0] + dg * ba.x; o[1] = acc[i][1] + dg * ba.y;
                o[2] = acc[i][2] + dg * ba.z; o[3] = acc[i][3] + dg * ba.w;
                o[4] = acc[i][4] + dg * bb.x; o[5] = acc[i][5] + dg * bb.y;
                o[6] = acc[i][6] + dg * bb.z; o[7] = acc[i][7] + dg * bb.w;
            }
            if (OBF16) {
                uint_t* ob = (uint_t*)outp;
                uint2 q0, q1;
                q0.x = packbf(o[0], o[1]); q0.y = packbf(o[2], o[3]);
                q1.x = packbf(o[4], o[5]); q1.y = packbf(o[6], o[7]);
                if (OILV) {
                    *reinterpret_cast<uint2*>(ob + (size_t)r * 128 + tx * 4) = q0;
                    *reinterpret_cast<uint2*>(ob + (size_t)r * 128 + 64 + tx * 4) = q1;
                } else {
                    *reinterpret_cast<uint2*>(ob + (size_t)r * 64 + tx * 2) = q0;
                    *reinterpret_cast<uint2*>(ob + (size_t)r * 64 + 32 + tx * 2) = q1;
                }
            } else {
                float* out = (float*)outp;
                *reinterpret_cast<float4*>(out + (size_t)r * 128 + tx * 4) =
                    make_float4(o[0], o[1], o[2], o[3]);
                *reinterpret_cast<float4*>(out + (size_t)r * 128 + 64 + tx * 4) =
                    make_float4(o[4], o[5], o[6], o[7]);
            }
        }
    }
}

// ---------------- node aggregations on interleaved m01 ----------------
// m01 layout: uint4 at [node*128 + c*4]: .xy = m0 dims 4c..4c+3, .zw = m1 same.
__global__ void k_agg_dual(const int* __restrict__ ptr, const int* __restrict__ nbr,
                           const uint_t* __restrict__ m01,
                           const float* __restrict__ b0, const float* __restrict__ b1,
                           const int* __restrict__ deg, uint_t* __restrict__ h0,
                           uint_t* __restrict__ h1, int n) {
    int c = threadIdx.x & 31, li = threadIdx.x >> 5;
    int node = blockIdx.x * 8 + li;
    if (node >= n) return;
    int p0 = ptr[node], p1 = ptr[node + 1];
    uint4 s = *reinterpret_cast<const uint4*>(m01 + (size_t)node * 128 + c * 4);
    float a00 = bflo(s.x), a01 = bfhi(s.x), a02 = bflo(s.y), a03 = bfhi(s.y);
    float a10 = bflo(s.z), a11 = bfhi(s.z), a12 = bflo(s.w), a13 = bfhi(s.w);
    int p = p0;
    for (; p + 4 <= p1; p += 4) {
        int i0 = nbr[p], i1 = nbr[p + 1], i2 = nbr[p + 2], i3 = nbr[p + 3];
        uint4 v0 = *reinterpret_cast<const uint4*>(m01 + (size_t)i0 * 128 + c * 4);
        uint4 v1 = *reinterpret_cast<const uint4*>(m01 + (size_t)i1 * 128 + c * 4);
        uint4 v2 = *reinterpret_cast<const uint4*>(m01 + (size_t)i2 * 128 + c * 4);
        uint4 v3 = *reinterpret_cast<const uint4*>(m01 + (size_t)i3 * 128 + c * 4);
        a00 += bflo(v0.x) + bflo(v1.x) + bflo(v2.x) + bflo(v3.x);
        a01 += bfhi(v0.x) + bfhi(v1.x) + bfhi(v2.x) + bfhi(v3.x);
        a02 += bflo(v0.y) + bflo(v1.y) + bflo(v2.y) + bflo(v3.y);
        a03 += bfhi(v0.y) + bfhi(v1.y) + bfhi(v2.y) + bfhi(v3.y);
        a10 += bflo(v0.z) + bflo(v1.z) + bflo(v2.z) + bflo(v3.z);
        a11 += bfhi(v0.z) + bfhi(v1.z) + bfhi(v2.z) + bfhi(v3.z);
        a12 += bflo(v0.w) + bflo(v1.w) + bflo(v2.w) + bflo(v3.w);
        a13 += bfhi(v0.w) + bfhi(v1.w) + bfhi(v2.w) + bfhi(v3.w);
    }
    for (; p < p1; p++) {
        uint4 v = *reinterpret_cast<const uint4*>(m01 + (size_t)nbr[p] * 128 + c * 4);
        a00 += bflo(v.x); a01 += bfhi(v.x); a02 += bflo(v.y); a03 += bfhi(v.y);
        a10 += bflo(v.z); a11 += bfhi(v.z); a12 += bflo(v.w); a13 += bfhi(v.w);
    }
    float sc = rsqrtf((float)deg[node] + 1.f);
    float4 bb0 = *reinterpret_cast<const float4*>(b0 + c * 4);
    float4 bb1 = *reinterpret_cast<const float4*>(b1 + c * 4);
    uint2 o0, o1;
    o0.x = packbf(sc * a00 + bb0.x, sc * a01 + bb0.y);
    o0.y = packbf(sc * a02 + bb0.z, sc * a03 + bb0.w);
    o1.x = packbf(sc * a10 + bb1.x, sc * a11 + bb1.y);
    o1.y = packbf(sc * a12 + bb1.z, sc * a13 + bb1.w);
    size_t idx = (size_t)node * 64 + c * 2;
    *reinterpret_cast<uint2*>(h0 + idx) = o0;
    *reinterpret_cast<uint2*>(h1 + idx) = o1;
}

// final agg: m01 slot0 = org (out_org), slot1 = meta (out_meta), + pr scale
__global__ void k_agg_hat(const int* __restrict__ ptr, const int* __restrict__ nbr,
                          const uint_t* __restrict__ m01,
                          const float* __restrict__ b_org, const float* __restrict__ b_meta,
                          const int* __restrict__ deg, const float* __restrict__ c_pr,
                          float* __restrict__ out_meta, float* __restrict__ out_org, int n) {
    int c = threadIdx.x & 31, li = threadIdx.x >> 5;
    int node = blockIdx.x * 8 + li;
    if (node >= n) return;
    int p0 = ptr[node], p1 = ptr[node + 1];
    uint4 s = *reinterpret_cast<const uint4*>(m01 + (size_t)node * 128 + c * 4);
    float a00 = bflo(s.x), a01 = bfhi(s.x), a02 = bflo(s.y), a03 = bfhi(s.y);
    float a10 = bflo(s.z), a11 = bfhi(s.z), a12 = bflo(s.w), a13 = bfhi(s.w);
    int p = p0;
    for (; p + 4 <= p1; p += 4) {
        int i0 = nbr[p], i1 = nbr[p + 1], i2 = nbr[p + 2], i3 = nbr[p + 3];
        uint4 v0 = *reinterpret_cast<const uint4*>(m01 + (size_t)i0 * 128 + c * 4);
        uint4 v1 = *reinterpret_cast<const uint4*>(m01 + (size_t)i1 * 128 + c * 4);
        uint4 v2 = *reinterpret_cast<const uint4*>(m01 + (size_t)i2 * 128 + c * 4);
        uint4 v3 = *reinterpret_cast<const uint4*>(m01 + (size_t)i3 * 128 + c * 4);
        a00 += bflo(v0.x) + bflo(v1.x) + bflo(v2.x) + bflo(v3.x);
        a01 += bfhi(v0.x) + bfhi(v1.x) + bfhi(v2.x) + bfhi(v3.x);
        a02 += bflo(v0.y) + bflo(v1.y) + bflo(v2.y) + bflo(v3.y);
        a03 += bfhi(v0.y) + bfhi(v1.y) + bfhi(v2.y) + bfhi(v3.y);
        a10 += bflo(v0.z) + bflo(v1.z) + bflo(v2.z) + bflo(v3.z);
        a11 += bfhi(v0.z) + bfhi(v1.z) + bfhi(v2.z) + bfhi(v3.z);
        a12 += bflo(v0.w) + bflo(v1.w) + bflo(v2.w) + bflo(v3.w);
        a13 += bfhi(v0.w) + bfhi(v1.w) + bfhi(v2.w) + bfhi(v3.w);
    }
    for (; p < p1; p++) {
        uint4 v = *reinterpret_cast<const uint4*>(m01 + (size_t)nbr[p] * 128 + c * 4);
        a00 += bflo(v.x); a01 += bfhi(v.x); a02 += bflo(v.y); a03 += bfhi(v.y);
        a10 += bflo(v.z); a11 += bfhi(v.z); a12 += bflo(v.w); a13 += bfhi(v.w);
    }
    int dg = deg[node];
    float sc = rsqrtf((float)dg + 1.f);
    float pr = c_pr[node] * fmaxf((float)dg, 1.f);
    float4 bo = *reinterpret_cast<const float4*>(b_org + c * 4);
    float4 bm = *reinterpret_cast<const float4*>(b_meta + c * 4);
    size_t o = (size_t)node * 128 + c * 4;
    *reinterpret_cast<float4*>(out_org + o) =
        make_float4((sc * a00 + bo.x) * pr, (sc * a01 + bo.y) * pr,
                    (sc * a02 + bo.z) * pr, (sc * a03 + bo.w) * pr);
    *reinterpret_cast<float4*>(out_meta + o) =
        make_float4((sc * a10 + bm.x) * pr, (sc * a11 + bm.y) * pr,
                    (sc * a12 + bm.z) * pr, (sc * a13 + bm.w) * pr);
}

// ---------------- line-graph path ----------------
// Grid-stride, one wave per edge. e is wave-uniform -> src/dst/eattr/
// deg_lg and the two 64B metafeat rows become scalar loads, done once per
// wave instead of once per lane. Each lane produces 2 output columns.
__global__ __launch_bounds__(256) void k_ef(
    const int* __restrict__ src, const int* __restrict__ dst,
    const int* __restrict__ eattr, const int* __restrict__ x,
    const float* __restrict__ metafeat, const float* __restrict__ atom_emb,
    const float* __restrict__ bond_emb, const float* __restrict__ meta_W,
    const float* __restrict__ meta_b, const int* __restrict__ deg_lg,
    ushort_t* __restrict__ u, int E) {
    __shared__ float W[16 * 128];
    __shared__ float bond[8 * 128];
    __shared__ float mb[128];
    for (int i = threadIdx.x; i < 16 * 128; i += 256) W[i] = meta_W[i];
    for (int i = threadIdx.x; i < 8 * 128; i += 256) bond[i] = bond_emb[i];
    if (threadIdx.x < 128) mb[threadIdx.x] = meta_b[threadIdx.x];
    __syncthreads();

    int l = threadIdx.x & 63;
    int j0 = l * 2;
    int wv = __builtin_amdgcn_readfirstlane(threadIdx.x >> 6);  // wave id in block (SGPR)
    int estep = gridDim.x * 4;

    for (int e = blockIdx.x * 4 + wv; e < E; e += estep) {
        int s = src[e], d = dst[e], at = eattr[e];
        int xs = x[s], xd = x[d];
        // metafeat rows: wave-uniform 64B each -> scalar (SMEM) loads
        const float4* ms4 = reinterpret_cast<const float4*>(metafeat + (size_t)s * 16);
        const float4* md4 = reinterpret_cast<const float4*>(metafeat + (size_t)d * 16);
        float mk[16];
#pragma unroll
        for (int q = 0; q < 4; q++) {
            float4 a = ms4[q], b = md4[q];
            mk[q * 4 + 0] = a.x + b.x;
            mk[q * 4 + 1] = a.y + b.y;
            mk[q * 4 + 2] = a.z + b.z;
            mk[q * 4 + 3] = a.w + b.w;
        }
        float2 av = *reinterpret_cast<const float2*>(atom_emb + (size_t)xs * 128 + j0);
        float2 bv = *reinterpret_cast<const float2*>(atom_emb + (size_t)xd * 128 + j0);
        float n0 = av.x + bv.x, n1 = av.y + bv.y;
        float2 mbv = *reinterpret_cast<const float2*>(&mb[j0]);
        float m0 = 2.f * mbv.x, m1 = 2.f * mbv.y;
#pragma unroll
        for (int k = 0; k < 16; k++) {
            float2 wv2 = *reinterpret_cast<const float2*>(&W[k * 128 + j0]);
            m0 = fmaf(mk[k], wv2.x, m0);
            m1 = fmaf(mk[k], wv2.y, m1);
        }
        float2 bo = *reinterpret_cast<const float2*>(&bond[at * 128 + j0]);
        float sc = rsqrtf((float)deg_lg[e] + 1.f);
        float v0 = sc * eluf_fast(bo.x * n0 * m0);
        float v1 = sc * eluf_fast(bo.y * n1 * m1);
        *reinterpret_cast<uint_t*>(u + (size_t)e * 128 + j0) = packbf(v0, v1);
    }
}

// v[e] = sc_e*(u[e] + sum u[e']) bf16, chunk [e0,e1) -> vout (row e-e0)
__global__ void k_lg_v(const int* __restrict__ ptr_lg, const int* __restrict__ adj_lg,
                       const int* __restrict__ deg_lg, const uint_t* __restrict__ u32,
                       uint_t* __restrict__ vout, int e0, int e1) {
    int l = threadIdx.x & 63, li = threadIdx.x >> 6;
    int e = e0 + blockIdx.x * 4 + li;
    if (e >= e1) return;
    int p0 = ptr_lg[e], p1 = ptr_lg[e + 1];
    uint_t self = u32[(size_t)e * 64 + l];
    float s0 = bflo(self), s1 = bfhi(self);
    int p = p0;
    for (; p + 4 <= p1; p += 4) {
        int i0 = adj_lg[p], i1 = adj_lg[p + 1], i2 = adj_lg[p + 2], i3 = adj_lg[p + 3];
        uint_t w0 = u32[(size_t)i0 * 64 + l];
        uint_t w1 = u32[(size_t)i1 * 64 + l];
        uint_t w2 = u32[(size_t)i2 * 64 + l];
        uint_t w3 = u32[(size_t)i3 * 64 + l];
        s0 += bflo(w0) + bflo(w1) + bflo(w2) + bflo(w3);
        s1 += bfhi(w0) + bfhi(w1) + bfhi(w2) + bfhi(w3);
    }
    for (; p < p1; p++) {
        uint_t w = u32[(size_t)adj_lg[p] * 64 + l];
        s0 += bflo(w); s1 += bfhi(w);
    }
    float sc = rsqrtf((float)deg_lg[e] + 1.f);
    vout[(size_t)(e - e0) * 64 + l] = packbf(sc * s0, sc * s1);
}

// g0f[n] (+)= sum over incident eids in [e0,e1) of v[eid-e0]; wave-uniform branch
template <int FIRST>
__global__ void k_gate_pass(const int* __restrict__ ptr, const int* __restrict__ eid,
                            const uint_t* __restrict__ v32, float* __restrict__ g0f,
                            int n, int e0, int e1) {
    int l = threadIdx.x & 63, li = threadIdx.x >> 6;
    int node = blockIdx.x * 4 + li;
    if (node >= n) return;
    int p0 = ptr[node], p1 = ptr[node + 1];
    float s0 = 0.f, s1 = 0.f;
    for (int p = p0; p < p1; p++) {
        int e = eid[p];
        if (e >= e0 && e < e1) {
            uint_t w = v32[(size_t)(e - e0) * 64 + l];
            s0 += bflo(w); s1 += bfhi(w);
        }
    }
    float2* out = reinterpret_cast<float2*>(g0f + (size_t)node * 128 + l * 2);
    if (FIRST) {
        *out = make_float2(s0, s1);
    } else {
        float2 c = *out;
        *out = make_float2(c.x + s0, c.y + s1);
    }
}

// ---------------- pagerank: ELL, 4 lanes/node ----------------
__global__ void k_pr_init(const int* __restrict__ deg, float* __restrict__ c,
                          float* __restrict__ invdeg, int n, float invN) {
    int i = blockIdx.x * blockDim.x + threadIdx.x;
    if (i < n) {
        float iv = 1.f / fmaxf((float)deg[i], 1.f);
        invdeg[i] = iv;
        c[i] = invN * iv;
    }
}

__global__ void k_ell_build(const int* __restrict__ ptr, const int* __restrict__ nbr,
                            int* __restrict__ ell, int N) {
    int tid = blockIdx.x * blockDim.x + threadIdx.x;
    int node = tid >> 2, t = tid & 3;
    if (node >= N) return;
    int p0 = ptr[node];
    int dg = ptr[node + 1] - p0;
    if (dg > ELL_CAP) dg = ELL_CAP;
    int stride = N * 4;
    for (int k = 0; 4 * k + t < dg; k++)
        ell[k * stride + tid] = nbr[p0 + 4 * k + t];
}

__global__ void k_pr_ell(const int* __restrict__ ell, const int* __restrict__ ptr,
                         const int* __restrict__ nbr, const float* __restrict__ invdeg,
                         const float* __restrict__ cin, float* __restrict__ cout,
                         int N, float base, float damp) {
    int tid = blockIdx.x * blockDim.x + threadIdx.x;
    int node = tid >> 2, t = tid & 3;
    if (node >= N) return;
    int p0 = ptr[node], p1 = ptr[node + 1];
    int dg = p1 - p0;
    int dgc = dg > ELL_CAP ? ELL_CAP : dg;
    int stride = N * 4;
    float s = 0.f;
    for (int k = 0; 4 * k + t < dgc; k++) s += cin[ell[k * stride + tid]];
    for (int p = p0 + ELL_CAP + t; p < p1; p += 4) s += cin[nbr[p]];
    s += __shfl_xor(s, 1);
    s += __shfl_xor(s, 2);
    if (t == 0) cout[node] = (base + damp * s) * invdeg[node];
}

// ---------------- pooling + heads ----------------
__global__ void k_pool(const float* __restrict__ out_meta, const float* __restrict__ out_org,
                       float* __restrict__ partial, int n) {
    int tid = threadIdx.x;
    const float* basep = (tid < 128) ? out_meta : out_org;
    int dim = tid & 127;
    float acc = 0.f;
    for (int i = blockIdx.x; i < n; i += gridDim.x) acc += basep[(size_t)i * 128 + dim];
    partial[blockIdx.x * 256 + tid] = acc;
}

__global__ void k_final(const float* __restrict__ partial, int nblocks,
                        const float* __restrict__ cat2_W, const float* __restrict__ cat2_b,
                        const float* __restrict__ pred_W, const float* __restrict__ pred_b,
                        float* __restrict__ out) {
    __shared__ float z[256];
    __shared__ float Z[128];
    int tid = threadIdx.x;
    float acc = 0.f;
    for (int p = 0; p < nblocks; p++) acc += partial[p * 256 + tid];
    z[tid] = acc;
    __syncthreads();
    if (tid < 128) {
        float s = cat2_b[tid];
        for (int k = 0; k < 256; k++) s = fmaf(z[k], cat2_W[k * 128 + tid], s);
        Z[tid] = s;
    }
    __syncthreads();
    if (tid < 12) {
        float s = pred_b[tid];
        for (int k = 0; k < 128; k++) s = fmaf(Z[k], pred_W[k * 12 + tid], s);
        out[tid] = s;
    }
}

// ---------------------------------------------------------------------------
extern "C" void kernel_launch(void* const* d_in, const int* in_sizes, int n_in,
                              void* d_out, int out_size, void* d_ws, size_t ws_size,
                              hipStream_t stream) {
    const int* x            = (const int*)d_in[0];
    const float* metafeat   = (const float*)d_in[1];
    const int* edge_attr    = (const int*)d_in[2];
    const int* edge_index   = (const int*)d_in[3];
    const int* lg_edge_index= (const int*)d_in[4];
    const float* atom_emb   = (const float*)d_in[5];
    const float* bond_emb   = (const float*)d_in[6];
    const float* meta_W     = (const float*)d_in[7];
    const float* meta_b     = (const float*)d_in[8];
    const float* org_W      = (const float*)d_in[9];
    const float* org_b      = (const float*)d_in[10];
    const float* org1_W     = (const float*)d_in[11];
    const float* org1_b     = (const float*)d_in[12];
    const float* mconv_W    = (const float*)d_in[13];
    const float* mconv_b    = (const float*)d_in[14];
    const float* mconv1_W   = (const float*)d_in[15];
    const float* mconv1_b   = (const float*)d_in[16];
    const float* lg_W       = (const float*)d_in[17];
    const float* lg_b       = (const float*)d_in[18];
    const float* cat2_W     = (const float*)d_in[21];
    const float* cat2_b     = (const float*)d_in[22];
    const float* pred_W     = (const float*)d_in[23];
    const float* pred_b     = (const float*)d_in[24];

    const int N = in_sizes[0];
    const int E = in_sizes[2];
    const int ELG = in_sizes[4] / 2;
    const int* src = edge_index;
    const int* dst = edge_index + E;
    const int* ls = lg_edge_index;
    const int* ld = lg_edge_index + ELG;

    // ---- workspace carve (~193 MB, proven R6 footprint) ----
    char* w = (char*)d_ws;
    auto alloc = [&](size_t bytes) -> void* {
        void* p = (void*)w;
        w += (bytes + 255) & ~(size_t)255;
        return p;
    };
    int* deg_n   = (int*)alloc((size_t)N * 4);
    int* ptr_n   = (int*)alloc((size_t)(N + 1) * 4);
    int* cur_n   = (int*)alloc((size_t)N * 4);
    int* adj_nbr = (int*)alloc((size_t)2 * E * 4);
    int* adj_eid = (int*)alloc((size_t)2 * E * 4);
    int* deg_lg  = (int*)alloc((size_t)E * 4);
    int* ptr_lg  = (int*)alloc((size_t)(E + 1) * 4);
    int* cur_lg  = (int*)alloc((size_t)E * 4);
    int* adj_lg  = (int*)alloc((size_t)2 * ELG * 4);
    int* bsum    = (int*)alloc((size_t)SCAN_NB * 4);
    float* c_a   = (float*)alloc((size_t)N * 4);
    float* c_b   = (float*)alloc((size_t)N * 4);
    float* invdg = (float*)alloc((size_t)N * 4);
    float* partial = (float*)alloc((size_t)POOL_BLOCKS * 256 * 4);
    uint_t* gateA = (uint_t*)alloc((size_t)N * 64 * 4);   // bf16: gate_n then gate_l
    float* g0f   = (float*)alloc((size_t)N * 128 * 4);    // fp32 gate accumulator
    uint_t* h_orgb  = (uint_t*)alloc((size_t)N * 64 * 4); // bf16
    uint_t* h_metab = (uint_t*)alloc((size_t)N * 64 * 4); // bf16
    size_t nodeB = (size_t)N * 64;                         // uints per bf16 node array
    size_t u_bytes = (size_t)E * 64 * 4;                   // E x 128 bf16
    size_t reg_bytes = 4 * nodeB * 4;
    uint_t* reg = (uint_t*)alloc(reg_bytes > u_bytes ? reg_bytes : u_bytes);
    uint_t* nf0b = reg;
    uint_t* mf0b = reg + nodeB;
    uint_t* m01  = reg + 2 * nodeB;  // interleaved m0/m1, pitch 128 uints/node
    ushort_t* u  = (ushort_t*)reg;   // overlays nf0b..m01 (all dead by then)
    int* ell     = (int*)reg;        // overlays nf0b quarter after u dies
    (void)n_in; (void)ws_size;

    float* out_pred = (float*)d_out;
    float* out_meta = out_pred + 12;
    float* out_org  = out_pred + 12 + (size_t)N * 128;
    // d_out doubles as the v-chunk scratch during the lg path (dead until agg_hat)
    uint_t* vhalf = (uint_t*)d_out;   // capacity: out_size*4 >= (E/2)*256 bytes
    (void)out_size;

    // ---- CSR build ----
    hipMemsetAsync(deg_n, 0, (size_t)N * 4, stream);
    hipMemsetAsync(deg_lg, 0, (size_t)E * 4, stream);
    k_count<<<(E + 255) / 256, 256, 0, stream>>>(src, dst, E, deg_n);
    {
        int C = (N + SCAN_NB - 1) / SCAN_NB;
        k_scan1<<<SCAN_NB, 256, 0, stream>>>(deg_n, N, C, bsum);
        k_scan2<<<1, 256, 0, stream>>>(bsum, SCAN_NB, ptr_n + N);
        k_scan3<<<SCAN_NB, 256, 0, stream>>>(deg_n, bsum, N, C, ptr_n, cur_n);
    }
    {
        int rngN = (N + FILL_NR - 1) / FILL_NR;
        int nchunkN = 96;
        k_fill_part<1><<<FILL_NR * nchunkN, 256, 0, stream>>>(src, dst, E, cur_n,
                                                              adj_nbr, adj_eid, rngN, nchunkN);
    }
    k_count<<<(ELG + 255) / 256, 256, 0, stream>>>(ls, ld, ELG, deg_lg);
    {
        int C = (E + SCAN_NB - 1) / SCAN_NB;
        k_scan1<<<SCAN_NB, 256, 0, stream>>>(deg_lg, E, C, bsum);
        k_scan2<<<1, 256, 0, stream>>>(bsum, SCAN_NB, ptr_lg + E);
        k_scan3<<<SCAN_NB, 256, 0, stream>>>(deg_lg, bsum, E, C, ptr_lg, cur_lg);
    }
    {
        int rngE = (E + FILL_NR - 1) / FILL_NR;
        int nchunkE = 192;
        k_fill_part<0><<<FILL_NR * nchunkE, 256, 0, stream>>>(ls, ld, ELG, cur_lg,
                                                              adj_lg, nullptr, rngE, nchunkE);
    }

    // ---- encoders + gate_n (bf16) ----
    k_encoder<<<(N * 64 + 255) / 256, 256, 0, stream>>>(x, metafeat, atom_emb, meta_W, meta_b,
                                                        nf0b, mf0b, N);
    k_gate_node<<<(N + 3) / 4, 256, 0, stream>>>(ptr_n, adj_eid, edge_attr, bond_emb, gateA, N);

    const int gb64 = (N + 63) / 64;

    // ---- GCN layer 1 (bf16 in, interleaved bf16 out; org+meta batched) ----
    k_gemm64<1, 0, 1, 1, 1, 1><<<2 * gb64, 256, 0, stream>>>(
        nf0b, gateA, org_W, nullptr, deg_n, m01 + 0,
        mf0b, mconv_W, m01 + 2, gb64, N);
    k_agg_dual<<<(N + 7) / 8, 256, 0, stream>>>(ptr_n, adj_nbr, m01, org_b, mconv_b,
                                                deg_n, h_orgb, h_metab, N);
    // reg region becomes u (bf16)

    // ---- line-graph path: u -> v (2 chunks via d_out scratch) -> g0f fp32 ----
    k_ef<<<EF_BLOCKS, 256, 0, stream>>>(src, dst, edge_attr, x, metafeat, atom_emb,
                                        bond_emb, meta_W, meta_b, deg_lg, u, E);
    {
        int eh = (E + 1) / 2;
        k_lg_v<<<(eh + 3) / 4, 256, 0, stream>>>(ptr_lg, adj_lg, deg_lg, (const uint_t*)u,
                                                 vhalf, 0, eh);
        k_gate_pass<1><<<(N + 3) / 4, 256, 0, stream>>>(ptr_n, adj_eid, vhalf, g0f, N, 0, eh);
        k_lg_v<<<(E - eh + 3) / 4, 256, 0, stream>>>(ptr_lg, adj_lg, deg_lg, (const uint_t*)u,
                                                     vhalf, eh, E);
        k_gate_pass<0><<<(N + 3) / 4, 256, 0, stream>>>(ptr_n, adj_eid, vhalf, g0f, N, eh, E);
    }
    k_gemm64<0, 1, 0, 1, 0, 0><<<gb64, 256, 0, stream>>>(
        g0f, nullptr, lg_W, lg_b, deg_n, gateA,
        nullptr, nullptr, nullptr, 0, N);   // gate_l bf16

    // ---- GCN layer 2 (gated, bf16 in, interleaved out; org+meta batched) ----
    k_gemm64<1, 0, 1, 1, 1, 1><<<2 * gb64, 256, 0, stream>>>(
        h_orgb, gateA, org1_W, nullptr, deg_n, m01 + 0,
        h_metab, mconv1_W, m01 + 2, gb64, N);
    // u dead; nf0b quarter free -> ELL

    // ---- pagerank: ELL build + PR_ITERS graph-captured launches ----
    float invN = (float)(1.0 / (double)N);
    float base = (float)((1.0 - 0.85) / (double)N);
    k_pr_init<<<(N + 255) / 256, 256, 0, stream>>>(deg_n, c_a, invdg, N, invN);
    int prb = (4 * N + 255) / 256;
    k_ell_build<<<prb, 256, 0, stream>>>(ptr_n, adj_nbr, ell, N);
    float* pin = c_a;
    float* pout = c_b;
    for (int it = 0; it < PR_ITERS; ++it) {
        k_pr_ell<<<prb, 256, 0, stream>>>(ell, ptr_n, adj_nbr, invdg, pin, pout, N,
                                          base, 0.85f);
        float* t = pin; pin = pout; pout = t;
    }

    // ---- final agg + pagerank scale -> d_out (vhalf scratch now dead) ----
    k_agg_hat<<<(N + 7) / 8, 256, 0, stream>>>(ptr_n, adj_nbr, m01, org1_b, mconv1_b,
                                               deg_n, pin, out_meta, out_org, N);
    k_pool<<<POOL_BLOCKS, 256, 0, stream>>>(out_meta, out_org, partial, N);
    k_final<<<1, 256, 0, stream>>>(partial, POOL_BLOCKS, cat2_W, cat2_b, pred_W, pred_b, out_pred);
}

// Round 5
// 1568.575 us; speedup vs baseline: 1.1602x; 1.0391x over previous
//
#include <hip/hip_runtime.h>
#include <hip/hip_bf16.h>
#include <math.h>

// ---------------------------------------------------------------------------
// IMPGNN on MI355X. fp32 accumulate; bf16 storage for streamed/gathered
// intermediates.
// R12 vs R11:
//   - CSR fills replaced by a two-pass BINNED build (k_bin + k_place +
//     k_ovf_fix), for both node and lg graphs. R9/R10 established the
//     direct scatter pays a full 64B line per 4B store (181-209MB writes).
//     Pass 1 bins endpoint pairs into private per-(chunk,bucket) segments
//     (LDS counters, sequential per-segment writes -> lines fill from one
//     CU). Pass 2: one block per bucket scatters into an LDS image of its
//     CSR slice, then streams it out coalesced. Overflow (8-sigma caps)
//     spills to a tiny list fixed after pass 2; LDS-slice overflow (45
//     sigma) falls back to direct scatter. Segments overlay the reg
//     region (dead until encoders). Legacy k_fill_part kept as fallback
//     for out-of-range shapes.
// ---------------------------------------------------------------------------

#define POOL_BLOCKS 400
#define SCAN_NB 256
#define ELL_CAP 64
#define PR_ITERS 32   // even: result ends in c_a
#define EF_BLOCKS 2048
#define FILL_NR 8     // legacy ranges (XCD-affine)
#define OVF_CAP 65536

typedef unsigned short ushort_t;
typedef unsigned int uint_t;

__device__ __forceinline__ float eluf(float x) { return x > 0.f ? x : expm1f(x); }
__device__ __forceinline__ float eluf_fast(float x) { return x > 0.f ? x : __expf(x) - 1.f; }
__device__ __forceinline__ float bf2f(ushort_t v) {
    return __uint_as_float(((unsigned int)v) << 16);
}
__device__ __forceinline__ ushort_t f2bf(float f) {
    unsigned int u = __float_as_uint(f);
    unsigned int lsb = (u >> 16) & 1u;
    u += 0x7fffu + lsb;           // round-to-nearest-even
    return (ushort_t)(u >> 16);
}
__device__ __forceinline__ float bflo(uint_t v) { return __uint_as_float(v << 16); }
__device__ __forceinline__ float bfhi(uint_t v) { return __uint_as_float(v & 0xffff0000u); }
__device__ __forceinline__ uint_t packbf(float a, float b) {
    return (uint_t)f2bf(a) | ((uint_t)f2bf(b) << 16);
}

// ---------------- CSR build ----------------
__global__ void k_count(const int* __restrict__ a, const int* __restrict__ b,
                        int E, int* __restrict__ deg) {
    int e = blockIdx.x * blockDim.x + threadIdx.x;
    if (e < E) {
        int s = __builtin_nontemporal_load(a + e);
        int d = __builtin_nontemporal_load(b + e);
        atomicAdd(&deg[s], 1); atomicAdd(&deg[d], 1);
    }
}

__global__ void k_scan1(const int* __restrict__ deg, int n, int C, int* __restrict__ bsum) {
    __shared__ int red[256];
    int b = blockIdx.x, tid = threadIdx.x;
    int base = b * C, end = min(base + C, n);
    int s = 0;
    for (int i = base + tid; i < end; i += 256) s += deg[i];
    red[tid] = s;
    __syncthreads();
    for (int off = 128; off > 0; off >>= 1) {
        if (tid < off) red[tid] += red[tid + off];
        __syncthreads();
    }
    if (tid == 0) bsum[b] = red[0];
}

__global__ void k_scan2(int* __restrict__ bsum, int NB, int* __restrict__ total_out) {
    __shared__ int s[256];
    int tid = threadIdx.x;
    int v = (tid < NB) ? bsum[tid] : 0;
    s[tid] = v;
    __syncthreads();
    for (int off = 1; off < 256; off <<= 1) {
        int w = (tid >= off) ? s[tid - off] : 0;
        __syncthreads();
        s[tid] += w;
        __syncthreads();
    }
    if (tid < NB) bsum[tid] = s[tid] - v;
    if (tid == 255) *total_out = s[255];
}

__global__ void k_scan3(const int* __restrict__ deg, const int* __restrict__ boff,
                        int n, int C, int* __restrict__ ptr, int* __restrict__ cur) {
    __shared__ int s[256];
    __shared__ int carry;
    int b = blockIdx.x, tid = threadIdx.x;
    int base = b * C, end = min(base + C, n);
    if (tid == 0) carry = boff[b];
    __syncthreads();
    for (int t = base; t < end; t += 256) {
        int i = t + tid;
        int v = (i < end) ? deg[i] : 0;
        s[tid] = v;
        __syncthreads();
        for (int off = 1; off < 256; off <<= 1) {
            int w = (tid >= off) ? s[tid - off] : 0;
            __syncthreads();
            s[tid] += w;
            __syncthreads();
        }
        int p = carry + s[tid] - v;
        if (i < end) { ptr[i] = p; cur[i] = p; }
        __syncthreads();
        if (tid == 0) carry += s[255];
        __syncthreads();
    }
}

// Legacy range-partitioned fill (fallback only; see R9/R10 notes).
template <int WITH_EID>
__global__ void k_fill_part(const int* __restrict__ a, const int* __restrict__ b,
                            int E, int* __restrict__ cur, int* __restrict__ nbr,
                            int* __restrict__ eid, int rngsize, int nchunk) {
    int r = blockIdx.x & (FILL_NR - 1);
    int chunk = blockIdx.x >> 3;
    int lo = r * rngsize, hi = lo + rngsize;
    int per = (E + nchunk - 1) / nchunk;
    int e0 = chunk * per;
    int e1 = min(e0 + per, E);
    for (int e = e0 + threadIdx.x; e < e1; e += blockDim.x) {
        int s = __builtin_nontemporal_load(a + e);
        int d = __builtin_nontemporal_load(b + e);
        if (s >= lo && s < hi) {
            int p = atomicAdd(&cur[s], 1);
            nbr[p] = d;
            if (WITH_EID) eid[p] = e;
        }
        if (d >= lo && d < hi) {
            int p = atomicAdd(&cur[d], 1);
            nbr[p] = s;
            if (WITH_EID) eid[p] = e;
        }
    }
}

// ---- binned CSR build ----
// Pass 1: bin endpoint pairs into private (chunk,bucket) segments.
// NODE=1: pair = {(key<<16)|nbr, eid}. NODE=0 (lg): pair = {key, val}.
template <int NODE>
__global__ __launch_bounds__(256) void k_bin(
    const int* __restrict__ a, const int* __restrict__ b, int ne,
    uint2* __restrict__ seg, int* __restrict__ cnt,
    uint2* __restrict__ ovf, int* __restrict__ ovf_cur,
    int nchunk, int B, int shift, int cap) {
    __shared__ int scnt[512];
    for (int i = threadIdx.x; i < B; i += 256) scnt[i] = 0;
    __syncthreads();
    int c = blockIdx.x;
    int per = (ne + nchunk - 1) / nchunk;
    int e0 = c * per, e1 = min(e0 + per, ne);
    uint2* segc = seg + (size_t)c * B * cap;
    for (int e = e0 + threadIdx.x; e < e1; e += 256) {
        int s = __builtin_nontemporal_load(a + e);
        int d = __builtin_nontemporal_load(b + e);
#pragma unroll
        for (int h = 0; h < 2; h++) {
            int key = h ? d : s;
            int oth = h ? s : d;
            int bkt = key >> shift;
            int pos = atomicAdd(&scnt[bkt], 1);
            uint2 pr;
            if (NODE) { pr.x = ((uint_t)key << 16) | (uint_t)oth; pr.y = (uint_t)e; }
            else      { pr.x = (uint_t)key; pr.y = (uint_t)oth; }
            if (pos < cap) segc[(size_t)bkt * cap + pos] = pr;
            else { int q = atomicAdd(ovf_cur, 1); if (q < OVF_CAP) ovf[q] = pr; }
        }
    }
    __syncthreads();
    for (int i = threadIdx.x; i < B; i += 256) cnt[c * B + i] = min(scnt[i], cap);
}

// Pass 2: one block per bucket; scatter into LDS image of the CSR slice,
// then stream it out coalesced. Writes cur[] (absolute next-slot) for the
// overflow cleanup. Fallback to direct scatter if slice exceeds LDS cap.
template <int NODE>
__global__ __launch_bounds__(256) void k_place(
    const uint2* __restrict__ seg, const int* __restrict__ cnt,
    const int* __restrict__ ptr, int* __restrict__ nbr, int* __restrict__ eid,
    int* __restrict__ cur, int nchunk, int B, int shift, int cap, int ntgt) {
    __shared__ int cur_l[1024];
    __shared__ uint2 obuf2[6144];
    int* obuf = (int*)obuf2;
    const int CAPLEN = NODE ? 6144 : 12288;
    int bkt = blockIdx.x;
    int lo = bkt << shift;
    int hi = min(ntgt, lo + (1 << shift));
    int base = ptr[lo];
    int len = ptr[hi] - base;
    int tid = threadIdx.x;
    if (len <= CAPLEN) {
        for (int t = lo + tid; t < hi; t += 256) cur_l[t - lo] = ptr[t] - base;
        __syncthreads();
        int wv = tid >> 6, ln = tid & 63;
        for (int c = wv; c < nchunk; c += 4) {
            int n = cnt[c * B + bkt];
            const uint2* sp = seg + ((size_t)c * B + bkt) * cap;
            for (int i = ln; i < n; i += 64) {
                uint2 pr = sp[i];
                int key, val;
                if (NODE) { key = (int)(pr.x >> 16); val = (int)(pr.x & 0xffffu); }
                else      { key = (int)pr.x; val = (int)pr.y; }
                int slot = atomicAdd(&cur_l[key - lo], 1);
                if (NODE) obuf2[slot] = make_uint2((uint_t)val, pr.y);
                else obuf[slot] = val;
            }
        }
        __syncthreads();
        if (NODE) {
            for (int i = tid; i < len; i += 256) {
                uint2 v = obuf2[i];
                nbr[base + i] = (int)v.x;
                eid[base + i] = (int)v.y;
            }
        } else {
            for (int i = tid; i < len; i += 256) nbr[base + i] = obuf[i];
        }
        for (int t = lo + tid; t < hi; t += 256) cur[t] = base + cur_l[t - lo];
    } else {
        for (int t = lo + tid; t < hi; t += 256) cur[t] = ptr[t];
        __syncthreads();
        for (int c = 0; c < nchunk; c++) {
            int n = cnt[c * B + bkt];
            const uint2* sp = seg + ((size_t)c * B + bkt) * cap;
            for (int i = tid; i < n; i += 256) {
                uint2 pr = sp[i];
                int key, val;
                if (NODE) { key = (int)(pr.x >> 16); val = (int)(pr.x & 0xffffu); }
                else      { key = (int)pr.x; val = (int)pr.y; }
                int p = atomicAdd(&cur[key], 1);
                nbr[p] = val;
                if (NODE) eid[p] = (int)pr.y;
            }
        }
    }
}

template <int NODE>
__global__ void k_ovf_fix(const uint2* __restrict__ ovf, const int* __restrict__ ovf_cur,
                          int* __restrict__ cur, int* __restrict__ nbr,
                          int* __restrict__ eid) {
    int n = min(*ovf_cur, OVF_CAP);
    for (int i = blockIdx.x * blockDim.x + threadIdx.x; i < n; i += gridDim.x * blockDim.x) {
        uint2 pr = ovf[i];
        int key, val;
        if (NODE) { key = (int)(pr.x >> 16); val = (int)(pr.x & 0xffffu); }
        else      { key = (int)pr.x; val = (int)pr.y; }
        int p = atomicAdd(&cur[key], 1);
        nbr[p] = val;
        if (NODE) eid[p] = (int)pr.y;
    }
}

// ---------------- encoders (bf16 out) ----------------
__global__ void k_encoder(const int* __restrict__ x, const float* __restrict__ metafeat,
                          const float* __restrict__ atom_emb, const float* __restrict__ meta_W,
                          const float* __restrict__ meta_b, uint_t* __restrict__ nf0,
                          uint_t* __restrict__ mf0, int N) {
    __shared__ float W[16 * 128];
    __shared__ float bsh[128];
    for (int i = threadIdx.x; i < 16 * 128; i += blockDim.x) W[i] = meta_W[i];
    if (threadIdx.x < 128) bsh[threadIdx.x] = meta_b[threadIdx.x];
    __syncthreads();
    int idx = blockIdx.x * blockDim.x + threadIdx.x;
    if (idx < N * 64) {
        int i = idx >> 6, j2 = idx & 63;
        float2 av = *reinterpret_cast<const float2*>(atom_emb + (size_t)x[i] * 128 + j2 * 2);
        nf0[idx] = packbf(av.x, av.y);
        const float* mrow = metafeat + (size_t)i * 16;
        float a0 = bsh[j2 * 2], a1 = bsh[j2 * 2 + 1];
#pragma unroll
        for (int k = 0; k < 16; k++) {
            float m = mrow[k];
            a0 = fmaf(m, W[k * 128 + j2 * 2], a0);
            a1 = fmaf(m, W[k * 128 + j2 * 2 + 1], a1);
        }
        mf0[idx] = packbf(a0, a1);
    }
}

__global__ void k_gate_node(const int* __restrict__ ptr, const int* __restrict__ eid_arr,
                            const int* __restrict__ edge_attr, const float* __restrict__ bond_emb,
                            uint_t* __restrict__ gate, int N) {
    __shared__ float bond[8 * 128];
    for (int i = threadIdx.x; i < 8 * 128; i += blockDim.x) bond[i] = bond_emb[i];
    __syncthreads();
    int l = threadIdx.x & 63, li = threadIdx.x >> 6;
    int node = blockIdx.x * 4 + li;
    if (node >= N) return;
    int p0 = ptr[node], p1 = ptr[node + 1];
    float g0 = 0.f, g1 = 0.f;
    for (int p = p0; p < p1; p++) {
        int a = edge_attr[eid_arr[p]];
        float2 bv = *reinterpret_cast<const float2*>(&bond[a * 128 + l * 2]);
        g0 += bv.x; g1 += bv.y;
    }
    gate[(size_t)node * 64 + l] = packbf(g0, g1);
}

// ---------------- GEMM (64-row tile, optional 2-batch) ----------------
// GATED: A = elu(X*G). IBF16: X packed bf16 pitch 64 (G always bf16 pitch 64).
// EPI 0: out = rsqrt(deg+1)*acc   EPI 1: out = acc + deg*bias
// OBF16: bf16 out. OILV: interleaved m01 layout (pitch 128 uints).
// BATCH: blocks >= gb handle (Xv2, W2, outv2) with the SAME gate/deg.
template <int GATED, int EPI, int IBF16, int OBF16, int OILV, int BATCH>
__global__ __launch_bounds__(256, 4) void k_gemm64(
    const void* __restrict__ Xv, const void* __restrict__ Gv,
    const float* __restrict__ W, const float* __restrict__ bias,
    const int* __restrict__ deg, void* __restrict__ outv,
    const void* __restrict__ Xv2, const float* __restrict__ W2,
    void* __restrict__ outv2, int gb, int M) {
    __shared__ float As[64][33];
    __shared__ float Bs[32][128];
    int tid = threadIdx.x;
    int tx = tid & 15, ty = tid >> 4;

    int bid = blockIdx.x;
    const void* Xp = Xv;
    const float* Wp = W;
    void* outp = outv;
    if (BATCH && bid >= gb) { bid -= gb; Xp = Xv2; Wp = W2; outp = outv2; }
    int row0 = bid * 64;

    float acc[4][8];
#pragma unroll
    for (int i = 0; i < 4; i++)
#pragma unroll
        for (int j = 0; j < 8; j++) acc[i][j] = 0.f;

    for (int h = 0; h < 4; h++) {
#pragma unroll
        for (int p = 0; p < 4; p++) {
            int idx = p * 256 + tid;
            int kk = idx >> 5, cg = idx & 31;
            float4 w = *reinterpret_cast<const float4*>(Wp + (h * 32 + kk) * 128 + cg * 4);
            *reinterpret_cast<float4*>(&Bs[kk][cg * 4]) = w;
        }
        int kg = tid & 7, rr = tid >> 3;
#pragma unroll
        for (int p = 0; p < 2; p++) {
            int r = p * 32 + rr;
            int grow = row0 + r;
            float4 av;
            if (grow < M) {
                float x0, x1, x2, x3;
                if (IBF16) {
                    const uint_t* Xb = (const uint_t*)Xp;
                    uint2 xu = *reinterpret_cast<const uint2*>(
                        Xb + (size_t)grow * 64 + h * 16 + kg * 2);
                    x0 = bflo(xu.x); x1 = bfhi(xu.x); x2 = bflo(xu.y); x3 = bfhi(xu.y);
                } else {
                    const float* Xf = (const float*)Xp;
                    float4 xv = *reinterpret_cast<const float4*>(
                        Xf + (size_t)grow * 128 + h * 32 + kg * 4);
                    x0 = xv.x; x1 = xv.y; x2 = xv.z; x3 = xv.w;
                }
                if (GATED) {
                    const uint_t* Gb = (const uint_t*)Gv;
                    uint2 gu = *reinterpret_cast<const uint2*>(
                        Gb + (size_t)grow * 64 + h * 16 + kg * 2);
                    av.x = eluf(x0 * bflo(gu.x)); av.y = eluf(x1 * bfhi(gu.x));
                    av.z = eluf(x2 * bflo(gu.y)); av.w = eluf(x3 * bfhi(gu.y));
                } else {
                    av = make_float4(x0, x1, x2, x3);
                }
            } else av = make_float4(0.f, 0.f, 0.f, 0.f);
            As[r][kg * 4 + 0] = av.x; As[r][kg * 4 + 1] = av.y;
            As[r][kg * 4 + 2] = av.z; As[r][kg * 4 + 3] = av.w;
        }
        __syncthreads();
#pragma unroll 8
        for (int k = 0; k < 32; k++) {
            float a[4], b[8];
#pragma unroll
            for (int i = 0; i < 4; i++) a[i] = As[ty * 4 + i][k];
            float4 b0 = *reinterpret_cast<const float4*>(&Bs[k][tx * 4]);
            float4 b1 = *reinterpret_cast<const float4*>(&Bs[k][64 + tx * 4]);
            b[0] = b0.x; b[1] = b0.y; b[2] = b0.z; b[3] = b0.w;
            b[4] = b1.x; b[5] = b1.y; b[6] = b1.z; b[7] = b1.w;
#pragma unroll
            for (int i = 0; i < 4; i++)
#pragma unroll
                for (int j = 0; j < 8; j++) acc[i][j] = fmaf(a[i], b[j], acc[i][j]);
        }
        __syncthreads();
    }
#pragma unroll
    for (int i = 0; i < 4; i++) {
        int r = row0 + ty * 4 + i;
        if (r < M) {
            float o[8];
            if (EPI == 0) {
                float sc = rsqrtf((float)deg[r] + 1.0f);
#pragma unroll
                for (int j = 0; j < 8; j++) o[j] = acc[i][j] * sc;
            } else {
                float dg = (float)deg[r];
                float4 ba = *reinterpret_cast<const float4*>(bias + tx * 4);
                float4 bb = *reinterpret_cast<const float4*>(bias + 64 + tx * 4);
                o[0] = acc[i][0] + dg * ba.x; o[1] = acc[i][1] + dg * ba.y;
                o[2] = acc[i][2] + dg * ba.z; o[3] = acc[i][3] + dg * ba.w;
                o[4] = acc[i][4] + dg * bb.x; o[5] = acc[i][5] + dg * bb.y;
                o[6] = acc[i][6] + dg * bb.z; o[7] = acc[i][7] + dg * bb.w;
            }
            if (OBF16) {
                uint_t* ob = (uint_t*)outp;
                uint2 q0, q1;
                q0.x = packbf(o[0], o[1]); q0.y = packbf(o[2], o[3]);
                q1.x = packbf(o[4], o[5]); q1.y = packbf(o[6], o[7]);
                if (OILV) {
                    *reinterpret_cast<uint2*>(ob + (size_t)r * 128 + tx * 4) = q0;
                    *reinterpret_cast<uint2*>(ob + (size_t)r * 128 + 64 + tx * 4) = q1;
                } else {
                    *reinterpret_cast<uint2*>(ob + (size_t)r * 64 + tx * 2) = q0;
                    *reinterpret_cast<uint2*>(ob + (size_t)r * 64 + 32 + tx * 2) = q1;
                }
            } else {
                float* out = (float*)outp;
                *reinterpret_cast<float4*>(out + (size_t)r * 128 + tx * 4) =
                    make_float4(o[0], o[1], o[2], o[3]);
                *reinterpret_cast<float4*>(out + (size_t)r * 128 + 64 + tx * 4) =
                    make_float4(o[4], o[5], o[6], o[7]);
            }
        }
    }
}

// ---------------- node aggregations on interleaved m01 ----------------
// m01 layout: uint4 at [node*128 + c*4]: .xy = m0 dims 4c..4c+3, .zw = m1 same.
__global__ void k_agg_dual(const int* __restrict__ ptr, const int* __restrict__ nbr,
                           const uint_t* __restrict__ m01,
                           const float* __restrict__ b0, const float* __restrict__ b1,
                           const int* __restrict__ deg, uint_t* __restrict__ h0,
                           uint_t* __restrict__ h1, int n) {
    int c = threadIdx.x & 31, li = threadIdx.x >> 5;
    int node = blockIdx.x * 8 + li;
    if (node >= n) return;
    int p0 = ptr[node], p1 = ptr[node + 1];
    uint4 s = *reinterpret_cast<const uint4*>(m01 + (size_t)node * 128 + c * 4);
    float a00 = bflo(s.x), a01 = bfhi(s.x), a02 = bflo(s.y), a03 = bfhi(s.y);
    float a10 = bflo(s.z), a11 = bfhi(s.z), a12 = bflo(s.w), a13 = bfhi(s.w);
    int p = p0;
    for (; p + 4 <= p1; p += 4) {
        int i0 = nbr[p], i1 = nbr[p + 1], i2 = nbr[p + 2], i3 = nbr[p + 3];
        uint4 v0 = *reinterpret_cast<const uint4*>(m01 + (size_t)i0 * 128 + c * 4);
        uint4 v1 = *reinterpret_cast<const uint4*>(m01 + (size_t)i1 * 128 + c * 4);
        uint4 v2 = *reinterpret_cast<const uint4*>(m01 + (size_t)i2 * 128 + c * 4);
        uint4 v3 = *reinterpret_cast<const uint4*>(m01 + (size_t)i3 * 128 + c * 4);
        a00 += bflo(v0.x) + bflo(v1.x) + bflo(v2.x) + bflo(v3.x);
        a01 += bfhi(v0.x) + bfhi(v1.x) + bfhi(v2.x) + bfhi(v3.x);
        a02 += bflo(v0.y) + bflo(v1.y) + bflo(v2.y) + bflo(v3.y);
        a03 += bfhi(v0.y) + bfhi(v1.y) + bfhi(v2.y) + bfhi(v3.y);
        a10 += bflo(v0.z) + bflo(v1.z) + bflo(v2.z) + bflo(v3.z);
        a11 += bfhi(v0.z) + bfhi(v1.z) + bfhi(v2.z) + bfhi(v3.z);
        a12 += bflo(v0.w) + bflo(v1.w) + bflo(v2.w) + bflo(v3.w);
        a13 += bfhi(v0.w) + bfhi(v1.w) + bfhi(v2.w) + bfhi(v3.w);
    }
    for (; p < p1; p++) {
        uint4 v = *reinterpret_cast<const uint4*>(m01 + (size_t)nbr[p] * 128 + c * 4);
        a00 += bflo(v.x); a01 += bfhi(v.x); a02 += bflo(v.y); a03 += bfhi(v.y);
        a10 += bflo(v.z); a11 += bfhi(v.z); a12 += bflo(v.w); a13 += bfhi(v.w);
    }
    float sc = rsqrtf((float)deg[node] + 1.f);
    float4 bb0 = *reinterpret_cast<const float4*>(b0 + c * 4);
    float4 bb1 = *reinterpret_cast<const float4*>(b1 + c * 4);
    uint2 o0, o1;
    o0.x = packbf(sc * a00 + bb0.x, sc * a01 + bb0.y);
    o0.y = packbf(sc * a02 + bb0.z, sc * a03 + bb0.w);
    o1.x = packbf(sc * a10 + bb1.x, sc * a11 + bb1.y);
    o1.y = packbf(sc * a12 + bb1.z, sc * a13 + bb1.w);
    size_t idx = (size_t)node * 64 + c * 2;
    *reinterpret_cast<uint2*>(h0 + idx) = o0;
    *reinterpret_cast<uint2*>(h1 + idx) = o1;
}

// final agg: m01 slot0 = org (out_org), slot1 = meta (out_meta), + pr scale
__global__ void k_agg_hat(const int* __restrict__ ptr, const int* __restrict__ nbr,
                          const uint_t* __restrict__ m01,
                          const float* __restrict__ b_org, const float* __restrict__ b_meta,
                          const int* __restrict__ deg, const float* __restrict__ c_pr,
                          float* __restrict__ out_meta, float* __restrict__ out_org, int n) {
    int c = threadIdx.x & 31, li = threadIdx.x >> 5;
    int node = blockIdx.x * 8 + li;
    if (node >= n) return;
    int p0 = ptr[node], p1 = ptr[node + 1];
    uint4 s = *reinterpret_cast<const uint4*>(m01 + (size_t)node * 128 + c * 4);
    float a00 = bflo(s.x), a01 = bfhi(s.x), a02 = bflo(s.y), a03 = bfhi(s.y);
    float a10 = bflo(s.z), a11 = bfhi(s.z), a12 = bflo(s.w), a13 = bfhi(s.w);
    int p = p0;
    for (; p + 4 <= p1; p += 4) {
        int i0 = nbr[p], i1 = nbr[p + 1], i2 = nbr[p + 2], i3 = nbr[p + 3];
        uint4 v0 = *reinterpret_cast<const uint4*>(m01 + (size_t)i0 * 128 + c * 4);
        uint4 v1 = *reinterpret_cast<const uint4*>(m01 + (size_t)i1 * 128 + c * 4);
        uint4 v2 = *reinterpret_cast<const uint4*>(m01 + (size_t)i2 * 128 + c * 4);
        uint4 v3 = *reinterpret_cast<const uint4*>(m01 + (size_t)i3 * 128 + c * 4);
        a00 += bflo(v0.x) + bflo(v1.x) + bflo(v2.x) + bflo(v3.x);
        a01 += bfhi(v0.x) + bfhi(v1.x) + bfhi(v2.x) + bfhi(v3.x);
        a02 += bflo(v0.y) + bflo(v1.y) + bflo(v2.y) + bflo(v3.y);
        a03 += bfhi(v0.y) + bfhi(v1.y) + bfhi(v2.y) + bfhi(v3.y);
        a10 += bflo(v0.z) + bflo(v1.z) + bflo(v2.z) + bflo(v3.z);
        a11 += bfhi(v0.z) + bfhi(v1.z) + bfhi(v2.z) + bfhi(v3.z);
        a12 += bflo(v0.w) + bflo(v1.w) + bflo(v2.w) + bflo(v3.w);
        a13 += bfhi(v0.w) + bfhi(v1.w) + bfhi(v2.w) + bfhi(v3.w);
    }
    for (; p < p1; p++) {
        uint4 v = *reinterpret_cast<const uint4*>(m01 + (size_t)nbr[p] * 128 + c * 4);
        a00 += bflo(v.x); a01 += bfhi(v.x); a02 += bflo(v.y); a03 += bfhi(v.y);
        a10 += bflo(v.z); a11 += bfhi(v.z); a12 += bflo(v.w); a13 += bfhi(v.w);
    }
    int dg = deg[node];
    float sc = rsqrtf((float)dg + 1.f);
    float pr = c_pr[node] * fmaxf((float)dg, 1.f);
    float4 bo = *reinterpret_cast<const float4*>(b_org + c * 4);
    float4 bm = *reinterpret_cast<const float4*>(b_meta + c * 4);
    size_t o = (size_t)node * 128 + c * 4;
    *reinterpret_cast<float4*>(out_org + o) =
        make_float4((sc * a00 + bo.x) * pr, (sc * a01 + bo.y) * pr,
                    (sc * a02 + bo.z) * pr, (sc * a03 + bo.w) * pr);
    *reinterpret_cast<float4*>(out_meta + o) =
        make_float4((sc * a10 + bm.x) * pr, (sc * a11 + bm.y) * pr,
                    (sc * a12 + bm.z) * pr, (sc * a13 + bm.w) * pr);
}

// ---------------- line-graph path ----------------
// Grid-stride, one wave per edge. e is wave-uniform -> src/dst/eattr/
// deg_lg and the two 64B metafeat rows become scalar loads, done once per
// wave instead of once per lane. Each lane produces 2 output columns.
__global__ __launch_bounds__(256) void k_ef(
    const int* __restrict__ src, const int* __restrict__ dst,
    const int* __restrict__ eattr, const int* __restrict__ x,
    const float* __restrict__ metafeat, const float* __restrict__ atom_emb,
    const float* __restrict__ bond_emb, const float* __restrict__ meta_W,
    const float* __restrict__ meta_b, const int* __restrict__ deg_lg,
    ushort_t* __restrict__ u, int E) {
    __shared__ float W[16 * 128];
    __shared__ float bond[8 * 128];
    __shared__ float mb[128];
    for (int i = threadIdx.x; i < 16 * 128; i += 256) W[i] = meta_W[i];
    for (int i = threadIdx.x; i < 8 * 128; i += 256) bond[i] = bond_emb[i];
    if (threadIdx.x < 128) mb[threadIdx.x] = meta_b[threadIdx.x];
    __syncthreads();

    int l = threadIdx.x & 63;
    int j0 = l * 2;
    int wv = __builtin_amdgcn_readfirstlane(threadIdx.x >> 6);  // wave id in block (SGPR)
    int estep = gridDim.x * 4;

    for (int e = blockIdx.x * 4 + wv; e < E; e += estep) {
        int s = src[e], d = dst[e], at = eattr[e];
        int xs = x[s], xd = x[d];
        // metafeat rows: wave-uniform 64B each -> scalar (SMEM) loads
        const float4* ms4 = reinterpret_cast<const float4*>(metafeat + (size_t)s * 16);
        const float4* md4 = reinterpret_cast<const float4*>(metafeat + (size_t)d * 16);
        float mk[16];
#pragma unroll
        for (int q = 0; q < 4; q++) {
            float4 a = ms4[q], b = md4[q];
            mk[q * 4 + 0] = a.x + b.x;
            mk[q * 4 + 1] = a.y + b.y;
            mk[q * 4 + 2] = a.z + b.z;
            mk[q * 4 + 3] = a.w + b.w;
        }
        float2 av = *reinterpret_cast<const float2*>(atom_emb + (size_t)xs * 128 + j0);
        float2 bv = *reinterpret_cast<const float2*>(atom_emb + (size_t)xd * 128 + j0);
        float n0 = av.x + bv.x, n1 = av.y + bv.y;
        float2 mbv = *reinterpret_cast<const float2*>(&mb[j0]);
        float m0 = 2.f * mbv.x, m1 = 2.f * mbv.y;
#pragma unroll
        for (int k = 0; k < 16; k++) {
            float2 wv2 = *reinterpret_cast<const float2*>(&W[k * 128 + j0]);
            m0 = fmaf(mk[k], wv2.x, m0);
            m1 = fmaf(mk[k], wv2.y, m1);
        }
        float2 bo = *reinterpret_cast<const float2*>(&bond[at * 128 + j0]);
        float sc = rsqrtf((float)deg_lg[e] + 1.f);
        float v0 = sc * eluf_fast(bo.x * n0 * m0);
        float v1 = sc * eluf_fast(bo.y * n1 * m1);
        *reinterpret_cast<uint_t*>(u + (size_t)e * 128 + j0) = packbf(v0, v1);
    }
}

// v[e] = sc_e*(u[e] + sum u[e']) bf16, chunk [e0,e1) -> vout (row e-e0)
__global__ void k_lg_v(const int* __restrict__ ptr_lg, const int* __restrict__ adj_lg,
                       const int* __restrict__ deg_lg, const uint_t* __restrict__ u32,
                       uint_t* __restrict__ vout, int e0, int e1) {
    int l = threadIdx.x & 63, li = threadIdx.x >> 6;
    int e = e0 + blockIdx.x * 4 + li;
    if (e >= e1) return;
    int p0 = ptr_lg[e], p1 = ptr_lg[e + 1];
    uint_t self = u32[(size_t)e * 64 + l];
    float s0 = bflo(self), s1 = bfhi(self);
    int p = p0;
    for (; p + 4 <= p1; p += 4) {
        int i0 = adj_lg[p], i1 = adj_lg[p + 1], i2 = adj_lg[p + 2], i3 = adj_lg[p + 3];
        uint_t w0 = u32[(size_t)i0 * 64 + l];
        uint_t w1 = u32[(size_t)i1 * 64 + l];
        uint_t w2 = u32[(size_t)i2 * 64 + l];
        uint_t w3 = u32[(size_t)i3 * 64 + l];
        s0 += bflo(w0) + bflo(w1) + bflo(w2) + bflo(w3);
        s1 += bfhi(w0) + bfhi(w1) + bfhi(w2) + bfhi(w3);
    }
    for (; p < p1; p++) {
        uint_t w = u32[(size_t)adj_lg[p] * 64 + l];
        s0 += bflo(w); s1 += bfhi(w);
    }
    float sc = rsqrtf((float)deg_lg[e] + 1.f);
    vout[(size_t)(e - e0) * 64 + l] = packbf(sc * s0, sc * s1);
}

// g0f[n] (+)= sum over incident eids in [e0,e1) of v[eid-e0]; wave-uniform branch
template <int FIRST>
__global__ void k_gate_pass(const int* __restrict__ ptr, const int* __restrict__ eid,
                            const uint_t* __restrict__ v32, float* __restrict__ g0f,
                            int n, int e0, int e1) {
    int l = threadIdx.x & 63, li = threadIdx.x >> 6;
    int node = blockIdx.x * 4 + li;
    if (node >= n) return;
    int p0 = ptr[node], p1 = ptr[node + 1];
    float s0 = 0.f, s1 = 0.f;
    for (int p = p0; p < p1; p++) {
        int e = eid[p];
        if (e >= e0 && e < e1) {
            uint_t w = v32[(size_t)(e - e0) * 64 + l];
            s0 += bflo(w); s1 += bfhi(w);
        }
    }
    float2* out = reinterpret_cast<float2*>(g0f + (size_t)node * 128 + l * 2);
    if (FIRST) {
        *out = make_float2(s0, s1);
    } else {
        float2 c = *out;
        *out = make_float2(c.x + s0, c.y + s1);
    }
}

// ---------------- pagerank: ELL, 4 lanes/node ----------------
__global__ void k_pr_init(const int* __restrict__ deg, float* __restrict__ c,
                          float* __restrict__ invdeg, int n, float invN) {
    int i = blockIdx.x * blockDim.x + threadIdx.x;
    if (i < n) {
        float iv = 1.f / fmaxf((float)deg[i], 1.f);
        invdeg[i] = iv;
        c[i] = invN * iv;
    }
}

__global__ void k_ell_build(const int* __restrict__ ptr, const int* __restrict__ nbr,
                            int* __restrict__ ell, int N) {
    int tid = blockIdx.x * blockDim.x + threadIdx.x;
    int node = tid >> 2, t = tid & 3;
    if (node >= N) return;
    int p0 = ptr[node];
    int dg = ptr[node + 1] - p0;
    if (dg > ELL_CAP) dg = ELL_CAP;
    int stride = N * 4;
    for (int k = 0; 4 * k + t < dg; k++)
        ell[k * stride + tid] = nbr[p0 + 4 * k + t];
}

__global__ void k_pr_ell(const int* __restrict__ ell, const int* __restrict__ ptr,
                         const int* __restrict__ nbr, const float* __restrict__ invdeg,
                         const float* __restrict__ cin, float* __restrict__ cout,
                         int N, float base, float damp) {
    int tid = blockIdx.x * blockDim.x + threadIdx.x;
    int node = tid >> 2, t = tid & 3;
    if (node >= N) return;
    int p0 = ptr[node], p1 = ptr[node + 1];
    int dg = p1 - p0;
    int dgc = dg > ELL_CAP ? ELL_CAP : dg;
    int stride = N * 4;
    float s = 0.f;
    for (int k = 0; 4 * k + t < dgc; k++) s += cin[ell[k * stride + tid]];
    for (int p = p0 + ELL_CAP + t; p < p1; p += 4) s += cin[nbr[p]];
    s += __shfl_xor(s, 1);
    s += __shfl_xor(s, 2);
    if (t == 0) cout[node] = (base + damp * s) * invdeg[node];
}

// ---------------- pooling + heads ----------------
__global__ void k_pool(const float* __restrict__ out_meta, const float* __restrict__ out_org,
                       float* __restrict__ partial, int n) {
    int tid = threadIdx.x;
    const float* basep = (tid < 128) ? out_meta : out_org;
    int dim = tid & 127;
    float acc = 0.f;
    for (int i = blockIdx.x; i < n; i += gridDim.x) acc += basep[(size_t)i * 128 + dim];
    partial[blockIdx.x * 256 + tid] = acc;
}

__global__ void k_final(const float* __restrict__ partial, int nblocks,
                        const float* __restrict__ cat2_W, const float* __restrict__ cat2_b,
                        const float* __restrict__ pred_W, const float* __restrict__ pred_b,
                        float* __restrict__ out) {
    __shared__ float z[256];
    __shared__ float Z[128];
    int tid = threadIdx.x;
    float acc = 0.f;
    for (int p = 0; p < nblocks; p++) acc += partial[p * 256 + tid];
    z[tid] = acc;
    __syncthreads();
    if (tid < 128) {
        float s = cat2_b[tid];
        for (int k = 0; k < 256; k++) s = fmaf(z[k], cat2_W[k * 128 + tid], s);
        Z[tid] = s;
    }
    __syncthreads();
    if (tid < 12) {
        float s = pred_b[tid];
        for (int k = 0; k < 128; k++) s = fmaf(Z[k], pred_W[k * 12 + tid], s);
        out[tid] = s;
    }
}

// ---------------------------------------------------------------------------
extern "C" void kernel_launch(void* const* d_in, const int* in_sizes, int n_in,
                              void* d_out, int out_size, void* d_ws, size_t ws_size,
                              hipStream_t stream) {
    const int* x            = (const int*)d_in[0];
    const float* metafeat   = (const float*)d_in[1];
    const int* edge_attr    = (const int*)d_in[2];
    const int* edge_index   = (const int*)d_in[3];
    const int* lg_edge_index= (const int*)d_in[4];
    const float* atom_emb   = (const float*)d_in[5];
    const float* bond_emb   = (const float*)d_in[6];
    const float* meta_W     = (const float*)d_in[7];
    const float* meta_b     = (const float*)d_in[8];
    const float* org_W      = (const float*)d_in[9];
    const float* org_b      = (const float*)d_in[10];
    const float* org1_W     = (const float*)d_in[11];
    const float* org1_b     = (const float*)d_in[12];
    const float* mconv_W    = (const float*)d_in[13];
    const float* mconv_b    = (const float*)d_in[14];
    const float* mconv1_W   = (const float*)d_in[15];
    const float* mconv1_b   = (const float*)d_in[16];
    const float* lg_W       = (const float*)d_in[17];
    const float* lg_b       = (const float*)d_in[18];
    const float* cat2_W     = (const float*)d_in[21];
    const float* cat2_b     = (const float*)d_in[22];
    const float* pred_W     = (const float*)d_in[23];
    const float* pred_b     = (const float*)d_in[24];

    const int N = in_sizes[0];
    const int E = in_sizes[2];
    const int ELG = in_sizes[4] / 2;
    const int* src = edge_index;
    const int* dst = edge_index + E;
    const int* ls = lg_edge_index;
    const int* ld = lg_edge_index + ELG;

    // ---- workspace carve (~194 MB, proven footprint) ----
    char* w = (char*)d_ws;
    auto alloc = [&](size_t bytes) -> void* {
        void* p = (void*)w;
        w += (bytes + 255) & ~(size_t)255;
        return p;
    };
    int* deg_n   = (int*)alloc((size_t)N * 4);
    int* ptr_n   = (int*)alloc((size_t)(N + 1) * 4);
    int* cur_n   = (int*)alloc((size_t)N * 4);
    int* adj_nbr = (int*)alloc((size_t)2 * E * 4);
    int* adj_eid = (int*)alloc((size_t)2 * E * 4);
    int* deg_lg  = (int*)alloc((size_t)E * 4);
    int* ptr_lg  = (int*)alloc((size_t)(E + 1) * 4);
    int* cur_lg  = (int*)alloc((size_t)E * 4);
    int* adj_lg  = (int*)alloc((size_t)2 * ELG * 4);
    int* bsum    = (int*)alloc((size_t)SCAN_NB * 4);
    float* c_a   = (float*)alloc((size_t)N * 4);
    float* c_b   = (float*)alloc((size_t)N * 4);
    float* invdg = (float*)alloc((size_t)N * 4);
    float* partial = (float*)alloc((size_t)POOL_BLOCKS * 256 * 4);
    uint_t* gateA = (uint_t*)alloc((size_t)N * 64 * 4);   // bf16: gate_n then gate_l
    float* g0f   = (float*)alloc((size_t)N * 128 * 4);    // fp32 gate accumulator
    uint_t* h_orgb  = (uint_t*)alloc((size_t)N * 64 * 4); // bf16
    uint_t* h_metab = (uint_t*)alloc((size_t)N * 64 * 4); // bf16
    size_t nodeB = (size_t)N * 64;                         // uints per bf16 node array
    size_t u_bytes = (size_t)E * 64 * 4;                   // E x 128 bf16
    size_t reg_bytes = 4 * nodeB * 4;
    uint_t* reg = (uint_t*)alloc(reg_bytes > u_bytes ? reg_bytes : u_bytes);
    uint_t* nf0b = reg;
    uint_t* mf0b = reg + nodeB;
    uint_t* m01  = reg + 2 * nodeB;  // interleaved m0/m1, pitch 128 uints/node
    ushort_t* u  = (ushort_t*)reg;   // overlays nf0b..m01 (all dead by then)
    int* ell     = (int*)reg;        // overlays nf0b quarter after u dies
    (void)n_in; (void)ws_size;

    float* out_pred = (float*)d_out;
    float* out_meta = out_pred + 12;
    float* out_org  = out_pred + 12 + (size_t)N * 128;
    // d_out doubles as the v-chunk scratch during the lg path (dead until agg_hat)
    uint_t* vhalf = (uint_t*)d_out;   // capacity: out_size*4 >= (E/2)*256 bytes
    (void)out_size;

    // ---- binned-fill scratch: overlays reg (dead until encoders) ----
    const int SH_N = 8, SH_LG = 10;
    const int NC_N = 128, CAP_N = 80;     // mean pairs/cell ~32, cap ~8.5 sigma
    const int NC_LG = 256, CAP_LG = 80;   // mean pairs/cell ~32, cap ~8.5 sigma
    int B_N  = (N + (1 << SH_N) - 1) >> SH_N;
    int B_LG = (E + (1 << SH_LG) - 1) >> SH_LG;
    bool binOK = (N <= 65535) && (B_N <= 512) && (B_LG <= 512);
    char* rw = (char*)reg;
    auto ralloc = [&](size_t bytes) -> void* {
        void* p = (void*)rw;
        rw += (bytes + 255) & ~(size_t)255;
        return p;
    };
    uint2* seg_lg = (uint2*)ralloc((size_t)NC_LG * B_LG * CAP_LG * 8);
    int*  cnt_lg  = (int*)ralloc((size_t)NC_LG * B_LG * 4);
    uint2* seg_n  = (uint2*)ralloc((size_t)NC_N * B_N * CAP_N * 8);
    int*  cnt_n   = (int*)ralloc((size_t)NC_N * B_N * 4);
    uint2* ovf_lg = (uint2*)ralloc((size_t)OVF_CAP * 8);
    uint2* ovf_n  = (uint2*)ralloc((size_t)OVF_CAP * 8);
    int* ovf_curs = (int*)ralloc(256);

    // ---- CSR build ----
    hipMemsetAsync(deg_n, 0, (size_t)N * 4, stream);
    hipMemsetAsync(deg_lg, 0, (size_t)E * 4, stream);
    if (binOK) hipMemsetAsync(ovf_curs, 0, 8, stream);
    k_count<<<(E + 255) / 256, 256, 0, stream>>>(src, dst, E, deg_n);
    {
        int C = (N + SCAN_NB - 1) / SCAN_NB;
        k_scan1<<<SCAN_NB, 256, 0, stream>>>(deg_n, N, C, bsum);
        k_scan2<<<1, 256, 0, stream>>>(bsum, SCAN_NB, ptr_n + N);
        k_scan3<<<SCAN_NB, 256, 0, stream>>>(deg_n, bsum, N, C, ptr_n, cur_n);
    }
    if (binOK) {
        k_bin<1><<<NC_N, 256, 0, stream>>>(src, dst, E, seg_n, cnt_n, ovf_n,
                                           ovf_curs + 0, NC_N, B_N, SH_N, CAP_N);
        k_place<1><<<B_N, 256, 0, stream>>>(seg_n, cnt_n, ptr_n, adj_nbr, adj_eid,
                                            cur_n, NC_N, B_N, SH_N, CAP_N, N);
        k_ovf_fix<1><<<16, 256, 0, stream>>>(ovf_n, ovf_curs + 0, cur_n, adj_nbr, adj_eid);
    } else {
        int rngN = (N + FILL_NR - 1) / FILL_NR;
        k_fill_part<1><<<FILL_NR * 96, 256, 0, stream>>>(src, dst, E, cur_n,
                                                         adj_nbr, adj_eid, rngN, 96);
    }
    k_count<<<(ELG + 255) / 256, 256, 0, stream>>>(ls, ld, ELG, deg_lg);
    {
        int C = (E + SCAN_NB - 1) / SCAN_NB;
        k_scan1<<<SCAN_NB, 256, 0, stream>>>(deg_lg, E, C, bsum);
        k_scan2<<<1, 256, 0, stream>>>(bsum, SCAN_NB, ptr_lg + E);
        k_scan3<<<SCAN_NB, 256, 0, stream>>>(deg_lg, bsum, E, C, ptr_lg, cur_lg);
    }
    if (binOK) {
        k_bin<0><<<NC_LG, 256, 0, stream>>>(ls, ld, ELG, seg_lg, cnt_lg, ovf_lg,
                                            ovf_curs + 1, NC_LG, B_LG, SH_LG, CAP_LG);
        k_place<0><<<B_LG, 256, 0, stream>>>(seg_lg, cnt_lg, ptr_lg, adj_lg, nullptr,
                                             cur_lg, NC_LG, B_LG, SH_LG, CAP_LG, E);
        k_ovf_fix<0><<<16, 256, 0, stream>>>(ovf_lg, ovf_curs + 1, cur_lg, adj_lg, nullptr);
    } else {
        int rngE = (E + FILL_NR - 1) / FILL_NR;
        k_fill_part<0><<<FILL_NR * 192, 256, 0, stream>>>(ls, ld, ELG, cur_lg,
                                                          adj_lg, nullptr, rngE, 192);
    }

    // ---- encoders + gate_n (bf16) ----
    k_encoder<<<(N * 64 + 255) / 256, 256, 0, stream>>>(x, metafeat, atom_emb, meta_W, meta_b,
                                                        nf0b, mf0b, N);
    k_gate_node<<<(N + 3) / 4, 256, 0, stream>>>(ptr_n, adj_eid, edge_attr, bond_emb, gateA, N);

    const int gb64 = (N + 63) / 64;

    // ---- GCN layer 1 (bf16 in, interleaved bf16 out; org+meta batched) ----
    k_gemm64<1, 0, 1, 1, 1, 1><<<2 * gb64, 256, 0, stream>>>(
        nf0b, gateA, org_W, nullptr, deg_n, m01 + 0,
        mf0b, mconv_W, m01 + 2, gb64, N);
    k_agg_dual<<<(N + 7) / 8, 256, 0, stream>>>(ptr_n, adj_nbr, m01, org_b, mconv_b,
                                                deg_n, h_orgb, h_metab, N);
    // reg region becomes u (bf16)

    // ---- line-graph path: u -> v (2 chunks via d_out scratch) -> g0f fp32 ----
    k_ef<<<EF_BLOCKS, 256, 0, stream>>>(src, dst, edge_attr, x, metafeat, atom_emb,
                                        bond_emb, meta_W, meta_b, deg_lg, u, E);
    {
        int eh = (E + 1) / 2;
        k_lg_v<<<(eh + 3) / 4, 256, 0, stream>>>(ptr_lg, adj_lg, deg_lg, (const uint_t*)u,
                                                 vhalf, 0, eh);
        k_gate_pass<1><<<(N + 3) / 4, 256, 0, stream>>>(ptr_n, adj_eid, vhalf, g0f, N, 0, eh);
        k_lg_v<<<(E - eh + 3) / 4, 256, 0, stream>>>(ptr_lg, adj_lg, deg_lg, (const uint_t*)u,
                                                     vhalf, eh, E);
        k_gate_pass<0><<<(N + 3) / 4, 256, 0, stream>>>(ptr_n, adj_eid, vhalf, g0f, N, eh, E);
    }
    k_gemm64<0, 1, 0, 1, 0, 0><<<gb64, 256, 0, stream>>>(
        g0f, nullptr, lg_W, lg_b, deg_n, gateA,
        nullptr, nullptr, nullptr, 0, N);   // gate_l bf16

    // ---- GCN layer 2 (gated, bf16 in, interleaved out; org+meta batched) ----
    k_gemm64<1, 0, 1, 1, 1, 1><<<2 * gb64, 256, 0, stream>>>(
        h_orgb, gateA, org1_W, nullptr, deg_n, m01 + 0,
        h_metab, mconv1_W, m01 + 2, gb64, N);
    // u dead; nf0b quarter free -> ELL

    // ---- pagerank: ELL build + PR_ITERS graph-captured launches ----
    float invN = (float)(1.0 / (double)N);
    float base = (float)((1.0 - 0.85) / (double)N);
    k_pr_init<<<(N + 255) / 256, 256, 0, stream>>>(deg_n, c_a, invdg, N, invN);
    int prb = (4 * N + 255) / 256;
    k_ell_build<<<prb, 256, 0, stream>>>(ptr_n, adj_nbr, ell, N);
    float* pin = c_a;
    float* pout = c_b;
    for (int it = 0; it < PR_ITERS; ++it) {
        k_pr_ell<<<prb, 256, 0, stream>>>(ell, ptr_n, adj_nbr, invdg, pin, pout, N,
                                          base, 0.85f);
        float* t = pin; pin = pout; pout = t;
    }

    // ---- final agg + pagerank scale -> d_out (vhalf scratch now dead) ----
    k_agg_hat<<<(N + 7) / 8, 256, 0, stream>>>(ptr_n, adj_nbr, m01, org1_b, mconv1_b,
                                               deg_n, pin, out_meta, out_org, N);
    k_pool<<<POOL_BLOCKS, 256, 0, stream>>>(out_meta, out_org, partial, N);
    k_final<<<1, 256, 0, stream>>>(partial, POOL_BLOCKS, cat2_W, cat2_b, pred_W, pred_b, out_pred);
}

// Round 6
// 1459.174 us; speedup vs baseline: 1.2472x; 1.0750x over previous
//
#include <hip/hip_runtime.h>
#include <hip/hip_bf16.h>
#include <math.h>

// ---------------------------------------------------------------------------
// IMPGNN on MI355X. fp32 accumulate; bf16 storage for streamed/gathered
// intermediates.
// R13 vs R12:
//   - k_count (global-atomic histogram; lg instance was 125us with 100MB
//     of atomic-RMW writeback) replaced by binned counting: k_bin now runs
//     FIRST (it never needed deg/ptr), then k_bcount (one block/bucket:
//     LDS histogram of the bucket's segment entries, coalesced deg-slice
//     write, no global atomics, no memset), then k_ovf_count for the
//     (expected-empty) overflow list, then scans + k_place as in R12.
//     Extra cost: one more streaming segment read (~32MB total, ~7us).
//   - PR stays at 32 iters (24 would put ~2% relative error on pr, at the
//     tolerance edge).
// ---------------------------------------------------------------------------

#define POOL_BLOCKS 400
#define SCAN_NB 256
#define ELL_CAP 64
#define PR_ITERS 32   // even: result ends in c_a
#define EF_BLOCKS 2048
#define FILL_NR 8     // legacy ranges (XCD-affine)
#define OVF_CAP 65536

typedef unsigned short ushort_t;
typedef unsigned int uint_t;

__device__ __forceinline__ float eluf(float x) { return x > 0.f ? x : expm1f(x); }
__device__ __forceinline__ float eluf_fast(float x) { return x > 0.f ? x : __expf(x) - 1.f; }
__device__ __forceinline__ float bf2f(ushort_t v) {
    return __uint_as_float(((unsigned int)v) << 16);
}
__device__ __forceinline__ ushort_t f2bf(float f) {
    unsigned int u = __float_as_uint(f);
    unsigned int lsb = (u >> 16) & 1u;
    u += 0x7fffu + lsb;           // round-to-nearest-even
    return (ushort_t)(u >> 16);
}
__device__ __forceinline__ float bflo(uint_t v) { return __uint_as_float(v << 16); }
__device__ __forceinline__ float bfhi(uint_t v) { return __uint_as_float(v & 0xffff0000u); }
__device__ __forceinline__ uint_t packbf(float a, float b) {
    return (uint_t)f2bf(a) | ((uint_t)f2bf(b) << 16);
}

// ---------------- CSR build ----------------
// Legacy global-atomic count (fallback only).
__global__ void k_count(const int* __restrict__ a, const int* __restrict__ b,
                        int E, int* __restrict__ deg) {
    int e = blockIdx.x * blockDim.x + threadIdx.x;
    if (e < E) {
        int s = __builtin_nontemporal_load(a + e);
        int d = __builtin_nontemporal_load(b + e);
        atomicAdd(&deg[s], 1); atomicAdd(&deg[d], 1);
    }
}

__global__ void k_scan1(const int* __restrict__ deg, int n, int C, int* __restrict__ bsum) {
    __shared__ int red[256];
    int b = blockIdx.x, tid = threadIdx.x;
    int base = b * C, end = min(base + C, n);
    int s = 0;
    for (int i = base + tid; i < end; i += 256) s += deg[i];
    red[tid] = s;
    __syncthreads();
    for (int off = 128; off > 0; off >>= 1) {
        if (tid < off) red[tid] += red[tid + off];
        __syncthreads();
    }
    if (tid == 0) bsum[b] = red[0];
}

__global__ void k_scan2(int* __restrict__ bsum, int NB, int* __restrict__ total_out) {
    __shared__ int s[256];
    int tid = threadIdx.x;
    int v = (tid < NB) ? bsum[tid] : 0;
    s[tid] = v;
    __syncthreads();
    for (int off = 1; off < 256; off <<= 1) {
        int w = (tid >= off) ? s[tid - off] : 0;
        __syncthreads();
        s[tid] += w;
        __syncthreads();
    }
    if (tid < NB) bsum[tid] = s[tid] - v;
    if (tid == 255) *total_out = s[255];
}

__global__ void k_scan3(const int* __restrict__ deg, const int* __restrict__ boff,
                        int n, int C, int* __restrict__ ptr, int* __restrict__ cur) {
    __shared__ int s[256];
    __shared__ int carry;
    int b = blockIdx.x, tid = threadIdx.x;
    int base = b * C, end = min(base + C, n);
    if (tid == 0) carry = boff[b];
    __syncthreads();
    for (int t = base; t < end; t += 256) {
        int i = t + tid;
        int v = (i < end) ? deg[i] : 0;
        s[tid] = v;
        __syncthreads();
        for (int off = 1; off < 256; off <<= 1) {
            int w = (tid >= off) ? s[tid - off] : 0;
            __syncthreads();
            s[tid] += w;
            __syncthreads();
        }
        int p = carry + s[tid] - v;
        if (i < end) { ptr[i] = p; cur[i] = p; }
        __syncthreads();
        if (tid == 0) carry += s[255];
        __syncthreads();
    }
}

// Legacy range-partitioned fill (fallback only; see R9/R10 notes).
template <int WITH_EID>
__global__ void k_fill_part(const int* __restrict__ a, const int* __restrict__ b,
                            int E, int* __restrict__ cur, int* __restrict__ nbr,
                            int* __restrict__ eid, int rngsize, int nchunk) {
    int r = blockIdx.x & (FILL_NR - 1);
    int chunk = blockIdx.x >> 3;
    int lo = r * rngsize, hi = lo + rngsize;
    int per = (E + nchunk - 1) / nchunk;
    int e0 = chunk * per;
    int e1 = min(e0 + per, E);
    for (int e = e0 + threadIdx.x; e < e1; e += blockDim.x) {
        int s = __builtin_nontemporal_load(a + e);
        int d = __builtin_nontemporal_load(b + e);
        if (s >= lo && s < hi) {
            int p = atomicAdd(&cur[s], 1);
            nbr[p] = d;
            if (WITH_EID) eid[p] = e;
        }
        if (d >= lo && d < hi) {
            int p = atomicAdd(&cur[d], 1);
            nbr[p] = s;
            if (WITH_EID) eid[p] = e;
        }
    }
}

// ---- binned CSR build ----
// Pass 1: bin endpoint pairs into private (chunk,bucket) segments.
// NODE=1: pair = {(key<<16)|nbr, eid}. NODE=0 (lg): pair = {key, val}.
template <int NODE>
__global__ __launch_bounds__(256) void k_bin(
    const int* __restrict__ a, const int* __restrict__ b, int ne,
    uint2* __restrict__ seg, int* __restrict__ cnt,
    uint2* __restrict__ ovf, int* __restrict__ ovf_cur,
    int nchunk, int B, int shift, int cap) {
    __shared__ int scnt[512];
    for (int i = threadIdx.x; i < B; i += 256) scnt[i] = 0;
    __syncthreads();
    int c = blockIdx.x;
    int per = (ne + nchunk - 1) / nchunk;
    int e0 = c * per, e1 = min(e0 + per, ne);
    uint2* segc = seg + (size_t)c * B * cap;
    for (int e = e0 + threadIdx.x; e < e1; e += 256) {
        int s = __builtin_nontemporal_load(a + e);
        int d = __builtin_nontemporal_load(b + e);
#pragma unroll
        for (int h = 0; h < 2; h++) {
            int key = h ? d : s;
            int oth = h ? s : d;
            int bkt = key >> shift;
            int pos = atomicAdd(&scnt[bkt], 1);
            uint2 pr;
            if (NODE) { pr.x = ((uint_t)key << 16) | (uint_t)oth; pr.y = (uint_t)e; }
            else      { pr.x = (uint_t)key; pr.y = (uint_t)oth; }
            if (pos < cap) segc[(size_t)bkt * cap + pos] = pr;
            else { int q = atomicAdd(ovf_cur, 1); if (q < OVF_CAP) ovf[q] = pr; }
        }
    }
    __syncthreads();
    for (int i = threadIdx.x; i < B; i += 256) cnt[c * B + i] = min(scnt[i], cap);
}

// Binned count: one block per bucket, LDS histogram of its segment
// entries, coalesced deg-slice write. No global atomics, no memset.
template <int NODE>
__global__ __launch_bounds__(256) void k_bcount(
    const uint2* __restrict__ seg, const int* __restrict__ cnt,
    int* __restrict__ deg, int nchunk, int B, int shift, int cap, int ntgt) {
    __shared__ int cur_l[1024];
    int bkt = blockIdx.x;
    int lo = bkt << shift;
    int hi = min(ntgt, lo + (1 << shift));
    int tid = threadIdx.x;
    for (int i = tid; i < (1 << shift); i += 256) cur_l[i] = 0;
    __syncthreads();
    int wv = tid >> 6, ln = tid & 63;
    for (int c = wv; c < nchunk; c += 4) {
        int n = cnt[c * B + bkt];
        const uint2* sp = seg + ((size_t)c * B + bkt) * cap;
        for (int i = ln; i < n; i += 64) {
            uint2 pr = sp[i];
            int key = NODE ? (int)(pr.x >> 16) : (int)pr.x;
            atomicAdd(&cur_l[key - lo], 1);
        }
    }
    __syncthreads();
    for (int t = lo + tid; t < hi; t += 256) deg[t] = cur_l[t - lo];
}

// Add overflow-list contributions to deg (expected n == 0).
template <int NODE>
__global__ void k_ovf_count(const uint2* __restrict__ ovf, const int* __restrict__ ovf_cur,
                            int* __restrict__ deg) {
    int n = min(*ovf_cur, OVF_CAP);
    for (int i = blockIdx.x * blockDim.x + threadIdx.x; i < n; i += gridDim.x * blockDim.x) {
        int key = NODE ? (int)(ovf[i].x >> 16) : (int)ovf[i].x;
        atomicAdd(&deg[key], 1);
    }
}

// Pass 2: one block per bucket; scatter into LDS image of the CSR slice,
// then stream it out coalesced. Writes cur[] (absolute next-slot) for the
// overflow cleanup. Fallback to direct scatter if slice exceeds LDS cap.
template <int NODE>
__global__ __launch_bounds__(256) void k_place(
    const uint2* __restrict__ seg, const int* __restrict__ cnt,
    const int* __restrict__ ptr, int* __restrict__ nbr, int* __restrict__ eid,
    int* __restrict__ cur, int nchunk, int B, int shift, int cap, int ntgt) {
    __shared__ int cur_l[1024];
    __shared__ uint2 obuf2[6144];
    int* obuf = (int*)obuf2;
    const int CAPLEN = NODE ? 6144 : 12288;
    int bkt = blockIdx.x;
    int lo = bkt << shift;
    int hi = min(ntgt, lo + (1 << shift));
    int base = ptr[lo];
    int len = ptr[hi] - base;
    int tid = threadIdx.x;
    if (len <= CAPLEN) {
        for (int t = lo + tid; t < hi; t += 256) cur_l[t - lo] = ptr[t] - base;
        __syncthreads();
        int wv = tid >> 6, ln = tid & 63;
        for (int c = wv; c < nchunk; c += 4) {
            int n = cnt[c * B + bkt];
            const uint2* sp = seg + ((size_t)c * B + bkt) * cap;
            for (int i = ln; i < n; i += 64) {
                uint2 pr = sp[i];
                int key, val;
                if (NODE) { key = (int)(pr.x >> 16); val = (int)(pr.x & 0xffffu); }
                else      { key = (int)pr.x; val = (int)pr.y; }
                int slot = atomicAdd(&cur_l[key - lo], 1);
                if (NODE) obuf2[slot] = make_uint2((uint_t)val, pr.y);
                else obuf[slot] = val;
            }
        }
        __syncthreads();
        if (NODE) {
            for (int i = tid; i < len; i += 256) {
                uint2 v = obuf2[i];
                nbr[base + i] = (int)v.x;
                eid[base + i] = (int)v.y;
            }
        } else {
            for (int i = tid; i < len; i += 256) nbr[base + i] = obuf[i];
        }
        for (int t = lo + tid; t < hi; t += 256) cur[t] = base + cur_l[t - lo];
    } else {
        for (int t = lo + tid; t < hi; t += 256) cur[t] = ptr[t];
        __syncthreads();
        for (int c = 0; c < nchunk; c++) {
            int n = cnt[c * B + bkt];
            const uint2* sp = seg + ((size_t)c * B + bkt) * cap;
            for (int i = tid; i < n; i += 256) {
                uint2 pr = sp[i];
                int key, val;
                if (NODE) { key = (int)(pr.x >> 16); val = (int)(pr.x & 0xffffu); }
                else      { key = (int)pr.x; val = (int)pr.y; }
                int p = atomicAdd(&cur[key], 1);
                nbr[p] = val;
                if (NODE) eid[p] = (int)pr.y;
            }
        }
    }
}

template <int NODE>
__global__ void k_ovf_fix(const uint2* __restrict__ ovf, const int* __restrict__ ovf_cur,
                          int* __restrict__ cur, int* __restrict__ nbr,
                          int* __restrict__ eid) {
    int n = min(*ovf_cur, OVF_CAP);
    for (int i = blockIdx.x * blockDim.x + threadIdx.x; i < n; i += gridDim.x * blockDim.x) {
        uint2 pr = ovf[i];
        int key, val;
        if (NODE) { key = (int)(pr.x >> 16); val = (int)(pr.x & 0xffffu); }
        else      { key = (int)pr.x; val = (int)pr.y; }
        int p = atomicAdd(&cur[key], 1);
        nbr[p] = val;
        if (NODE) eid[p] = (int)pr.y;
    }
}

// ---------------- encoders (bf16 out) ----------------
__global__ void k_encoder(const int* __restrict__ x, const float* __restrict__ metafeat,
                          const float* __restrict__ atom_emb, const float* __restrict__ meta_W,
                          const float* __restrict__ meta_b, uint_t* __restrict__ nf0,
                          uint_t* __restrict__ mf0, int N) {
    __shared__ float W[16 * 128];
    __shared__ float bsh[128];
    for (int i = threadIdx.x; i < 16 * 128; i += blockDim.x) W[i] = meta_W[i];
    if (threadIdx.x < 128) bsh[threadIdx.x] = meta_b[threadIdx.x];
    __syncthreads();
    int idx = blockIdx.x * blockDim.x + threadIdx.x;
    if (idx < N * 64) {
        int i = idx >> 6, j2 = idx & 63;
        float2 av = *reinterpret_cast<const float2*>(atom_emb + (size_t)x[i] * 128 + j2 * 2);
        nf0[idx] = packbf(av.x, av.y);
        const float* mrow = metafeat + (size_t)i * 16;
        float a0 = bsh[j2 * 2], a1 = bsh[j2 * 2 + 1];
#pragma unroll
        for (int k = 0; k < 16; k++) {
            float m = mrow[k];
            a0 = fmaf(m, W[k * 128 + j2 * 2], a0);
            a1 = fmaf(m, W[k * 128 + j2 * 2 + 1], a1);
        }
        mf0[idx] = packbf(a0, a1);
    }
}

__global__ void k_gate_node(const int* __restrict__ ptr, const int* __restrict__ eid_arr,
                            const int* __restrict__ edge_attr, const float* __restrict__ bond_emb,
                            uint_t* __restrict__ gate, int N) {
    __shared__ float bond[8 * 128];
    for (int i = threadIdx.x; i < 8 * 128; i += blockDim.x) bond[i] = bond_emb[i];
    __syncthreads();
    int l = threadIdx.x & 63, li = threadIdx.x >> 6;
    int node = blockIdx.x * 4 + li;
    if (node >= N) return;
    int p0 = ptr[node], p1 = ptr[node + 1];
    float g0 = 0.f, g1 = 0.f;
    for (int p = p0; p < p1; p++) {
        int a = edge_attr[eid_arr[p]];
        float2 bv = *reinterpret_cast<const float2*>(&bond[a * 128 + l * 2]);
        g0 += bv.x; g1 += bv.y;
    }
    gate[(size_t)node * 64 + l] = packbf(g0, g1);
}

// ---------------- GEMM (64-row tile, optional 2-batch) ----------------
// GATED: A = elu(X*G). IBF16: X packed bf16 pitch 64 (G always bf16 pitch 64).
// EPI 0: out = rsqrt(deg+1)*acc   EPI 1: out = acc + deg*bias
// OBF16: bf16 out. OILV: interleaved m01 layout (pitch 128 uints).
// BATCH: blocks >= gb handle (Xv2, W2, outv2) with the SAME gate/deg.
template <int GATED, int EPI, int IBF16, int OBF16, int OILV, int BATCH>
__global__ __launch_bounds__(256, 4) void k_gemm64(
    const void* __restrict__ Xv, const void* __restrict__ Gv,
    const float* __restrict__ W, const float* __restrict__ bias,
    const int* __restrict__ deg, void* __restrict__ outv,
    const void* __restrict__ Xv2, const float* __restrict__ W2,
    void* __restrict__ outv2, int gb, int M) {
    __shared__ float As[64][33];
    __shared__ float Bs[32][128];
    int tid = threadIdx.x;
    int tx = tid & 15, ty = tid >> 4;

    int bid = blockIdx.x;
    const void* Xp = Xv;
    const float* Wp = W;
    void* outp = outv;
    if (BATCH && bid >= gb) { bid -= gb; Xp = Xv2; Wp = W2; outp = outv2; }
    int row0 = bid * 64;

    float acc[4][8];
#pragma unroll
    for (int i = 0; i < 4; i++)
#pragma unroll
        for (int j = 0; j < 8; j++) acc[i][j] = 0.f;

    for (int h = 0; h < 4; h++) {
#pragma unroll
        for (int p = 0; p < 4; p++) {
            int idx = p * 256 + tid;
            int kk = idx >> 5, cg = idx & 31;
            float4 w = *reinterpret_cast<const float4*>(Wp + (h * 32 + kk) * 128 + cg * 4);
            *reinterpret_cast<float4*>(&Bs[kk][cg * 4]) = w;
        }
        int kg = tid & 7, rr = tid >> 3;
#pragma unroll
        for (int p = 0; p < 2; p++) {
            int r = p * 32 + rr;
            int grow = row0 + r;
            float4 av;
            if (grow < M) {
                float x0, x1, x2, x3;
                if (IBF16) {
                    const uint_t* Xb = (const uint_t*)Xp;
                    uint2 xu = *reinterpret_cast<const uint2*>(
                        Xb + (size_t)grow * 64 + h * 16 + kg * 2);
                    x0 = bflo(xu.x); x1 = bfhi(xu.x); x2 = bflo(xu.y); x3 = bfhi(xu.y);
                } else {
                    const float* Xf = (const float*)Xp;
                    float4 xv = *reinterpret_cast<const float4*>(
                        Xf + (size_t)grow * 128 + h * 32 + kg * 4);
                    x0 = xv.x; x1 = xv.y; x2 = xv.z; x3 = xv.w;
                }
                if (GATED) {
                    const uint_t* Gb = (const uint_t*)Gv;
                    uint2 gu = *reinterpret_cast<const uint2*>(
                        Gb + (size_t)grow * 64 + h * 16 + kg * 2);
                    av.x = eluf(x0 * bflo(gu.x)); av.y = eluf(x1 * bfhi(gu.x));
                    av.z = eluf(x2 * bflo(gu.y)); av.w = eluf(x3 * bfhi(gu.y));
                } else {
                    av = make_float4(x0, x1, x2, x3);
                }
            } else av = make_float4(0.f, 0.f, 0.f, 0.f);
            As[r][kg * 4 + 0] = av.x; As[r][kg * 4 + 1] = av.y;
            As[r][kg * 4 + 2] = av.z; As[r][kg * 4 + 3] = av.w;
        }
        __syncthreads();
#pragma unroll 8
        for (int k = 0; k < 32; k++) {
            float a[4], b[8];
#pragma unroll
            for (int i = 0; i < 4; i++) a[i] = As[ty * 4 + i][k];
            float4 b0 = *reinterpret_cast<const float4*>(&Bs[k][tx * 4]);
            float4 b1 = *reinterpret_cast<const float4*>(&Bs[k][64 + tx * 4]);
            b[0] = b0.x; b[1] = b0.y; b[2] = b0.z; b[3] = b0.w;
            b[4] = b1.x; b[5] = b1.y; b[6] = b1.z; b[7] = b1.w;
#pragma unroll
            for (int i = 0; i < 4; i++)
#pragma unroll
                for (int j = 0; j < 8; j++) acc[i][j] = fmaf(a[i], b[j], acc[i][j]);
        }
        __syncthreads();
    }
#pragma unroll
    for (int i = 0; i < 4; i++) {
        int r = row0 + ty * 4 + i;
        if (r < M) {
            float o[8];
            if (EPI == 0) {
                float sc = rsqrtf((float)deg[r] + 1.0f);
#pragma unroll
                for (int j = 0; j < 8; j++) o[j] = acc[i][j] * sc;
            } else {
                float dg = (float)deg[r];
                float4 ba = *reinterpret_cast<const float4*>(bias + tx * 4);
                float4 bb = *reinterpret_cast<const float4*>(bias + 64 + tx * 4);
                o[0] = acc[i][0] + dg * ba.x; o[1] = acc[i][1] + dg * ba.y;
                o[2] = acc[i][2] + dg * ba.z; o[3] = acc[i][3] + dg * ba.w;
                o[4] = acc[i][4] + dg * bb.x; o[5] = acc[i][5] + dg * bb.y;
                o[6] = acc[i][6] + dg * bb.z; o[7] = acc[i][7] + dg * bb.w;
            }
            if (OBF16) {
                uint_t* ob = (uint_t*)outp;
                uint2 q0, q1;
                q0.x = packbf(o[0], o[1]); q0.y = packbf(o[2], o[3]);
                q1.x = packbf(o[4], o[5]); q1.y = packbf(o[6], o[7]);
                if (OILV) {
                    *reinterpret_cast<uint2*>(ob + (size_t)r * 128 + tx * 4) = q0;
                    *reinterpret_cast<uint2*>(ob + (size_t)r * 128 + 64 + tx * 4) = q1;
                } else {
                    *reinterpret_cast<uint2*>(ob + (size_t)r * 64 + tx * 2) = q0;
                    *reinterpret_cast<uint2*>(ob + (size_t)r * 64 + 32 + tx * 2) = q1;
                }
            } else {
                float* out = (float*)outp;
                *reinterpret_cast<float4*>(out + (size_t)r * 128 + tx * 4) =
                    make_float4(o[0], o[1], o[2], o[3]);
                *reinterpret_cast<float4*>(out + (size_t)r * 128 + 64 + tx * 4) =
                    make_float4(o[4], o[5], o[6], o[7]);
            }
        }
    }
}

// ---------------- node aggregations on interleaved m01 ----------------
// m01 layout: uint4 at [node*128 + c*4]: .xy = m0 dims 4c..4c+3, .zw = m1 same.
__global__ void k_agg_dual(const int* __restrict__ ptr, const int* __restrict__ nbr,
                           const uint_t* __restrict__ m01,
                           const float* __restrict__ b0, const float* __restrict__ b1,
                           const int* __restrict__ deg, uint_t* __restrict__ h0,
                           uint_t* __restrict__ h1, int n) {
    int c = threadIdx.x & 31, li = threadIdx.x >> 5;
    int node = blockIdx.x * 8 + li;
    if (node >= n) return;
    int p0 = ptr[node], p1 = ptr[node + 1];
    uint4 s = *reinterpret_cast<const uint4*>(m01 + (size_t)node * 128 + c * 4);
    float a00 = bflo(s.x), a01 = bfhi(s.x), a02 = bflo(s.y), a03 = bfhi(s.y);
    float a10 = bflo(s.z), a11 = bfhi(s.z), a12 = bflo(s.w), a13 = bfhi(s.w);
    int p = p0;
    for (; p + 4 <= p1; p += 4) {
        int i0 = nbr[p], i1 = nbr[p + 1], i2 = nbr[p + 2], i3 = nbr[p + 3];
        uint4 v0 = *reinterpret_cast<const uint4*>(m01 + (size_t)i0 * 128 + c * 4);
        uint4 v1 = *reinterpret_cast<const uint4*>(m01 + (size_t)i1 * 128 + c * 4);
        uint4 v2 = *reinterpret_cast<const uint4*>(m01 + (size_t)i2 * 128 + c * 4);
        uint4 v3 = *reinterpret_cast<const uint4*>(m01 + (size_t)i3 * 128 + c * 4);
        a00 += bflo(v0.x) + bflo(v1.x) + bflo(v2.x) + bflo(v3.x);
        a01 += bfhi(v0.x) + bfhi(v1.x) + bfhi(v2.x) + bfhi(v3.x);
        a02 += bflo(v0.y) + bflo(v1.y) + bflo(v2.y) + bflo(v3.y);
        a03 += bfhi(v0.y) + bfhi(v1.y) + bfhi(v2.y) + bfhi(v3.y);
        a10 += bflo(v0.z) + bflo(v1.z) + bflo(v2.z) + bflo(v3.z);
        a11 += bfhi(v0.z) + bfhi(v1.z) + bfhi(v2.z) + bfhi(v3.z);
        a12 += bflo(v0.w) + bflo(v1.w) + bflo(v2.w) + bflo(v3.w);
        a13 += bfhi(v0.w) + bfhi(v1.w) + bfhi(v2.w) + bfhi(v3.w);
    }
    for (; p < p1; p++) {
        uint4 v = *reinterpret_cast<const uint4*>(m01 + (size_t)nbr[p] * 128 + c * 4);
        a00 += bflo(v.x); a01 += bfhi(v.x); a02 += bflo(v.y); a03 += bfhi(v.y);
        a10 += bflo(v.z); a11 += bfhi(v.z); a12 += bflo(v.w); a13 += bfhi(v.w);
    }
    float sc = rsqrtf((float)deg[node] + 1.f);
    float4 bb0 = *reinterpret_cast<const float4*>(b0 + c * 4);
    float4 bb1 = *reinterpret_cast<const float4*>(b1 + c * 4);
    uint2 o0, o1;
    o0.x = packbf(sc * a00 + bb0.x, sc * a01 + bb0.y);
    o0.y = packbf(sc * a02 + bb0.z, sc * a03 + bb0.w);
    o1.x = packbf(sc * a10 + bb1.x, sc * a11 + bb1.y);
    o1.y = packbf(sc * a12 + bb1.z, sc * a13 + bb1.w);
    size_t idx = (size_t)node * 64 + c * 2;
    *reinterpret_cast<uint2*>(h0 + idx) = o0;
    *reinterpret_cast<uint2*>(h1 + idx) = o1;
}

// final agg: m01 slot0 = org (out_org), slot1 = meta (out_meta), + pr scale
__global__ void k_agg_hat(const int* __restrict__ ptr, const int* __restrict__ nbr,
                          const uint_t* __restrict__ m01,
                          const float* __restrict__ b_org, const float* __restrict__ b_meta,
                          const int* __restrict__ deg, const float* __restrict__ c_pr,
                          float* __restrict__ out_meta, float* __restrict__ out_org, int n) {
    int c = threadIdx.x & 31, li = threadIdx.x >> 5;
    int node = blockIdx.x * 8 + li;
    if (node >= n) return;
    int p0 = ptr[node], p1 = ptr[node + 1];
    uint4 s = *reinterpret_cast<const uint4*>(m01 + (size_t)node * 128 + c * 4);
    float a00 = bflo(s.x), a01 = bfhi(s.x), a02 = bflo(s.y), a03 = bfhi(s.y);
    float a10 = bflo(s.z), a11 = bfhi(s.z), a12 = bflo(s.w), a13 = bfhi(s.w);
    int p = p0;
    for (; p + 4 <= p1; p += 4) {
        int i0 = nbr[p], i1 = nbr[p + 1], i2 = nbr[p + 2], i3 = nbr[p + 3];
        uint4 v0 = *reinterpret_cast<const uint4*>(m01 + (size_t)i0 * 128 + c * 4);
        uint4 v1 = *reinterpret_cast<const uint4*>(m01 + (size_t)i1 * 128 + c * 4);
        uint4 v2 = *reinterpret_cast<const uint4*>(m01 + (size_t)i2 * 128 + c * 4);
        uint4 v3 = *reinterpret_cast<const uint4*>(m01 + (size_t)i3 * 128 + c * 4);
        a00 += bflo(v0.x) + bflo(v1.x) + bflo(v2.x) + bflo(v3.x);
        a01 += bfhi(v0.x) + bfhi(v1.x) + bfhi(v2.x) + bfhi(v3.x);
        a02 += bflo(v0.y) + bflo(v1.y) + bflo(v2.y) + bflo(v3.y);
        a03 += bfhi(v0.y) + bfhi(v1.y) + bfhi(v2.y) + bfhi(v3.y);
        a10 += bflo(v0.z) + bflo(v1.z) + bflo(v2.z) + bflo(v3.z);
        a11 += bfhi(v0.z) + bfhi(v1.z) + bfhi(v2.z) + bfhi(v3.z);
        a12 += bflo(v0.w) + bflo(v1.w) + bflo(v2.w) + bflo(v3.w);
        a13 += bfhi(v0.w) + bfhi(v1.w) + bfhi(v2.w) + bfhi(v3.w);
    }
    for (; p < p1; p++) {
        uint4 v = *reinterpret_cast<const uint4*>(m01 + (size_t)nbr[p] * 128 + c * 4);
        a00 += bflo(v.x); a01 += bfhi(v.x); a02 += bflo(v.y); a03 += bfhi(v.y);
        a10 += bflo(v.z); a11 += bfhi(v.z); a12 += bflo(v.w); a13 += bfhi(v.w);
    }
    int dg = deg[node];
    float sc = rsqrtf((float)dg + 1.f);
    float pr = c_pr[node] * fmaxf((float)dg, 1.f);
    float4 bo = *reinterpret_cast<const float4*>(b_org + c * 4);
    float4 bm = *reinterpret_cast<const float4*>(b_meta + c * 4);
    size_t o = (size_t)node * 128 + c * 4;
    *reinterpret_cast<float4*>(out_org + o) =
        make_float4((sc * a00 + bo.x) * pr, (sc * a01 + bo.y) * pr,
                    (sc * a02 + bo.z) * pr, (sc * a03 + bo.w) * pr);
    *reinterpret_cast<float4*>(out_meta + o) =
        make_float4((sc * a10 + bm.x) * pr, (sc * a11 + bm.y) * pr,
                    (sc * a12 + bm.z) * pr, (sc * a13 + bm.w) * pr);
}

// ---------------- line-graph path ----------------
// Grid-stride, one wave per edge. e is wave-uniform -> src/dst/eattr/
// deg_lg and the two 64B metafeat rows become scalar loads, done once per
// wave instead of once per lane. Each lane produces 2 output columns.
__global__ __launch_bounds__(256) void k_ef(
    const int* __restrict__ src, const int* __restrict__ dst,
    const int* __restrict__ eattr, const int* __restrict__ x,
    const float* __restrict__ metafeat, const float* __restrict__ atom_emb,
    const float* __restrict__ bond_emb, const float* __restrict__ meta_W,
    const float* __restrict__ meta_b, const int* __restrict__ deg_lg,
    ushort_t* __restrict__ u, int E) {
    __shared__ float W[16 * 128];
    __shared__ float bond[8 * 128];
    __shared__ float mb[128];
    for (int i = threadIdx.x; i < 16 * 128; i += 256) W[i] = meta_W[i];
    for (int i = threadIdx.x; i < 8 * 128; i += 256) bond[i] = bond_emb[i];
    if (threadIdx.x < 128) mb[threadIdx.x] = meta_b[threadIdx.x];
    __syncthreads();

    int l = threadIdx.x & 63;
    int j0 = l * 2;
    int wv = __builtin_amdgcn_readfirstlane(threadIdx.x >> 6);  // wave id in block (SGPR)
    int estep = gridDim.x * 4;

    for (int e = blockIdx.x * 4 + wv; e < E; e += estep) {
        int s = src[e], d = dst[e], at = eattr[e];
        int xs = x[s], xd = x[d];
        // metafeat rows: wave-uniform 64B each -> scalar (SMEM) loads
        const float4* ms4 = reinterpret_cast<const float4*>(metafeat + (size_t)s * 16);
        const float4* md4 = reinterpret_cast<const float4*>(metafeat + (size_t)d * 16);
        float mk[16];
#pragma unroll
        for (int q = 0; q < 4; q++) {
            float4 a = ms4[q], b = md4[q];
            mk[q * 4 + 0] = a.x + b.x;
            mk[q * 4 + 1] = a.y + b.y;
            mk[q * 4 + 2] = a.z + b.z;
            mk[q * 4 + 3] = a.w + b.w;
        }
        float2 av = *reinterpret_cast<const float2*>(atom_emb + (size_t)xs * 128 + j0);
        float2 bv = *reinterpret_cast<const float2*>(atom_emb + (size_t)xd * 128 + j0);
        float n0 = av.x + bv.x, n1 = av.y + bv.y;
        float2 mbv = *reinterpret_cast<const float2*>(&mb[j0]);
        float m0 = 2.f * mbv.x, m1 = 2.f * mbv.y;
#pragma unroll
        for (int k = 0; k < 16; k++) {
            float2 wv2 = *reinterpret_cast<const float2*>(&W[k * 128 + j0]);
            m0 = fmaf(mk[k], wv2.x, m0);
            m1 = fmaf(mk[k], wv2.y, m1);
        }
        float2 bo = *reinterpret_cast<const float2*>(&bond[at * 128 + j0]);
        float sc = rsqrtf((float)deg_lg[e] + 1.f);
        float v0 = sc * eluf_fast(bo.x * n0 * m0);
        float v1 = sc * eluf_fast(bo.y * n1 * m1);
        *reinterpret_cast<uint_t*>(u + (size_t)e * 128 + j0) = packbf(v0, v1);
    }
}

// v[e] = sc_e*(u[e] + sum u[e']) bf16, chunk [e0,e1) -> vout (row e-e0)
__global__ void k_lg_v(const int* __restrict__ ptr_lg, const int* __restrict__ adj_lg,
                       const int* __restrict__ deg_lg, const uint_t* __restrict__ u32,
                       uint_t* __restrict__ vout, int e0, int e1) {
    int l = threadIdx.x & 63, li = threadIdx.x >> 6;
    int e = e0 + blockIdx.x * 4 + li;
    if (e >= e1) return;
    int p0 = ptr_lg[e], p1 = ptr_lg[e + 1];
    uint_t self = u32[(size_t)e * 64 + l];
    float s0 = bflo(self), s1 = bfhi(self);
    int p = p0;
    for (; p + 4 <= p1; p += 4) {
        int i0 = adj_lg[p], i1 = adj_lg[p + 1], i2 = adj_lg[p + 2], i3 = adj_lg[p + 3];
        uint_t w0 = u32[(size_t)i0 * 64 + l];
        uint_t w1 = u32[(size_t)i1 * 64 + l];
        uint_t w2 = u32[(size_t)i2 * 64 + l];
        uint_t w3 = u32[(size_t)i3 * 64 + l];
        s0 += bflo(w0) + bflo(w1) + bflo(w2) + bflo(w3);
        s1 += bfhi(w0) + bfhi(w1) + bfhi(w2) + bfhi(w3);
    }
    for (; p < p1; p++) {
        uint_t w = u32[(size_t)adj_lg[p] * 64 + l];
        s0 += bflo(w); s1 += bfhi(w);
    }
    float sc = rsqrtf((float)deg_lg[e] + 1.f);
    vout[(size_t)(e - e0) * 64 + l] = packbf(sc * s0, sc * s1);
}

// g0f[n] (+)= sum over incident eids in [e0,e1) of v[eid-e0]; wave-uniform branch
template <int FIRST>
__global__ void k_gate_pass(const int* __restrict__ ptr, const int* __restrict__ eid,
                            const uint_t* __restrict__ v32, float* __restrict__ g0f,
                            int n, int e0, int e1) {
    int l = threadIdx.x & 63, li = threadIdx.x >> 6;
    int node = blockIdx.x * 4 + li;
    if (node >= n) return;
    int p0 = ptr[node], p1 = ptr[node + 1];
    float s0 = 0.f, s1 = 0.f;
    for (int p = p0; p < p1; p++) {
        int e = eid[p];
        if (e >= e0 && e < e1) {
            uint_t w = v32[(size_t)(e - e0) * 64 + l];
            s0 += bflo(w); s1 += bfhi(w);
        }
    }
    float2* out = reinterpret_cast<float2*>(g0f + (size_t)node * 128 + l * 2);
    if (FIRST) {
        *out = make_float2(s0, s1);
    } else {
        float2 c = *out;
        *out = make_float2(c.x + s0, c.y + s1);
    }
}

// ---------------- pagerank: ELL, 4 lanes/node ----------------
__global__ void k_pr_init(const int* __restrict__ deg, float* __restrict__ c,
                          float* __restrict__ invdeg, int n, float invN) {
    int i = blockIdx.x * blockDim.x + threadIdx.x;
    if (i < n) {
        float iv = 1.f / fmaxf((float)deg[i], 1.f);
        invdeg[i] = iv;
        c[i] = invN * iv;
    }
}

__global__ void k_ell_build(const int* __restrict__ ptr, const int* __restrict__ nbr,
                            int* __restrict__ ell, int N) {
    int tid = blockIdx.x * blockDim.x + threadIdx.x;
    int node = tid >> 2, t = tid & 3;
    if (node >= N) return;
    int p0 = ptr[node];
    int dg = ptr[node + 1] - p0;
    if (dg > ELL_CAP) dg = ELL_CAP;
    int stride = N * 4;
    for (int k = 0; 4 * k + t < dg; k++)
        ell[k * stride + tid] = nbr[p0 + 4 * k + t];
}

__global__ void k_pr_ell(const int* __restrict__ ell, const int* __restrict__ ptr,
                         const int* __restrict__ nbr, const float* __restrict__ invdeg,
                         const float* __restrict__ cin, float* __restrict__ cout,
                         int N, float base, float damp) {
    int tid = blockIdx.x * blockDim.x + threadIdx.x;
    int node = tid >> 2, t = tid & 3;
    if (node >= N) return;
    int p0 = ptr[node], p1 = ptr[node + 1];
    int dg = p1 - p0;
    int dgc = dg > ELL_CAP ? ELL_CAP : dg;
    int stride = N * 4;
    float s = 0.f;
    for (int k = 0; 4 * k + t < dgc; k++) s += cin[ell[k * stride + tid]];
    for (int p = p0 + ELL_CAP + t; p < p1; p += 4) s += cin[nbr[p]];
    s += __shfl_xor(s, 1);
    s += __shfl_xor(s, 2);
    if (t == 0) cout[node] = (base + damp * s) * invdeg[node];
}

// ---------------- pooling + heads ----------------
__global__ void k_pool(const float* __restrict__ out_meta, const float* __restrict__ out_org,
                       float* __restrict__ partial, int n) {
    int tid = threadIdx.x;
    const float* basep = (tid < 128) ? out_meta : out_org;
    int dim = tid & 127;
    float acc = 0.f;
    for (int i = blockIdx.x; i < n; i += gridDim.x) acc += basep[(size_t)i * 128 + dim];
    partial[blockIdx.x * 256 + tid] = acc;
}

__global__ void k_final(const float* __restrict__ partial, int nblocks,
                        const float* __restrict__ cat2_W, const float* __restrict__ cat2_b,
                        const float* __restrict__ pred_W, const float* __restrict__ pred_b,
                        float* __restrict__ out) {
    __shared__ float z[256];
    __shared__ float Z[128];
    int tid = threadIdx.x;
    float acc = 0.f;
    for (int p = 0; p < nblocks; p++) acc += partial[p * 256 + tid];
    z[tid] = acc;
    __syncthreads();
    if (tid < 128) {
        float s = cat2_b[tid];
        for (int k = 0; k < 256; k++) s = fmaf(z[k], cat2_W[k * 128 + tid], s);
        Z[tid] = s;
    }
    __syncthreads();
    if (tid < 12) {
        float s = pred_b[tid];
        for (int k = 0; k < 128; k++) s = fmaf(Z[k], pred_W[k * 12 + tid], s);
        out[tid] = s;
    }
}

// ---------------------------------------------------------------------------
extern "C" void kernel_launch(void* const* d_in, const int* in_sizes, int n_in,
                              void* d_out, int out_size, void* d_ws, size_t ws_size,
                              hipStream_t stream) {
    const int* x            = (const int*)d_in[0];
    const float* metafeat   = (const float*)d_in[1];
    const int* edge_attr    = (const int*)d_in[2];
    const int* edge_index   = (const int*)d_in[3];
    const int* lg_edge_index= (const int*)d_in[4];
    const float* atom_emb   = (const float*)d_in[5];
    const float* bond_emb   = (const float*)d_in[6];
    const float* meta_W     = (const float*)d_in[7];
    const float* meta_b     = (const float*)d_in[8];
    const float* org_W      = (const float*)d_in[9];
    const float* org_b      = (const float*)d_in[10];
    const float* org1_W     = (const float*)d_in[11];
    const float* org1_b     = (const float*)d_in[12];
    const float* mconv_W    = (const float*)d_in[13];
    const float* mconv_b    = (const float*)d_in[14];
    const float* mconv1_W   = (const float*)d_in[15];
    const float* mconv1_b   = (const float*)d_in[16];
    const float* lg_W       = (const float*)d_in[17];
    const float* lg_b       = (const float*)d_in[18];
    const float* cat2_W     = (const float*)d_in[21];
    const float* cat2_b     = (const float*)d_in[22];
    const float* pred_W     = (const float*)d_in[23];
    const float* pred_b     = (const float*)d_in[24];

    const int N = in_sizes[0];
    const int E = in_sizes[2];
    const int ELG = in_sizes[4] / 2;
    const int* src = edge_index;
    const int* dst = edge_index + E;
    const int* ls = lg_edge_index;
    const int* ld = lg_edge_index + ELG;

    // ---- workspace carve (~194 MB, proven footprint) ----
    char* w = (char*)d_ws;
    auto alloc = [&](size_t bytes) -> void* {
        void* p = (void*)w;
        w += (bytes + 255) & ~(size_t)255;
        return p;
    };
    int* deg_n   = (int*)alloc((size_t)N * 4);
    int* ptr_n   = (int*)alloc((size_t)(N + 1) * 4);
    int* cur_n   = (int*)alloc((size_t)N * 4);
    int* adj_nbr = (int*)alloc((size_t)2 * E * 4);
    int* adj_eid = (int*)alloc((size_t)2 * E * 4);
    int* deg_lg  = (int*)alloc((size_t)E * 4);
    int* ptr_lg  = (int*)alloc((size_t)(E + 1) * 4);
    int* cur_lg  = (int*)alloc((size_t)E * 4);
    int* adj_lg  = (int*)alloc((size_t)2 * ELG * 4);
    int* bsum    = (int*)alloc((size_t)SCAN_NB * 4);
    float* c_a   = (float*)alloc((size_t)N * 4);
    float* c_b   = (float*)alloc((size_t)N * 4);
    float* invdg = (float*)alloc((size_t)N * 4);
    float* partial = (float*)alloc((size_t)POOL_BLOCKS * 256 * 4);
    uint_t* gateA = (uint_t*)alloc((size_t)N * 64 * 4);   // bf16: gate_n then gate_l
    float* g0f   = (float*)alloc((size_t)N * 128 * 4);    // fp32 gate accumulator
    uint_t* h_orgb  = (uint_t*)alloc((size_t)N * 64 * 4); // bf16
    uint_t* h_metab = (uint_t*)alloc((size_t)N * 64 * 4); // bf16
    size_t nodeB = (size_t)N * 64;                         // uints per bf16 node array
    size_t u_bytes = (size_t)E * 64 * 4;                   // E x 128 bf16
    size_t reg_bytes = 4 * nodeB * 4;
    uint_t* reg = (uint_t*)alloc(reg_bytes > u_bytes ? reg_bytes : u_bytes);
    uint_t* nf0b = reg;
    uint_t* mf0b = reg + nodeB;
    uint_t* m01  = reg + 2 * nodeB;  // interleaved m0/m1, pitch 128 uints/node
    ushort_t* u  = (ushort_t*)reg;   // overlays nf0b..m01 (all dead by then)
    int* ell     = (int*)reg;        // overlays nf0b quarter after u dies
    (void)n_in; (void)ws_size;

    float* out_pred = (float*)d_out;
    float* out_meta = out_pred + 12;
    float* out_org  = out_pred + 12 + (size_t)N * 128;
    // d_out doubles as the v-chunk scratch during the lg path (dead until agg_hat)
    uint_t* vhalf = (uint_t*)d_out;   // capacity: out_size*4 >= (E/2)*256 bytes
    (void)out_size;

    // ---- binned-fill scratch: overlays reg (dead until encoders) ----
    const int SH_N = 8, SH_LG = 10;
    const int NC_N = 128, CAP_N = 80;     // mean pairs/cell ~32, cap ~8.5 sigma
    const int NC_LG = 256, CAP_LG = 80;   // mean pairs/cell ~32, cap ~8.5 sigma
    int B_N  = (N + (1 << SH_N) - 1) >> SH_N;
    int B_LG = (E + (1 << SH_LG) - 1) >> SH_LG;
    bool binOK = (N <= 65535) && (B_N <= 512) && (B_LG <= 512);
    char* rw = (char*)reg;
    auto ralloc = [&](size_t bytes) -> void* {
        void* p = (void*)rw;
        rw += (bytes + 255) & ~(size_t)255;
        return p;
    };
    uint2* seg_lg = (uint2*)ralloc((size_t)NC_LG * B_LG * CAP_LG * 8);
    int*  cnt_lg  = (int*)ralloc((size_t)NC_LG * B_LG * 4);
    uint2* seg_n  = (uint2*)ralloc((size_t)NC_N * B_N * CAP_N * 8);
    int*  cnt_n   = (int*)ralloc((size_t)NC_N * B_N * 4);
    uint2* ovf_lg = (uint2*)ralloc((size_t)OVF_CAP * 8);
    uint2* ovf_n  = (uint2*)ralloc((size_t)OVF_CAP * 8);
    int* ovf_curs = (int*)ralloc(256);

    // ---- CSR build ----
    if (binOK) {
        hipMemsetAsync(ovf_curs, 0, 8, stream);
        // node graph: bin -> binned count -> scan -> place
        k_bin<1><<<NC_N, 256, 0, stream>>>(src, dst, E, seg_n, cnt_n, ovf_n,
                                           ovf_curs + 0, NC_N, B_N, SH_N, CAP_N);
        k_bcount<1><<<B_N, 256, 0, stream>>>(seg_n, cnt_n, deg_n, NC_N, B_N, SH_N, CAP_N, N);
        k_ovf_count<1><<<4, 256, 0, stream>>>(ovf_n, ovf_curs + 0, deg_n);
        {
            int C = (N + SCAN_NB - 1) / SCAN_NB;
            k_scan1<<<SCAN_NB, 256, 0, stream>>>(deg_n, N, C, bsum);
            k_scan2<<<1, 256, 0, stream>>>(bsum, SCAN_NB, ptr_n + N);
            k_scan3<<<SCAN_NB, 256, 0, stream>>>(deg_n, bsum, N, C, ptr_n, cur_n);
        }
        k_place<1><<<B_N, 256, 0, stream>>>(seg_n, cnt_n, ptr_n, adj_nbr, adj_eid,
                                            cur_n, NC_N, B_N, SH_N, CAP_N, N);
        k_ovf_fix<1><<<16, 256, 0, stream>>>(ovf_n, ovf_curs + 0, cur_n, adj_nbr, adj_eid);
        // lg graph
        k_bin<0><<<NC_LG, 256, 0, stream>>>(ls, ld, ELG, seg_lg, cnt_lg, ovf_lg,
                                            ovf_curs + 1, NC_LG, B_LG, SH_LG, CAP_LG);
        k_bcount<0><<<B_LG, 256, 0, stream>>>(seg_lg, cnt_lg, deg_lg, NC_LG, B_LG,
                                              SH_LG, CAP_LG, E);
        k_ovf_count<0><<<4, 256, 0, stream>>>(ovf_lg, ovf_curs + 1, deg_lg);
        {
            int C = (E + SCAN_NB - 1) / SCAN_NB;
            k_scan1<<<SCAN_NB, 256, 0, stream>>>(deg_lg, E, C, bsum);
            k_scan2<<<1, 256, 0, stream>>>(bsum, SCAN_NB, ptr_lg + E);
            k_scan3<<<SCAN_NB, 256, 0, stream>>>(deg_lg, bsum, E, C, ptr_lg, cur_lg);
        }
        k_place<0><<<B_LG, 256, 0, stream>>>(seg_lg, cnt_lg, ptr_lg, adj_lg, nullptr,
                                             cur_lg, NC_LG, B_LG, SH_LG, CAP_LG, E);
        k_ovf_fix<0><<<16, 256, 0, stream>>>(ovf_lg, ovf_curs + 1, cur_lg, adj_lg, nullptr);
    } else {
        hipMemsetAsync(deg_n, 0, (size_t)N * 4, stream);
        hipMemsetAsync(deg_lg, 0, (size_t)E * 4, stream);
        k_count<<<(E + 255) / 256, 256, 0, stream>>>(src, dst, E, deg_n);
        {
            int C = (N + SCAN_NB - 1) / SCAN_NB;
            k_scan1<<<SCAN_NB, 256, 0, stream>>>(deg_n, N, C, bsum);
            k_scan2<<<1, 256, 0, stream>>>(bsum, SCAN_NB, ptr_n + N);
            k_scan3<<<SCAN_NB, 256, 0, stream>>>(deg_n, bsum, N, C, ptr_n, cur_n);
        }
        int rngN = (N + FILL_NR - 1) / FILL_NR;
        k_fill_part<1><<<FILL_NR * 96, 256, 0, stream>>>(src, dst, E, cur_n,
                                                         adj_nbr, adj_eid, rngN, 96);
        k_count<<<(ELG + 255) / 256, 256, 0, stream>>>(ls, ld, ELG, deg_lg);
        {
            int C = (E + SCAN_NB - 1) / SCAN_NB;
            k_scan1<<<SCAN_NB, 256, 0, stream>>>(deg_lg, E, C, bsum);
            k_scan2<<<1, 256, 0, stream>>>(bsum, SCAN_NB, ptr_lg + E);
            k_scan3<<<SCAN_NB, 256, 0, stream>>>(deg_lg, bsum, E, C, ptr_lg, cur_lg);
        }
        int rngE = (E + FILL_NR - 1) / FILL_NR;
        k_fill_part<0><<<FILL_NR * 192, 256, 0, stream>>>(ls, ld, ELG, cur_lg,
                                                          adj_lg, nullptr, rngE, 192);
    }

    // ---- encoders + gate_n (bf16) ----
    k_encoder<<<(N * 64 + 255) / 256, 256, 0, stream>>>(x, metafeat, atom_emb, meta_W, meta_b,
                                                        nf0b, mf0b, N);
    k_gate_node<<<(N + 3) / 4, 256, 0, stream>>>(ptr_n, adj_eid, edge_attr, bond_emb, gateA, N);

    const int gb64 = (N + 63) / 64;

    // ---- GCN layer 1 (bf16 in, interleaved bf16 out; org+meta batched) ----
    k_gemm64<1, 0, 1, 1, 1, 1><<<2 * gb64, 256, 0, stream>>>(
        nf0b, gateA, org_W, nullptr, deg_n, m01 + 0,
        mf0b, mconv_W, m01 + 2, gb64, N);
    k_agg_dual<<<(N + 7) / 8, 256, 0, stream>>>(ptr_n, adj_nbr, m01, org_b, mconv_b,
                                                deg_n, h_orgb, h_metab, N);
    // reg region becomes u (bf16)

    // ---- line-graph path: u -> v (2 chunks via d_out scratch) -> g0f fp32 ----
    k_ef<<<EF_BLOCKS, 256, 0, stream>>>(src, dst, edge_attr, x, metafeat, atom_emb,
                                        bond_emb, meta_W, meta_b, deg_lg, u, E);
    {
        int eh = (E + 1) / 2;
        k_lg_v<<<(eh + 3) / 4, 256, 0, stream>>>(ptr_lg, adj_lg, deg_lg, (const uint_t*)u,
                                                 vhalf, 0, eh);
        k_gate_pass<1><<<(N + 3) / 4, 256, 0, stream>>>(ptr_n, adj_eid, vhalf, g0f, N, 0, eh);
        k_lg_v<<<(E - eh + 3) / 4, 256, 0, stream>>>(ptr_lg, adj_lg, deg_lg, (const uint_t*)u,
                                                     vhalf, eh, E);
        k_gate_pass<0><<<(N + 3) / 4, 256, 0, stream>>>(ptr_n, adj_eid, vhalf, g0f, N, eh, E);
    }
    k_gemm64<0, 1, 0, 1, 0, 0><<<gb64, 256, 0, stream>>>(
        g0f, nullptr, lg_W, lg_b, deg_n, gateA,
        nullptr, nullptr, nullptr, 0, N);   // gate_l bf16

    // ---- GCN layer 2 (gated, bf16 in, interleaved out; org+meta batched) ----
    k_gemm64<1, 0, 1, 1, 1, 1><<<2 * gb64, 256, 0, stream>>>(
        h_orgb, gateA, org1_W, nullptr, deg_n, m01 + 0,
        h_metab, mconv1_W, m01 + 2, gb64, N);
    // u dead; nf0b quarter free -> ELL

    // ---- pagerank: ELL build + PR_ITERS graph-captured launches ----
    float invN = (float)(1.0 / (double)N);
    float base = (float)((1.0 - 0.85) / (double)N);
    k_pr_init<<<(N + 255) / 256, 256, 0, stream>>>(deg_n, c_a, invdg, N, invN);
    int prb = (4 * N + 255) / 256;
    k_ell_build<<<prb, 256, 0, stream>>>(ptr_n, adj_nbr, ell, N);
    float* pin = c_a;
    float* pout = c_b;
    for (int it = 0; it < PR_ITERS; ++it) {
        k_pr_ell<<<prb, 256, 0, stream>>>(ell, ptr_n, adj_nbr, invdg, pin, pout, N,
                                          base, 0.85f);
        float* t = pin; pin = pout; pout = t;
    }

    // ---- final agg + pagerank scale -> d_out (vhalf scratch now dead) ----
    k_agg_hat<<<(N + 7) / 8, 256, 0, stream>>>(ptr_n, adj_nbr, m01, org1_b, mconv1_b,
                                               deg_n, pin, out_meta, out_org, N);
    k_pool<<<POOL_BLOCKS, 256, 0, stream>>>(out_meta, out_org, partial, N);
    k_final<<<1, 256, 0, stream>>>(partial, POOL_BLOCKS, cat2_W, cat2_b, pred_W, pred_b, out_pred);
}

// Round 7
// 1458.047 us; speedup vs baseline: 1.2482x; 1.0008x over previous
//
#include <hip/hip_runtime.h>
#include <hip/hip_bf16.h>
#include <math.h>

// ---------------------------------------------------------------------------
// IMPGNN on MI355X. fp32 accumulate; bf16 storage for streamed/gathered
// intermediates.
// R14 vs R13:
//   - k_ef no longer recomputes mf0 = metafeat@W+b per edge (was 32 FMA +
//     16 ds_read per lane-edge -> 48% VALUBusy, 112us). k_encoder now also
//     stores mf0 in fp32 into g0f (dead until k_gate_pass, runs after
//     k_ef -> zero new workspace), and k_ef gathers the two endpoint rows:
//     mf0f[s]+mf0f[d] == (ms+md)@W + 2b exactly. k_ef is now 4 coalesced
//     row gathers + bond LDS + ELU + pack per edge.
// ---------------------------------------------------------------------------

#define POOL_BLOCKS 400
#define SCAN_NB 256
#define ELL_CAP 64
#define PR_ITERS 32   // even: result ends in c_a
#define EF_BLOCKS 2048
#define FILL_NR 8     // legacy ranges (XCD-affine)
#define OVF_CAP 65536

typedef unsigned short ushort_t;
typedef unsigned int uint_t;

__device__ __forceinline__ float eluf(float x) { return x > 0.f ? x : expm1f(x); }
__device__ __forceinline__ float eluf_fast(float x) { return x > 0.f ? x : __expf(x) - 1.f; }
__device__ __forceinline__ float bf2f(ushort_t v) {
    return __uint_as_float(((unsigned int)v) << 16);
}
__device__ __forceinline__ ushort_t f2bf(float f) {
    unsigned int u = __float_as_uint(f);
    unsigned int lsb = (u >> 16) & 1u;
    u += 0x7fffu + lsb;           // round-to-nearest-even
    return (ushort_t)(u >> 16);
}
__device__ __forceinline__ float bflo(uint_t v) { return __uint_as_float(v << 16); }
__device__ __forceinline__ float bfhi(uint_t v) { return __uint_as_float(v & 0xffff0000u); }
__device__ __forceinline__ uint_t packbf(float a, float b) {
    return (uint_t)f2bf(a) | ((uint_t)f2bf(b) << 16);
}

// ---------------- CSR build ----------------
// Legacy global-atomic count (fallback only).
__global__ void k_count(const int* __restrict__ a, const int* __restrict__ b,
                        int E, int* __restrict__ deg) {
    int e = blockIdx.x * blockDim.x + threadIdx.x;
    if (e < E) {
        int s = __builtin_nontemporal_load(a + e);
        int d = __builtin_nontemporal_load(b + e);
        atomicAdd(&deg[s], 1); atomicAdd(&deg[d], 1);
    }
}

__global__ void k_scan1(const int* __restrict__ deg, int n, int C, int* __restrict__ bsum) {
    __shared__ int red[256];
    int b = blockIdx.x, tid = threadIdx.x;
    int base = b * C, end = min(base + C, n);
    int s = 0;
    for (int i = base + tid; i < end; i += 256) s += deg[i];
    red[tid] = s;
    __syncthreads();
    for (int off = 128; off > 0; off >>= 1) {
        if (tid < off) red[tid] += red[tid + off];
        __syncthreads();
    }
    if (tid == 0) bsum[b] = red[0];
}

__global__ void k_scan2(int* __restrict__ bsum, int NB, int* __restrict__ total_out) {
    __shared__ int s[256];
    int tid = threadIdx.x;
    int v = (tid < NB) ? bsum[tid] : 0;
    s[tid] = v;
    __syncthreads();
    for (int off = 1; off < 256; off <<= 1) {
        int w = (tid >= off) ? s[tid - off] : 0;
        __syncthreads();
        s[tid] += w;
        __syncthreads();
    }
    if (tid < NB) bsum[tid] = s[tid] - v;
    if (tid == 255) *total_out = s[255];
}

__global__ void k_scan3(const int* __restrict__ deg, const int* __restrict__ boff,
                        int n, int C, int* __restrict__ ptr, int* __restrict__ cur) {
    __shared__ int s[256];
    __shared__ int carry;
    int b = blockIdx.x, tid = threadIdx.x;
    int base = b * C, end = min(base + C, n);
    if (tid == 0) carry = boff[b];
    __syncthreads();
    for (int t = base; t < end; t += 256) {
        int i = t + tid;
        int v = (i < end) ? deg[i] : 0;
        s[tid] = v;
        __syncthreads();
        for (int off = 1; off < 256; off <<= 1) {
            int w = (tid >= off) ? s[tid - off] : 0;
            __syncthreads();
            s[tid] += w;
            __syncthreads();
        }
        int p = carry + s[tid] - v;
        if (i < end) { ptr[i] = p; cur[i] = p; }
        __syncthreads();
        if (tid == 0) carry += s[255];
        __syncthreads();
    }
}

// Legacy range-partitioned fill (fallback only; see R9/R10 notes).
template <int WITH_EID>
__global__ void k_fill_part(const int* __restrict__ a, const int* __restrict__ b,
                            int E, int* __restrict__ cur, int* __restrict__ nbr,
                            int* __restrict__ eid, int rngsize, int nchunk) {
    int r = blockIdx.x & (FILL_NR - 1);
    int chunk = blockIdx.x >> 3;
    int lo = r * rngsize, hi = lo + rngsize;
    int per = (E + nchunk - 1) / nchunk;
    int e0 = chunk * per;
    int e1 = min(e0 + per, E);
    for (int e = e0 + threadIdx.x; e < e1; e += blockDim.x) {
        int s = __builtin_nontemporal_load(a + e);
        int d = __builtin_nontemporal_load(b + e);
        if (s >= lo && s < hi) {
            int p = atomicAdd(&cur[s], 1);
            nbr[p] = d;
            if (WITH_EID) eid[p] = e;
        }
        if (d >= lo && d < hi) {
            int p = atomicAdd(&cur[d], 1);
            nbr[p] = s;
            if (WITH_EID) eid[p] = e;
        }
    }
}

// ---- binned CSR build ----
// Pass 1: bin endpoint pairs into private (chunk,bucket) segments.
// NODE=1: pair = {(key<<16)|nbr, eid}. NODE=0 (lg): pair = {key, val}.
template <int NODE>
__global__ __launch_bounds__(256) void k_bin(
    const int* __restrict__ a, const int* __restrict__ b, int ne,
    uint2* __restrict__ seg, int* __restrict__ cnt,
    uint2* __restrict__ ovf, int* __restrict__ ovf_cur,
    int nchunk, int B, int shift, int cap) {
    __shared__ int scnt[512];
    for (int i = threadIdx.x; i < B; i += 256) scnt[i] = 0;
    __syncthreads();
    int c = blockIdx.x;
    int per = (ne + nchunk - 1) / nchunk;
    int e0 = c * per, e1 = min(e0 + per, ne);
    uint2* segc = seg + (size_t)c * B * cap;
    for (int e = e0 + threadIdx.x; e < e1; e += 256) {
        int s = __builtin_nontemporal_load(a + e);
        int d = __builtin_nontemporal_load(b + e);
#pragma unroll
        for (int h = 0; h < 2; h++) {
            int key = h ? d : s;
            int oth = h ? s : d;
            int bkt = key >> shift;
            int pos = atomicAdd(&scnt[bkt], 1);
            uint2 pr;
            if (NODE) { pr.x = ((uint_t)key << 16) | (uint_t)oth; pr.y = (uint_t)e; }
            else      { pr.x = (uint_t)key; pr.y = (uint_t)oth; }
            if (pos < cap) segc[(size_t)bkt * cap + pos] = pr;
            else { int q = atomicAdd(ovf_cur, 1); if (q < OVF_CAP) ovf[q] = pr; }
        }
    }
    __syncthreads();
    for (int i = threadIdx.x; i < B; i += 256) cnt[c * B + i] = min(scnt[i], cap);
}

// Binned count: one block per bucket, LDS histogram of its segment
// entries, coalesced deg-slice write. No global atomics, no memset.
template <int NODE>
__global__ __launch_bounds__(256) void k_bcount(
    const uint2* __restrict__ seg, const int* __restrict__ cnt,
    int* __restrict__ deg, int nchunk, int B, int shift, int cap, int ntgt) {
    __shared__ int cur_l[1024];
    int bkt = blockIdx.x;
    int lo = bkt << shift;
    int hi = min(ntgt, lo + (1 << shift));
    int tid = threadIdx.x;
    for (int i = tid; i < (1 << shift); i += 256) cur_l[i] = 0;
    __syncthreads();
    int wv = tid >> 6, ln = tid & 63;
    for (int c = wv; c < nchunk; c += 4) {
        int n = cnt[c * B + bkt];
        const uint2* sp = seg + ((size_t)c * B + bkt) * cap;
        for (int i = ln; i < n; i += 64) {
            uint2 pr = sp[i];
            int key = NODE ? (int)(pr.x >> 16) : (int)pr.x;
            atomicAdd(&cur_l[key - lo], 1);
        }
    }
    __syncthreads();
    for (int t = lo + tid; t < hi; t += 256) deg[t] = cur_l[t - lo];
}

// Add overflow-list contributions to deg (expected n == 0).
template <int NODE>
__global__ void k_ovf_count(const uint2* __restrict__ ovf, const int* __restrict__ ovf_cur,
                            int* __restrict__ deg) {
    int n = min(*ovf_cur, OVF_CAP);
    for (int i = blockIdx.x * blockDim.x + threadIdx.x; i < n; i += gridDim.x * blockDim.x) {
        int key = NODE ? (int)(ovf[i].x >> 16) : (int)ovf[i].x;
        atomicAdd(&deg[key], 1);
    }
}

// Pass 2: one block per bucket; scatter into LDS image of the CSR slice,
// then stream it out coalesced. Writes cur[] (absolute next-slot) for the
// overflow cleanup. Fallback to direct scatter if slice exceeds LDS cap.
template <int NODE>
__global__ __launch_bounds__(256) void k_place(
    const uint2* __restrict__ seg, const int* __restrict__ cnt,
    const int* __restrict__ ptr, int* __restrict__ nbr, int* __restrict__ eid,
    int* __restrict__ cur, int nchunk, int B, int shift, int cap, int ntgt) {
    __shared__ int cur_l[1024];
    __shared__ uint2 obuf2[6144];
    int* obuf = (int*)obuf2;
    const int CAPLEN = NODE ? 6144 : 12288;
    int bkt = blockIdx.x;
    int lo = bkt << shift;
    int hi = min(ntgt, lo + (1 << shift));
    int base = ptr[lo];
    int len = ptr[hi] - base;
    int tid = threadIdx.x;
    if (len <= CAPLEN) {
        for (int t = lo + tid; t < hi; t += 256) cur_l[t - lo] = ptr[t] - base;
        __syncthreads();
        int wv = tid >> 6, ln = tid & 63;
        for (int c = wv; c < nchunk; c += 4) {
            int n = cnt[c * B + bkt];
            const uint2* sp = seg + ((size_t)c * B + bkt) * cap;
            for (int i = ln; i < n; i += 64) {
                uint2 pr = sp[i];
                int key, val;
                if (NODE) { key = (int)(pr.x >> 16); val = (int)(pr.x & 0xffffu); }
                else      { key = (int)pr.x; val = (int)pr.y; }
                int slot = atomicAdd(&cur_l[key - lo], 1);
                if (NODE) obuf2[slot] = make_uint2((uint_t)val, pr.y);
                else obuf[slot] = val;
            }
        }
        __syncthreads();
        if (NODE) {
            for (int i = tid; i < len; i += 256) {
                uint2 v = obuf2[i];
                nbr[base + i] = (int)v.x;
                eid[base + i] = (int)v.y;
            }
        } else {
            for (int i = tid; i < len; i += 256) nbr[base + i] = obuf[i];
        }
        for (int t = lo + tid; t < hi; t += 256) cur[t] = base + cur_l[t - lo];
    } else {
        for (int t = lo + tid; t < hi; t += 256) cur[t] = ptr[t];
        __syncthreads();
        for (int c = 0; c < nchunk; c++) {
            int n = cnt[c * B + bkt];
            const uint2* sp = seg + ((size_t)c * B + bkt) * cap;
            for (int i = tid; i < n; i += 256) {
                uint2 pr = sp[i];
                int key, val;
                if (NODE) { key = (int)(pr.x >> 16); val = (int)(pr.x & 0xffffu); }
                else      { key = (int)pr.x; val = (int)pr.y; }
                int p = atomicAdd(&cur[key], 1);
                nbr[p] = val;
                if (NODE) eid[p] = (int)pr.y;
            }
        }
    }
}

template <int NODE>
__global__ void k_ovf_fix(const uint2* __restrict__ ovf, const int* __restrict__ ovf_cur,
                          int* __restrict__ cur, int* __restrict__ nbr,
                          int* __restrict__ eid) {
    int n = min(*ovf_cur, OVF_CAP);
    for (int i = blockIdx.x * blockDim.x + threadIdx.x; i < n; i += gridDim.x * blockDim.x) {
        uint2 pr = ovf[i];
        int key, val;
        if (NODE) { key = (int)(pr.x >> 16); val = (int)(pr.x & 0xffffu); }
        else      { key = (int)pr.x; val = (int)pr.y; }
        int p = atomicAdd(&cur[key], 1);
        nbr[p] = val;
        if (NODE) eid[p] = (int)pr.y;
    }
}

// ---------------- encoders (bf16 out + fp32 mf0 copy) ----------------
__global__ void k_encoder(const int* __restrict__ x, const float* __restrict__ metafeat,
                          const float* __restrict__ atom_emb, const float* __restrict__ meta_W,
                          const float* __restrict__ meta_b, uint_t* __restrict__ nf0,
                          uint_t* __restrict__ mf0, float* __restrict__ mf0f, int N) {
    __shared__ float W[16 * 128];
    __shared__ float bsh[128];
    for (int i = threadIdx.x; i < 16 * 128; i += blockDim.x) W[i] = meta_W[i];
    if (threadIdx.x < 128) bsh[threadIdx.x] = meta_b[threadIdx.x];
    __syncthreads();
    int idx = blockIdx.x * blockDim.x + threadIdx.x;
    if (idx < N * 64) {
        int i = idx >> 6, j2 = idx & 63;
        float2 av = *reinterpret_cast<const float2*>(atom_emb + (size_t)x[i] * 128 + j2 * 2);
        nf0[idx] = packbf(av.x, av.y);
        const float* mrow = metafeat + (size_t)i * 16;
        float a0 = bsh[j2 * 2], a1 = bsh[j2 * 2 + 1];
#pragma unroll
        for (int k = 0; k < 16; k++) {
            float m = mrow[k];
            a0 = fmaf(m, W[k * 128 + j2 * 2], a0);
            a1 = fmaf(m, W[k * 128 + j2 * 2 + 1], a1);
        }
        mf0[idx] = packbf(a0, a1);
        *reinterpret_cast<float2*>(mf0f + (size_t)i * 128 + j2 * 2) = make_float2(a0, a1);
    }
}

__global__ void k_gate_node(const int* __restrict__ ptr, const int* __restrict__ eid_arr,
                            const int* __restrict__ edge_attr, const float* __restrict__ bond_emb,
                            uint_t* __restrict__ gate, int N) {
    __shared__ float bond[8 * 128];
    for (int i = threadIdx.x; i < 8 * 128; i += blockDim.x) bond[i] = bond_emb[i];
    __syncthreads();
    int l = threadIdx.x & 63, li = threadIdx.x >> 6;
    int node = blockIdx.x * 4 + li;
    if (node >= N) return;
    int p0 = ptr[node], p1 = ptr[node + 1];
    float g0 = 0.f, g1 = 0.f;
    for (int p = p0; p < p1; p++) {
        int a = edge_attr[eid_arr[p]];
        float2 bv = *reinterpret_cast<const float2*>(&bond[a * 128 + l * 2]);
        g0 += bv.x; g1 += bv.y;
    }
    gate[(size_t)node * 64 + l] = packbf(g0, g1);
}

// ---------------- GEMM (64-row tile, optional 2-batch) ----------------
// GATED: A = elu(X*G). IBF16: X packed bf16 pitch 64 (G always bf16 pitch 64).
// EPI 0: out = rsqrt(deg+1)*acc   EPI 1: out = acc + deg*bias
// OBF16: bf16 out. OILV: interleaved m01 layout (pitch 128 uints).
// BATCH: blocks >= gb handle (Xv2, W2, outv2) with the SAME gate/deg.
template <int GATED, int EPI, int IBF16, int OBF16, int OILV, int BATCH>
__global__ __launch_bounds__(256, 4) void k_gemm64(
    const void* __restrict__ Xv, const void* __restrict__ Gv,
    const float* __restrict__ W, const float* __restrict__ bias,
    const int* __restrict__ deg, void* __restrict__ outv,
    const void* __restrict__ Xv2, const float* __restrict__ W2,
    void* __restrict__ outv2, int gb, int M) {
    __shared__ float As[64][33];
    __shared__ float Bs[32][128];
    int tid = threadIdx.x;
    int tx = tid & 15, ty = tid >> 4;

    int bid = blockIdx.x;
    const void* Xp = Xv;
    const float* Wp = W;
    void* outp = outv;
    if (BATCH && bid >= gb) { bid -= gb; Xp = Xv2; Wp = W2; outp = outv2; }
    int row0 = bid * 64;

    float acc[4][8];
#pragma unroll
    for (int i = 0; i < 4; i++)
#pragma unroll
        for (int j = 0; j < 8; j++) acc[i][j] = 0.f;

    for (int h = 0; h < 4; h++) {
#pragma unroll
        for (int p = 0; p < 4; p++) {
            int idx = p * 256 + tid;
            int kk = idx >> 5, cg = idx & 31;
            float4 w = *reinterpret_cast<const float4*>(Wp + (h * 32 + kk) * 128 + cg * 4);
            *reinterpret_cast<float4*>(&Bs[kk][cg * 4]) = w;
        }
        int kg = tid & 7, rr = tid >> 3;
#pragma unroll
        for (int p = 0; p < 2; p++) {
            int r = p * 32 + rr;
            int grow = row0 + r;
            float4 av;
            if (grow < M) {
                float x0, x1, x2, x3;
                if (IBF16) {
                    const uint_t* Xb = (const uint_t*)Xp;
                    uint2 xu = *reinterpret_cast<const uint2*>(
                        Xb + (size_t)grow * 64 + h * 16 + kg * 2);
                    x0 = bflo(xu.x); x1 = bfhi(xu.x); x2 = bflo(xu.y); x3 = bfhi(xu.y);
                } else {
                    const float* Xf = (const float*)Xp;
                    float4 xv = *reinterpret_cast<const float4*>(
                        Xf + (size_t)grow * 128 + h * 32 + kg * 4);
                    x0 = xv.x; x1 = xv.y; x2 = xv.z; x3 = xv.w;
                }
                if (GATED) {
                    const uint_t* Gb = (const uint_t*)Gv;
                    uint2 gu = *reinterpret_cast<const uint2*>(
                        Gb + (size_t)grow * 64 + h * 16 + kg * 2);
                    av.x = eluf(x0 * bflo(gu.x)); av.y = eluf(x1 * bfhi(gu.x));
                    av.z = eluf(x2 * bflo(gu.y)); av.w = eluf(x3 * bfhi(gu.y));
                } else {
                    av = make_float4(x0, x1, x2, x3);
                }
            } else av = make_float4(0.f, 0.f, 0.f, 0.f);
            As[r][kg * 4 + 0] = av.x; As[r][kg * 4 + 1] = av.y;
            As[r][kg * 4 + 2] = av.z; As[r][kg * 4 + 3] = av.w;
        }
        __syncthreads();
#pragma unroll 8
        for (int k = 0; k < 32; k++) {
            float a[4], b[8];
#pragma unroll
            for (int i = 0; i < 4; i++) a[i] = As[ty * 4 + i][k];
            float4 b0 = *reinterpret_cast<const float4*>(&Bs[k][tx * 4]);
            float4 b1 = *reinterpret_cast<const float4*>(&Bs[k][64 + tx * 4]);
            b[0] = b0.x; b[1] = b0.y; b[2] = b0.z; b[3] = b0.w;
            b[4] = b1.x; b[5] = b1.y; b[6] = b1.z; b[7] = b1.w;
#pragma unroll
            for (int i = 0; i < 4; i++)
#pragma unroll
                for (int j = 0; j < 8; j++) acc[i][j] = fmaf(a[i], b[j], acc[i][j]);
        }
        __syncthreads();
    }
#pragma unroll
    for (int i = 0; i < 4; i++) {
        int r = row0 + ty * 4 + i;
        if (r < M) {
            float o[8];
            if (EPI == 0) {
                float sc = rsqrtf((float)deg[r] + 1.0f);
#pragma unroll
                for (int j = 0; j < 8; j++) o[j] = acc[i][j] * sc;
            } else {
                float dg = (float)deg[r];
                float4 ba = *reinterpret_cast<const float4*>(bias + tx * 4);
                float4 bb = *reinterpret_cast<const float4*>(bias + 64 + tx * 4);
                o[0] = acc[i][0] + dg * ba.x; o[1] = acc[i][1] + dg * ba.y;
                o[2] = acc[i][2] + dg * ba.z; o[3] = acc[i][3] + dg * ba.w;
                o[4] = acc[i][4] + dg * bb.x; o[5] = acc[i][5] + dg * bb.y;
                o[6] = acc[i][6] + dg * bb.z; o[7] = acc[i][7] + dg * bb.w;
            }
            if (OBF16) {
                uint_t* ob = (uint_t*)outp;
                uint2 q0, q1;
                q0.x = packbf(o[0], o[1]); q0.y = packbf(o[2], o[3]);
                q1.x = packbf(o[4], o[5]); q1.y = packbf(o[6], o[7]);
                if (OILV) {
                    *reinterpret_cast<uint2*>(ob + (size_t)r * 128 + tx * 4) = q0;
                    *reinterpret_cast<uint2*>(ob + (size_t)r * 128 + 64 + tx * 4) = q1;
                } else {
                    *reinterpret_cast<uint2*>(ob + (size_t)r * 64 + tx * 2) = q0;
                    *reinterpret_cast<uint2*>(ob + (size_t)r * 64 + 32 + tx * 2) = q1;
                }
            } else {
                float* out = (float*)outp;
                *reinterpret_cast<float4*>(out + (size_t)r * 128 + tx * 4) =
                    make_float4(o[0], o[1], o[2], o[3]);
                *reinterpret_cast<float4*>(out + (size_t)r * 128 + 64 + tx * 4) =
                    make_float4(o[4], o[5], o[6], o[7]);
            }
        }
    }
}

// ---------------- node aggregations on interleaved m01 ----------------
// m01 layout: uint4 at [node*128 + c*4]: .xy = m0 dims 4c..4c+3, .zw = m1 same.
__global__ void k_agg_dual(const int* __restrict__ ptr, const int* __restrict__ nbr,
                           const uint_t* __restrict__ m01,
                           const float* __restrict__ b0, const float* __restrict__ b1,
                           const int* __restrict__ deg, uint_t* __restrict__ h0,
                           uint_t* __restrict__ h1, int n) {
    int c = threadIdx.x & 31, li = threadIdx.x >> 5;
    int node = blockIdx.x * 8 + li;
    if (node >= n) return;
    int p0 = ptr[node], p1 = ptr[node + 1];
    uint4 s = *reinterpret_cast<const uint4*>(m01 + (size_t)node * 128 + c * 4);
    float a00 = bflo(s.x), a01 = bfhi(s.x), a02 = bflo(s.y), a03 = bfhi(s.y);
    float a10 = bflo(s.z), a11 = bfhi(s.z), a12 = bflo(s.w), a13 = bfhi(s.w);
    int p = p0;
    for (; p + 4 <= p1; p += 4) {
        int i0 = nbr[p], i1 = nbr[p + 1], i2 = nbr[p + 2], i3 = nbr[p + 3];
        uint4 v0 = *reinterpret_cast<const uint4*>(m01 + (size_t)i0 * 128 + c * 4);
        uint4 v1 = *reinterpret_cast<const uint4*>(m01 + (size_t)i1 * 128 + c * 4);
        uint4 v2 = *reinterpret_cast<const uint4*>(m01 + (size_t)i2 * 128 + c * 4);
        uint4 v3 = *reinterpret_cast<const uint4*>(m01 + (size_t)i3 * 128 + c * 4);
        a00 += bflo(v0.x) + bflo(v1.x) + bflo(v2.x) + bflo(v3.x);
        a01 += bfhi(v0.x) + bfhi(v1.x) + bfhi(v2.x) + bfhi(v3.x);
        a02 += bflo(v0.y) + bflo(v1.y) + bflo(v2.y) + bflo(v3.y);
        a03 += bfhi(v0.y) + bfhi(v1.y) + bfhi(v2.y) + bfhi(v3.y);
        a10 += bflo(v0.z) + bflo(v1.z) + bflo(v2.z) + bflo(v3.z);
        a11 += bfhi(v0.z) + bfhi(v1.z) + bfhi(v2.z) + bfhi(v3.z);
        a12 += bflo(v0.w) + bflo(v1.w) + bflo(v2.w) + bflo(v3.w);
        a13 += bfhi(v0.w) + bfhi(v1.w) + bfhi(v2.w) + bfhi(v3.w);
    }
    for (; p < p1; p++) {
        uint4 v = *reinterpret_cast<const uint4*>(m01 + (size_t)nbr[p] * 128 + c * 4);
        a00 += bflo(v.x); a01 += bfhi(v.x); a02 += bflo(v.y); a03 += bfhi(v.y);
        a10 += bflo(v.z); a11 += bfhi(v.z); a12 += bflo(v.w); a13 += bfhi(v.w);
    }
    float sc = rsqrtf((float)deg[node] + 1.f);
    float4 bb0 = *reinterpret_cast<const float4*>(b0 + c * 4);
    float4 bb1 = *reinterpret_cast<const float4*>(b1 + c * 4);
    uint2 o0, o1;
    o0.x = packbf(sc * a00 + bb0.x, sc * a01 + bb0.y);
    o0.y = packbf(sc * a02 + bb0.z, sc * a03 + bb0.w);
    o1.x = packbf(sc * a10 + bb1.x, sc * a11 + bb1.y);
    o1.y = packbf(sc * a12 + bb1.z, sc * a13 + bb1.w);
    size_t idx = (size_t)node * 64 + c * 2;
    *reinterpret_cast<uint2*>(h0 + idx) = o0;
    *reinterpret_cast<uint2*>(h1 + idx) = o1;
}

// final agg: m01 slot0 = org (out_org), slot1 = meta (out_meta), + pr scale
__global__ void k_agg_hat(const int* __restrict__ ptr, const int* __restrict__ nbr,
                          const uint_t* __restrict__ m01,
                          const float* __restrict__ b_org, const float* __restrict__ b_meta,
                          const int* __restrict__ deg, const float* __restrict__ c_pr,
                          float* __restrict__ out_meta, float* __restrict__ out_org, int n) {
    int c = threadIdx.x & 31, li = threadIdx.x >> 5;
    int node = blockIdx.x * 8 + li;
    if (node >= n) return;
    int p0 = ptr[node], p1 = ptr[node + 1];
    uint4 s = *reinterpret_cast<const uint4*>(m01 + (size_t)node * 128 + c * 4);
    float a00 = bflo(s.x), a01 = bfhi(s.x), a02 = bflo(s.y), a03 = bfhi(s.y);
    float a10 = bflo(s.z), a11 = bfhi(s.z), a12 = bflo(s.w), a13 = bfhi(s.w);
    int p = p0;
    for (; p + 4 <= p1; p += 4) {
        int i0 = nbr[p], i1 = nbr[p + 1], i2 = nbr[p + 2], i3 = nbr[p + 3];
        uint4 v0 = *reinterpret_cast<const uint4*>(m01 + (size_t)i0 * 128 + c * 4);
        uint4 v1 = *reinterpret_cast<const uint4*>(m01 + (size_t)i1 * 128 + c * 4);
        uint4 v2 = *reinterpret_cast<const uint4*>(m01 + (size_t)i2 * 128 + c * 4);
        uint4 v3 = *reinterpret_cast<const uint4*>(m01 + (size_t)i3 * 128 + c * 4);
        a00 += bflo(v0.x) + bflo(v1.x) + bflo(v2.x) + bflo(v3.x);
        a01 += bfhi(v0.x) + bfhi(v1.x) + bfhi(v2.x) + bfhi(v3.x);
        a02 += bflo(v0.y) + bflo(v1.y) + bflo(v2.y) + bflo(v3.y);
        a03 += bfhi(v0.y) + bfhi(v1.y) + bfhi(v2.y) + bfhi(v3.y);
        a10 += bflo(v0.z) + bflo(v1.z) + bflo(v2.z) + bflo(v3.z);
        a11 += bfhi(v0.z) + bfhi(v1.z) + bfhi(v2.z) + bfhi(v3.z);
        a12 += bflo(v0.w) + bflo(v1.w) + bflo(v2.w) + bflo(v3.w);
        a13 += bfhi(v0.w) + bfhi(v1.w) + bfhi(v2.w) + bfhi(v3.w);
    }
    for (; p < p1; p++) {
        uint4 v = *reinterpret_cast<const uint4*>(m01 + (size_t)nbr[p] * 128 + c * 4);
        a00 += bflo(v.x); a01 += bfhi(v.x); a02 += bflo(v.y); a03 += bfhi(v.y);
        a10 += bflo(v.z); a11 += bfhi(v.z); a12 += bflo(v.w); a13 += bfhi(v.w);
    }
    int dg = deg[node];
    float sc = rsqrtf((float)dg + 1.f);
    float pr = c_pr[node] * fmaxf((float)dg, 1.f);
    float4 bo = *reinterpret_cast<const float4*>(b_org + c * 4);
    float4 bm = *reinterpret_cast<const float4*>(b_meta + c * 4);
    size_t o = (size_t)node * 128 + c * 4;
    *reinterpret_cast<float4*>(out_org + o) =
        make_float4((sc * a00 + bo.x) * pr, (sc * a01 + bo.y) * pr,
                    (sc * a02 + bo.z) * pr, (sc * a03 + bo.w) * pr);
    *reinterpret_cast<float4*>(out_meta + o) =
        make_float4((sc * a10 + bm.x) * pr, (sc * a11 + bm.y) * pr,
                    (sc * a12 + bm.z) * pr, (sc * a13 + bm.w) * pr);
}

// ---------------- line-graph path ----------------
// One wave per edge, grid-stride. u[e] = dinv_e * elu(bond[at] *
// (nf0[s]+nf0[d]) * (mf0f[s]+mf0f[d])). mf0f (fp32) comes from k_encoder
// via the g0f buffer -> no per-edge metafeat@W recompute (R14).
__global__ __launch_bounds__(256) void k_ef(
    const int* __restrict__ src, const int* __restrict__ dst,
    const int* __restrict__ eattr, const int* __restrict__ x,
    const float* __restrict__ atom_emb, const float* __restrict__ bond_emb,
    const float* __restrict__ mf0f, const int* __restrict__ deg_lg,
    ushort_t* __restrict__ u, int E) {
    __shared__ float bond[8 * 128];
    for (int i = threadIdx.x; i < 8 * 128; i += 256) bond[i] = bond_emb[i];
    __syncthreads();

    int l = threadIdx.x & 63;
    int j0 = l * 2;
    int wv = __builtin_amdgcn_readfirstlane(threadIdx.x >> 6);  // wave id in block (SGPR)
    int estep = gridDim.x * 4;

    for (int e = blockIdx.x * 4 + wv; e < E; e += estep) {
        int s = src[e], d = dst[e], at = eattr[e];
        int xs = x[s], xd = x[d];
        float2 av = *reinterpret_cast<const float2*>(atom_emb + (size_t)xs * 128 + j0);
        float2 bv = *reinterpret_cast<const float2*>(atom_emb + (size_t)xd * 128 + j0);
        float2 ms = *reinterpret_cast<const float2*>(mf0f + (size_t)s * 128 + j0);
        float2 md = *reinterpret_cast<const float2*>(mf0f + (size_t)d * 128 + j0);
        float n0 = av.x + bv.x, n1 = av.y + bv.y;
        float m0 = ms.x + md.x, m1 = ms.y + md.y;
        float2 bo = *reinterpret_cast<const float2*>(&bond[at * 128 + j0]);
        float sc = rsqrtf((float)deg_lg[e] + 1.f);
        float v0 = sc * eluf_fast(bo.x * n0 * m0);
        float v1 = sc * eluf_fast(bo.y * n1 * m1);
        *reinterpret_cast<uint_t*>(u + (size_t)e * 128 + j0) = packbf(v0, v1);
    }
}

// v[e] = sc_e*(u[e] + sum u[e']) bf16, chunk [e0,e1) -> vout (row e-e0)
__global__ void k_lg_v(const int* __restrict__ ptr_lg, const int* __restrict__ adj_lg,
                       const int* __restrict__ deg_lg, const uint_t* __restrict__ u32,
                       uint_t* __restrict__ vout, int e0, int e1) {
    int l = threadIdx.x & 63, li = threadIdx.x >> 6;
    int e = e0 + blockIdx.x * 4 + li;
    if (e >= e1) return;
    int p0 = ptr_lg[e], p1 = ptr_lg[e + 1];
    uint_t self = u32[(size_t)e * 64 + l];
    float s0 = bflo(self), s1 = bfhi(self);
    int p = p0;
    for (; p + 4 <= p1; p += 4) {
        int i0 = adj_lg[p], i1 = adj_lg[p + 1], i2 = adj_lg[p + 2], i3 = adj_lg[p + 3];
        uint_t w0 = u32[(size_t)i0 * 64 + l];
        uint_t w1 = u32[(size_t)i1 * 64 + l];
        uint_t w2 = u32[(size_t)i2 * 64 + l];
        uint_t w3 = u32[(size_t)i3 * 64 + l];
        s0 += bflo(w0) + bflo(w1) + bflo(w2) + bflo(w3);
        s1 += bfhi(w0) + bfhi(w1) + bfhi(w2) + bfhi(w3);
    }
    for (; p < p1; p++) {
        uint_t w = u32[(size_t)adj_lg[p] * 64 + l];
        s0 += bflo(w); s1 += bfhi(w);
    }
    float sc = rsqrtf((float)deg_lg[e] + 1.f);
    vout[(size_t)(e - e0) * 64 + l] = packbf(sc * s0, sc * s1);
}

// g0f[n] (+)= sum over incident eids in [e0,e1) of v[eid-e0]; wave-uniform branch
template <int FIRST>
__global__ void k_gate_pass(const int* __restrict__ ptr, const int* __restrict__ eid,
                            const uint_t* __restrict__ v32, float* __restrict__ g0f,
                            int n, int e0, int e1) {
    int l = threadIdx.x & 63, li = threadIdx.x >> 6;
    int node = blockIdx.x * 4 + li;
    if (node >= n) return;
    int p0 = ptr[node], p1 = ptr[node + 1];
    float s0 = 0.f, s1 = 0.f;
    for (int p = p0; p < p1; p++) {
        int e = eid[p];
        if (e >= e0 && e < e1) {
            uint_t w = v32[(size_t)(e - e0) * 64 + l];
            s0 += bflo(w); s1 += bfhi(w);
        }
    }
    float2* out = reinterpret_cast<float2*>(g0f + (size_t)node * 128 + l * 2);
    if (FIRST) {
        *out = make_float2(s0, s1);
    } else {
        float2 c = *out;
        *out = make_float2(c.x + s0, c.y + s1);
    }
}

// ---------------- pagerank: ELL, 4 lanes/node ----------------
__global__ void k_pr_init(const int* __restrict__ deg, float* __restrict__ c,
                          float* __restrict__ invdeg, int n, float invN) {
    int i = blockIdx.x * blockDim.x + threadIdx.x;
    if (i < n) {
        float iv = 1.f / fmaxf((float)deg[i], 1.f);
        invdeg[i] = iv;
        c[i] = invN * iv;
    }
}

__global__ void k_ell_build(const int* __restrict__ ptr, const int* __restrict__ nbr,
                            int* __restrict__ ell, int N) {
    int tid = blockIdx.x * blockDim.x + threadIdx.x;
    int node = tid >> 2, t = tid & 3;
    if (node >= N) return;
    int p0 = ptr[node];
    int dg = ptr[node + 1] - p0;
    if (dg > ELL_CAP) dg = ELL_CAP;
    int stride = N * 4;
    for (int k = 0; 4 * k + t < dg; k++)
        ell[k * stride + tid] = nbr[p0 + 4 * k + t];
}

__global__ void k_pr_ell(const int* __restrict__ ell, const int* __restrict__ ptr,
                         const int* __restrict__ nbr, const float* __restrict__ invdeg,
                         const float* __restrict__ cin, float* __restrict__ cout,
                         int N, float base, float damp) {
    int tid = blockIdx.x * blockDim.x + threadIdx.x;
    int node = tid >> 2, t = tid & 3;
    if (node >= N) return;
    int p0 = ptr[node], p1 = ptr[node + 1];
    int dg = p1 - p0;
    int dgc = dg > ELL_CAP ? ELL_CAP : dg;
    int stride = N * 4;
    float s = 0.f;
    for (int k = 0; 4 * k + t < dgc; k++) s += cin[ell[k * stride + tid]];
    for (int p = p0 + ELL_CAP + t; p < p1; p += 4) s += cin[nbr[p]];
    s += __shfl_xor(s, 1);
    s += __shfl_xor(s, 2);
    if (t == 0) cout[node] = (base + damp * s) * invdeg[node];
}

// ---------------- pooling + heads ----------------
__global__ void k_pool(const float* __restrict__ out_meta, const float* __restrict__ out_org,
                       float* __restrict__ partial, int n) {
    int tid = threadIdx.x;
    const float* basep = (tid < 128) ? out_meta : out_org;
    int dim = tid & 127;
    float acc = 0.f;
    for (int i = blockIdx.x; i < n; i += gridDim.x) acc += basep[(size_t)i * 128 + dim];
    partial[blockIdx.x * 256 + tid] = acc;
}

__global__ void k_final(const float* __restrict__ partial, int nblocks,
                        const float* __restrict__ cat2_W, const float* __restrict__ cat2_b,
                        const float* __restrict__ pred_W, const float* __restrict__ pred_b,
                        float* __restrict__ out) {
    __shared__ float z[256];
    __shared__ float Z[128];
    int tid = threadIdx.x;
    float acc = 0.f;
    for (int p = 0; p < nblocks; p++) acc += partial[p * 256 + tid];
    z[tid] = acc;
    __syncthreads();
    if (tid < 128) {
        float s = cat2_b[tid];
        for (int k = 0; k < 256; k++) s = fmaf(z[k], cat2_W[k * 128 + tid], s);
        Z[tid] = s;
    }
    __syncthreads();
    if (tid < 12) {
        float s = pred_b[tid];
        for (int k = 0; k < 128; k++) s = fmaf(Z[k], pred_W[k * 12 + tid], s);
        out[tid] = s;
    }
}

// ---------------------------------------------------------------------------
extern "C" void kernel_launch(void* const* d_in, const int* in_sizes, int n_in,
                              void* d_out, int out_size, void* d_ws, size_t ws_size,
                              hipStream_t stream) {
    const int* x            = (const int*)d_in[0];
    const float* metafeat   = (const float*)d_in[1];
    const int* edge_attr    = (const int*)d_in[2];
    const int* edge_index   = (const int*)d_in[3];
    const int* lg_edge_index= (const int*)d_in[4];
    const float* atom_emb   = (const float*)d_in[5];
    const float* bond_emb   = (const float*)d_in[6];
    const float* meta_W     = (const float*)d_in[7];
    const float* meta_b     = (const float*)d_in[8];
    const float* org_W      = (const float*)d_in[9];
    const float* org_b      = (const float*)d_in[10];
    const float* org1_W     = (const float*)d_in[11];
    const float* org1_b     = (const float*)d_in[12];
    const float* mconv_W    = (const float*)d_in[13];
    const float* mconv_b    = (const float*)d_in[14];
    const float* mconv1_W   = (const float*)d_in[15];
    const float* mconv1_b   = (const float*)d_in[16];
    const float* lg_W       = (const float*)d_in[17];
    const float* lg_b       = (const float*)d_in[18];
    const float* cat2_W     = (const float*)d_in[21];
    const float* cat2_b     = (const float*)d_in[22];
    const float* pred_W     = (const float*)d_in[23];
    const float* pred_b     = (const float*)d_in[24];

    const int N = in_sizes[0];
    const int E = in_sizes[2];
    const int ELG = in_sizes[4] / 2;
    const int* src = edge_index;
    const int* dst = edge_index + E;
    const int* ls = lg_edge_index;
    const int* ld = lg_edge_index + ELG;

    // ---- workspace carve (~194 MB, proven footprint) ----
    char* w = (char*)d_ws;
    auto alloc = [&](size_t bytes) -> void* {
        void* p = (void*)w;
        w += (bytes + 255) & ~(size_t)255;
        return p;
    };
    int* deg_n   = (int*)alloc((size_t)N * 4);
    int* ptr_n   = (int*)alloc((size_t)(N + 1) * 4);
    int* cur_n   = (int*)alloc((size_t)N * 4);
    int* adj_nbr = (int*)alloc((size_t)2 * E * 4);
    int* adj_eid = (int*)alloc((size_t)2 * E * 4);
    int* deg_lg  = (int*)alloc((size_t)E * 4);
    int* ptr_lg  = (int*)alloc((size_t)(E + 1) * 4);
    int* cur_lg  = (int*)alloc((size_t)E * 4);
    int* adj_lg  = (int*)alloc((size_t)2 * ELG * 4);
    int* bsum    = (int*)alloc((size_t)SCAN_NB * 4);
    float* c_a   = (float*)alloc((size_t)N * 4);
    float* c_b   = (float*)alloc((size_t)N * 4);
    float* invdg = (float*)alloc((size_t)N * 4);
    float* partial = (float*)alloc((size_t)POOL_BLOCKS * 256 * 4);
    uint_t* gateA = (uint_t*)alloc((size_t)N * 64 * 4);   // bf16: gate_n then gate_l
    float* g0f   = (float*)alloc((size_t)N * 128 * 4);    // fp32: mf0f copy, then gate acc
    uint_t* h_orgb  = (uint_t*)alloc((size_t)N * 64 * 4); // bf16
    uint_t* h_metab = (uint_t*)alloc((size_t)N * 64 * 4); // bf16
    size_t nodeB = (size_t)N * 64;                         // uints per bf16 node array
    size_t u_bytes = (size_t)E * 64 * 4;                   // E x 128 bf16
    size_t reg_bytes = 4 * nodeB * 4;
    uint_t* reg = (uint_t*)alloc(reg_bytes > u_bytes ? reg_bytes : u_bytes);
    uint_t* nf0b = reg;
    uint_t* mf0b = reg + nodeB;
    uint_t* m01  = reg + 2 * nodeB;  // interleaved m0/m1, pitch 128 uints/node
    ushort_t* u  = (ushort_t*)reg;   // overlays nf0b..m01 (all dead by then)
    int* ell     = (int*)reg;        // overlays nf0b quarter after u dies
    (void)n_in; (void)ws_size;

    float* out_pred = (float*)d_out;
    float* out_meta = out_pred + 12;
    float* out_org  = out_pred + 12 + (size_t)N * 128;
    // d_out doubles as the v-chunk scratch during the lg path (dead until agg_hat)
    uint_t* vhalf = (uint_t*)d_out;   // capacity: out_size*4 >= (E/2)*256 bytes
    (void)out_size;

    // ---- binned-fill scratch: overlays reg (dead until encoders) ----
    const int SH_N = 8, SH_LG = 10;
    const int NC_N = 128, CAP_N = 80;     // mean pairs/cell ~32, cap ~8.5 sigma
    const int NC_LG = 256, CAP_LG = 80;   // mean pairs/cell ~32, cap ~8.5 sigma
    int B_N  = (N + (1 << SH_N) - 1) >> SH_N;
    int B_LG = (E + (1 << SH_LG) - 1) >> SH_LG;
    bool binOK = (N <= 65535) && (B_N <= 512) && (B_LG <= 512);
    char* rw = (char*)reg;
    auto ralloc = [&](size_t bytes) -> void* {
        void* p = (void*)rw;
        rw += (bytes + 255) & ~(size_t)255;
        return p;
    };
    uint2* seg_lg = (uint2*)ralloc((size_t)NC_LG * B_LG * CAP_LG * 8);
    int*  cnt_lg  = (int*)ralloc((size_t)NC_LG * B_LG * 4);
    uint2* seg_n  = (uint2*)ralloc((size_t)NC_N * B_N * CAP_N * 8);
    int*  cnt_n   = (int*)ralloc((size_t)NC_N * B_N * 4);
    uint2* ovf_lg = (uint2*)ralloc((size_t)OVF_CAP * 8);
    uint2* ovf_n  = (uint2*)ralloc((size_t)OVF_CAP * 8);
    int* ovf_curs = (int*)ralloc(256);

    // ---- CSR build ----
    if (binOK) {
        hipMemsetAsync(ovf_curs, 0, 8, stream);
        // node graph: bin -> binned count -> scan -> place
        k_bin<1><<<NC_N, 256, 0, stream>>>(src, dst, E, seg_n, cnt_n, ovf_n,
                                           ovf_curs + 0, NC_N, B_N, SH_N, CAP_N);
        k_bcount<1><<<B_N, 256, 0, stream>>>(seg_n, cnt_n, deg_n, NC_N, B_N, SH_N, CAP_N, N);
        k_ovf_count<1><<<4, 256, 0, stream>>>(ovf_n, ovf_curs + 0, deg_n);
        {
            int C = (N + SCAN_NB - 1) / SCAN_NB;
            k_scan1<<<SCAN_NB, 256, 0, stream>>>(deg_n, N, C, bsum);
            k_scan2<<<1, 256, 0, stream>>>(bsum, SCAN_NB, ptr_n + N);
            k_scan3<<<SCAN_NB, 256, 0, stream>>>(deg_n, bsum, N, C, ptr_n, cur_n);
        }
        k_place<1><<<B_N, 256, 0, stream>>>(seg_n, cnt_n, ptr_n, adj_nbr, adj_eid,
                                            cur_n, NC_N, B_N, SH_N, CAP_N, N);
        k_ovf_fix<1><<<16, 256, 0, stream>>>(ovf_n, ovf_curs + 0, cur_n, adj_nbr, adj_eid);
        // lg graph
        k_bin<0><<<NC_LG, 256, 0, stream>>>(ls, ld, ELG, seg_lg, cnt_lg, ovf_lg,
                                            ovf_curs + 1, NC_LG, B_LG, SH_LG, CAP_LG);
        k_bcount<0><<<B_LG, 256, 0, stream>>>(seg_lg, cnt_lg, deg_lg, NC_LG, B_LG,
                                              SH_LG, CAP_LG, E);
        k_ovf_count<0><<<4, 256, 0, stream>>>(ovf_lg, ovf_curs + 1, deg_lg);
        {
            int C = (E + SCAN_NB - 1) / SCAN_NB;
            k_scan1<<<SCAN_NB, 256, 0, stream>>>(deg_lg, E, C, bsum);
            k_scan2<<<1, 256, 0, stream>>>(bsum, SCAN_NB, ptr_lg + E);
            k_scan3<<<SCAN_NB, 256, 0, stream>>>(deg_lg, bsum, E, C, ptr_lg, cur_lg);
        }
        k_place<0><<<B_LG, 256, 0, stream>>>(seg_lg, cnt_lg, ptr_lg, adj_lg, nullptr,
                                             cur_lg, NC_LG, B_LG, SH_LG, CAP_LG, E);
        k_ovf_fix<0><<<16, 256, 0, stream>>>(ovf_lg, ovf_curs + 1, cur_lg, adj_lg, nullptr);
    } else {
        hipMemsetAsync(deg_n, 0, (size_t)N * 4, stream);
        hipMemsetAsync(deg_lg, 0, (size_t)E * 4, stream);
        k_count<<<(E + 255) / 256, 256, 0, stream>>>(src, dst, E, deg_n);
        {
            int C = (N + SCAN_NB - 1) / SCAN_NB;
            k_scan1<<<SCAN_NB, 256, 0, stream>>>(deg_n, N, C, bsum);
            k_scan2<<<1, 256, 0, stream>>>(bsum, SCAN_NB, ptr_n + N);
            k_scan3<<<SCAN_NB, 256, 0, stream>>>(deg_n, bsum, N, C, ptr_n, cur_n);
        }
        int rngN = (N + FILL_NR - 1) / FILL_NR;
        k_fill_part<1><<<FILL_NR * 96, 256, 0, stream>>>(src, dst, E, cur_n,
                                                         adj_nbr, adj_eid, rngN, 96);
        k_count<<<(ELG + 255) / 256, 256, 0, stream>>>(ls, ld, ELG, deg_lg);
        {
            int C = (E + SCAN_NB - 1) / SCAN_NB;
            k_scan1<<<SCAN_NB, 256, 0, stream>>>(deg_lg, E, C, bsum);
            k_scan2<<<1, 256, 0, stream>>>(bsum, SCAN_NB, ptr_lg + E);
            k_scan3<<<SCAN_NB, 256, 0, stream>>>(deg_lg, bsum, E, C, ptr_lg, cur_lg);
        }
        int rngE = (E + FILL_NR - 1) / FILL_NR;
        k_fill_part<0><<<FILL_NR * 192, 256, 0, stream>>>(ls, ld, ELG, cur_lg,
                                                          adj_lg, nullptr, rngE, 192);
    }

    // ---- encoders + gate_n (bf16; mf0 also in fp32 -> g0f for k_ef) ----
    k_encoder<<<(N * 64 + 255) / 256, 256, 0, stream>>>(x, metafeat, atom_emb, meta_W, meta_b,
                                                        nf0b, mf0b, g0f, N);
    k_gate_node<<<(N + 3) / 4, 256, 0, stream>>>(ptr_n, adj_eid, edge_attr, bond_emb, gateA, N);

    const int gb64 = (N + 63) / 64;

    // ---- GCN layer 1 (bf16 in, interleaved bf16 out; org+meta batched) ----
    k_gemm64<1, 0, 1, 1, 1, 1><<<2 * gb64, 256, 0, stream>>>(
        nf0b, gateA, org_W, nullptr, deg_n, m01 + 0,
        mf0b, mconv_W, m01 + 2, gb64, N);
    k_agg_dual<<<(N + 7) / 8, 256, 0, stream>>>(ptr_n, adj_nbr, m01, org_b, mconv_b,
                                                deg_n, h_orgb, h_metab, N);
    // reg region becomes u (bf16)

    // ---- line-graph path: u -> v (2 chunks via d_out scratch) -> g0f fp32 ----
    k_ef<<<EF_BLOCKS, 256, 0, stream>>>(src, dst, edge_attr, x, atom_emb, bond_emb,
                                        g0f, deg_lg, u, E);
    {
        int eh = (E + 1) / 2;
        k_lg_v<<<(eh + 3) / 4, 256, 0, stream>>>(ptr_lg, adj_lg, deg_lg, (const uint_t*)u,
                                                 vhalf, 0, eh);
        k_gate_pass<1><<<(N + 3) / 4, 256, 0, stream>>>(ptr_n, adj_eid, vhalf, g0f, N, 0, eh);
        k_lg_v<<<(E - eh + 3) / 4, 256, 0, stream>>>(ptr_lg, adj_lg, deg_lg, (const uint_t*)u,
                                                     vhalf, eh, E);
        k_gate_pass<0><<<(N + 3) / 4, 256, 0, stream>>>(ptr_n, adj_eid, vhalf, g0f, N, eh, E);
    }
    k_gemm64<0, 1, 0, 1, 0, 0><<<gb64, 256, 0, stream>>>(
        g0f, nullptr, lg_W, lg_b, deg_n, gateA,
        nullptr, nullptr, nullptr, 0, N);   // gate_l bf16

    // ---- GCN layer 2 (gated, bf16 in, interleaved out; org+meta batched) ----
    k_gemm64<1, 0, 1, 1, 1, 1><<<2 * gb64, 256, 0, stream>>>(
        h_orgb, gateA, org1_W, nullptr, deg_n, m01 + 0,
        h_metab, mconv1_W, m01 + 2, gb64, N);
    // u dead; nf0b quarter free -> ELL

    // ---- pagerank: ELL build + PR_ITERS graph-captured launches ----
    float invN = (float)(1.0 / (double)N);
    float base = (float)((1.0 - 0.85) / (double)N);
    k_pr_init<<<(N + 255) / 256, 256, 0, stream>>>(deg_n, c_a, invdg, N, invN);
    int prb = (4 * N + 255) / 256;
    k_ell_build<<<prb, 256, 0, stream>>>(ptr_n, adj_nbr, ell, N);
    float* pin = c_a;
    float* pout = c_b;
    for (int it = 0; it < PR_ITERS; ++it) {
        k_pr_ell<<<prb, 256, 0, stream>>>(ell, ptr_n, adj_nbr, invdg, pin, pout, N,
                                          base, 0.85f);
        float* t = pin; pin = pout; pout = t;
    }

    // ---- final agg + pagerank scale -> d_out (vhalf scratch now dead) ----
    k_agg_hat<<<(N + 7) / 8, 256, 0, stream>>>(ptr_n, adj_nbr, m01, org1_b, mconv1_b,
                                               deg_n, pin, out_meta, out_org, N);
    k_pool<<<POOL_BLOCKS, 256, 0, stream>>>(out_meta, out_org, partial, N);
    k_final<<<1, 256, 0, stream>>>(partial, POOL_BLOCKS, cat2_W, cat2_b, pred_W, pred_b, out_pred);
}

// Round 8
// 1367.524 us; speedup vs baseline: 1.3308x; 1.0662x over previous
//
#include <hip/hip_runtime.h>
#include <hip/hip_bf16.h>
#include <math.h>

// ---------------------------------------------------------------------------
// IMPGNN on MI355X. fp32 accumulate; bf16 storage for streamed/gathered
// intermediates.
// R15 vs R14:
//   - k_final parallelized: was 1 block / 400-deep serial load loop +
//     256-deep serial GEMV loops = 111us at 0.04% occupancy (pure latency,
//     sat in top-5 every round). Now 1024 threads: partial-reduce split
//     4-way over p, cat2 GEMV split 8-way over k-segments, pred GEMV split
//     16-way; LDS tree combines. fp32 reassociation only.
//   - k_ef: 2 consecutive edges per wave iteration (R14 post-mortem:
//     neutral total => gather-latency bound). Doubles gather MLP.
// ---------------------------------------------------------------------------

#define POOL_BLOCKS 400
#define SCAN_NB 256
#define ELL_CAP 64
#define PR_ITERS 32   // even: result ends in c_a
#define EF_BLOCKS 2048
#define FILL_NR 8     // legacy ranges (XCD-affine)
#define OVF_CAP 65536

typedef unsigned short ushort_t;
typedef unsigned int uint_t;

__device__ __forceinline__ float eluf(float x) { return x > 0.f ? x : expm1f(x); }
__device__ __forceinline__ float eluf_fast(float x) { return x > 0.f ? x : __expf(x) - 1.f; }
__device__ __forceinline__ float bf2f(ushort_t v) {
    return __uint_as_float(((unsigned int)v) << 16);
}
__device__ __forceinline__ ushort_t f2bf(float f) {
    unsigned int u = __float_as_uint(f);
    unsigned int lsb = (u >> 16) & 1u;
    u += 0x7fffu + lsb;           // round-to-nearest-even
    return (ushort_t)(u >> 16);
}
__device__ __forceinline__ float bflo(uint_t v) { return __uint_as_float(v << 16); }
__device__ __forceinline__ float bfhi(uint_t v) { return __uint_as_float(v & 0xffff0000u); }
__device__ __forceinline__ uint_t packbf(float a, float b) {
    return (uint_t)f2bf(a) | ((uint_t)f2bf(b) << 16);
}

// ---------------- CSR build ----------------
// Legacy global-atomic count (fallback only).
__global__ void k_count(const int* __restrict__ a, const int* __restrict__ b,
                        int E, int* __restrict__ deg) {
    int e = blockIdx.x * blockDim.x + threadIdx.x;
    if (e < E) {
        int s = __builtin_nontemporal_load(a + e);
        int d = __builtin_nontemporal_load(b + e);
        atomicAdd(&deg[s], 1); atomicAdd(&deg[d], 1);
    }
}

__global__ void k_scan1(const int* __restrict__ deg, int n, int C, int* __restrict__ bsum) {
    __shared__ int red[256];
    int b = blockIdx.x, tid = threadIdx.x;
    int base = b * C, end = min(base + C, n);
    int s = 0;
    for (int i = base + tid; i < end; i += 256) s += deg[i];
    red[tid] = s;
    __syncthreads();
    for (int off = 128; off > 0; off >>= 1) {
        if (tid < off) red[tid] += red[tid + off];
        __syncthreads();
    }
    if (tid == 0) bsum[b] = red[0];
}

__global__ void k_scan2(int* __restrict__ bsum, int NB, int* __restrict__ total_out) {
    __shared__ int s[256];
    int tid = threadIdx.x;
    int v = (tid < NB) ? bsum[tid] : 0;
    s[tid] = v;
    __syncthreads();
    for (int off = 1; off < 256; off <<= 1) {
        int w = (tid >= off) ? s[tid - off] : 0;
        __syncthreads();
        s[tid] += w;
        __syncthreads();
    }
    if (tid < NB) bsum[tid] = s[tid] - v;
    if (tid == 255) *total_out = s[255];
}

__global__ void k_scan3(const int* __restrict__ deg, const int* __restrict__ boff,
                        int n, int C, int* __restrict__ ptr, int* __restrict__ cur) {
    __shared__ int s[256];
    __shared__ int carry;
    int b = blockIdx.x, tid = threadIdx.x;
    int base = b * C, end = min(base + C, n);
    if (tid == 0) carry = boff[b];
    __syncthreads();
    for (int t = base; t < end; t += 256) {
        int i = t + tid;
        int v = (i < end) ? deg[i] : 0;
        s[tid] = v;
        __syncthreads();
        for (int off = 1; off < 256; off <<= 1) {
            int w = (tid >= off) ? s[tid - off] : 0;
            __syncthreads();
            s[tid] += w;
            __syncthreads();
        }
        int p = carry + s[tid] - v;
        if (i < end) { ptr[i] = p; cur[i] = p; }
        __syncthreads();
        if (tid == 0) carry += s[255];
        __syncthreads();
    }
}

// Legacy range-partitioned fill (fallback only; see R9/R10 notes).
template <int WITH_EID>
__global__ void k_fill_part(const int* __restrict__ a, const int* __restrict__ b,
                            int E, int* __restrict__ cur, int* __restrict__ nbr,
                            int* __restrict__ eid, int rngsize, int nchunk) {
    int r = blockIdx.x & (FILL_NR - 1);
    int chunk = blockIdx.x >> 3;
    int lo = r * rngsize, hi = lo + rngsize;
    int per = (E + nchunk - 1) / nchunk;
    int e0 = chunk * per;
    int e1 = min(e0 + per, E);
    for (int e = e0 + threadIdx.x; e < e1; e += blockDim.x) {
        int s = __builtin_nontemporal_load(a + e);
        int d = __builtin_nontemporal_load(b + e);
        if (s >= lo && s < hi) {
            int p = atomicAdd(&cur[s], 1);
            nbr[p] = d;
            if (WITH_EID) eid[p] = e;
        }
        if (d >= lo && d < hi) {
            int p = atomicAdd(&cur[d], 1);
            nbr[p] = s;
            if (WITH_EID) eid[p] = e;
        }
    }
}

// ---- binned CSR build ----
// Pass 1: bin endpoint pairs into private (chunk,bucket) segments.
// NODE=1: pair = {(key<<16)|nbr, eid}. NODE=0 (lg): pair = {key, val}.
template <int NODE>
__global__ __launch_bounds__(256) void k_bin(
    const int* __restrict__ a, const int* __restrict__ b, int ne,
    uint2* __restrict__ seg, int* __restrict__ cnt,
    uint2* __restrict__ ovf, int* __restrict__ ovf_cur,
    int nchunk, int B, int shift, int cap) {
    __shared__ int scnt[512];
    for (int i = threadIdx.x; i < B; i += 256) scnt[i] = 0;
    __syncthreads();
    int c = blockIdx.x;
    int per = (ne + nchunk - 1) / nchunk;
    int e0 = c * per, e1 = min(e0 + per, ne);
    uint2* segc = seg + (size_t)c * B * cap;
    for (int e = e0 + threadIdx.x; e < e1; e += 256) {
        int s = __builtin_nontemporal_load(a + e);
        int d = __builtin_nontemporal_load(b + e);
#pragma unroll
        for (int h = 0; h < 2; h++) {
            int key = h ? d : s;
            int oth = h ? s : d;
            int bkt = key >> shift;
            int pos = atomicAdd(&scnt[bkt], 1);
            uint2 pr;
            if (NODE) { pr.x = ((uint_t)key << 16) | (uint_t)oth; pr.y = (uint_t)e; }
            else      { pr.x = (uint_t)key; pr.y = (uint_t)oth; }
            if (pos < cap) segc[(size_t)bkt * cap + pos] = pr;
            else { int q = atomicAdd(ovf_cur, 1); if (q < OVF_CAP) ovf[q] = pr; }
        }
    }
    __syncthreads();
    for (int i = threadIdx.x; i < B; i += 256) cnt[c * B + i] = min(scnt[i], cap);
}

// Binned count: one block per bucket, LDS histogram of its segment
// entries, coalesced deg-slice write. No global atomics, no memset.
template <int NODE>
__global__ __launch_bounds__(256) void k_bcount(
    const uint2* __restrict__ seg, const int* __restrict__ cnt,
    int* __restrict__ deg, int nchunk, int B, int shift, int cap, int ntgt) {
    __shared__ int cur_l[1024];
    int bkt = blockIdx.x;
    int lo = bkt << shift;
    int hi = min(ntgt, lo + (1 << shift));
    int tid = threadIdx.x;
    for (int i = tid; i < (1 << shift); i += 256) cur_l[i] = 0;
    __syncthreads();
    int wv = tid >> 6, ln = tid & 63;
    for (int c = wv; c < nchunk; c += 4) {
        int n = cnt[c * B + bkt];
        const uint2* sp = seg + ((size_t)c * B + bkt) * cap;
        for (int i = ln; i < n; i += 64) {
            uint2 pr = sp[i];
            int key = NODE ? (int)(pr.x >> 16) : (int)pr.x;
            atomicAdd(&cur_l[key - lo], 1);
        }
    }
    __syncthreads();
    for (int t = lo + tid; t < hi; t += 256) deg[t] = cur_l[t - lo];
}

// Add overflow-list contributions to deg (expected n == 0).
template <int NODE>
__global__ void k_ovf_count(const uint2* __restrict__ ovf, const int* __restrict__ ovf_cur,
                            int* __restrict__ deg) {
    int n = min(*ovf_cur, OVF_CAP);
    for (int i = blockIdx.x * blockDim.x + threadIdx.x; i < n; i += gridDim.x * blockDim.x) {
        int key = NODE ? (int)(ovf[i].x >> 16) : (int)ovf[i].x;
        atomicAdd(&deg[key], 1);
    }
}

// Pass 2: one block per bucket; scatter into LDS image of the CSR slice,
// then stream it out coalesced. Writes cur[] (absolute next-slot) for the
// overflow cleanup. Fallback to direct scatter if slice exceeds LDS cap.
template <int NODE>
__global__ __launch_bounds__(256) void k_place(
    const uint2* __restrict__ seg, const int* __restrict__ cnt,
    const int* __restrict__ ptr, int* __restrict__ nbr, int* __restrict__ eid,
    int* __restrict__ cur, int nchunk, int B, int shift, int cap, int ntgt) {
    __shared__ int cur_l[1024];
    __shared__ uint2 obuf2[6144];
    int* obuf = (int*)obuf2;
    const int CAPLEN = NODE ? 6144 : 12288;
    int bkt = blockIdx.x;
    int lo = bkt << shift;
    int hi = min(ntgt, lo + (1 << shift));
    int base = ptr[lo];
    int len = ptr[hi] - base;
    int tid = threadIdx.x;
    if (len <= CAPLEN) {
        for (int t = lo + tid; t < hi; t += 256) cur_l[t - lo] = ptr[t] - base;
        __syncthreads();
        int wv = tid >> 6, ln = tid & 63;
        for (int c = wv; c < nchunk; c += 4) {
            int n = cnt[c * B + bkt];
            const uint2* sp = seg + ((size_t)c * B + bkt) * cap;
            for (int i = ln; i < n; i += 64) {
                uint2 pr = sp[i];
                int key, val;
                if (NODE) { key = (int)(pr.x >> 16); val = (int)(pr.x & 0xffffu); }
                else      { key = (int)pr.x; val = (int)pr.y; }
                int slot = atomicAdd(&cur_l[key - lo], 1);
                if (NODE) obuf2[slot] = make_uint2((uint_t)val, pr.y);
                else obuf[slot] = val;
            }
        }
        __syncthreads();
        if (NODE) {
            for (int i = tid; i < len; i += 256) {
                uint2 v = obuf2[i];
                nbr[base + i] = (int)v.x;
                eid[base + i] = (int)v.y;
            }
        } else {
            for (int i = tid; i < len; i += 256) nbr[base + i] = obuf[i];
        }
        for (int t = lo + tid; t < hi; t += 256) cur[t] = base + cur_l[t - lo];
    } else {
        for (int t = lo + tid; t < hi; t += 256) cur[t] = ptr[t];
        __syncthreads();
        for (int c = 0; c < nchunk; c++) {
            int n = cnt[c * B + bkt];
            const uint2* sp = seg + ((size_t)c * B + bkt) * cap;
            for (int i = tid; i < n; i += 256) {
                uint2 pr = sp[i];
                int key, val;
                if (NODE) { key = (int)(pr.x >> 16); val = (int)(pr.x & 0xffffu); }
                else      { key = (int)pr.x; val = (int)pr.y; }
                int p = atomicAdd(&cur[key], 1);
                nbr[p] = val;
                if (NODE) eid[p] = (int)pr.y;
            }
        }
    }
}

template <int NODE>
__global__ void k_ovf_fix(const uint2* __restrict__ ovf, const int* __restrict__ ovf_cur,
                          int* __restrict__ cur, int* __restrict__ nbr,
                          int* __restrict__ eid) {
    int n = min(*ovf_cur, OVF_CAP);
    for (int i = blockIdx.x * blockDim.x + threadIdx.x; i < n; i += gridDim.x * blockDim.x) {
        uint2 pr = ovf[i];
        int key, val;
        if (NODE) { key = (int)(pr.x >> 16); val = (int)(pr.x & 0xffffu); }
        else      { key = (int)pr.x; val = (int)pr.y; }
        int p = atomicAdd(&cur[key], 1);
        nbr[p] = val;
        if (NODE) eid[p] = (int)pr.y;
    }
}

// ---------------- encoders (bf16 out + fp32 mf0 copy) ----------------
__global__ void k_encoder(const int* __restrict__ x, const float* __restrict__ metafeat,
                          const float* __restrict__ atom_emb, const float* __restrict__ meta_W,
                          const float* __restrict__ meta_b, uint_t* __restrict__ nf0,
                          uint_t* __restrict__ mf0, float* __restrict__ mf0f, int N) {
    __shared__ float W[16 * 128];
    __shared__ float bsh[128];
    for (int i = threadIdx.x; i < 16 * 128; i += blockDim.x) W[i] = meta_W[i];
    if (threadIdx.x < 128) bsh[threadIdx.x] = meta_b[threadIdx.x];
    __syncthreads();
    int idx = blockIdx.x * blockDim.x + threadIdx.x;
    if (idx < N * 64) {
        int i = idx >> 6, j2 = idx & 63;
        float2 av = *reinterpret_cast<const float2*>(atom_emb + (size_t)x[i] * 128 + j2 * 2);
        nf0[idx] = packbf(av.x, av.y);
        const float* mrow = metafeat + (size_t)i * 16;
        float a0 = bsh[j2 * 2], a1 = bsh[j2 * 2 + 1];
#pragma unroll
        for (int k = 0; k < 16; k++) {
            float m = mrow[k];
            a0 = fmaf(m, W[k * 128 + j2 * 2], a0);
            a1 = fmaf(m, W[k * 128 + j2 * 2 + 1], a1);
        }
        mf0[idx] = packbf(a0, a1);
        *reinterpret_cast<float2*>(mf0f + (size_t)i * 128 + j2 * 2) = make_float2(a0, a1);
    }
}

__global__ void k_gate_node(const int* __restrict__ ptr, const int* __restrict__ eid_arr,
                            const int* __restrict__ edge_attr, const float* __restrict__ bond_emb,
                            uint_t* __restrict__ gate, int N) {
    __shared__ float bond[8 * 128];
    for (int i = threadIdx.x; i < 8 * 128; i += blockDim.x) bond[i] = bond_emb[i];
    __syncthreads();
    int l = threadIdx.x & 63, li = threadIdx.x >> 6;
    int node = blockIdx.x * 4 + li;
    if (node >= N) return;
    int p0 = ptr[node], p1 = ptr[node + 1];
    float g0 = 0.f, g1 = 0.f;
    for (int p = p0; p < p1; p++) {
        int a = edge_attr[eid_arr[p]];
        float2 bv = *reinterpret_cast<const float2*>(&bond[a * 128 + l * 2]);
        g0 += bv.x; g1 += bv.y;
    }
    gate[(size_t)node * 64 + l] = packbf(g0, g1);
}

// ---------------- GEMM (64-row tile, optional 2-batch) ----------------
// GATED: A = elu(X*G). IBF16: X packed bf16 pitch 64 (G always bf16 pitch 64).
// EPI 0: out = rsqrt(deg+1)*acc   EPI 1: out = acc + deg*bias
// OBF16: bf16 out. OILV: interleaved m01 layout (pitch 128 uints).
// BATCH: blocks >= gb handle (Xv2, W2, outv2) with the SAME gate/deg.
template <int GATED, int EPI, int IBF16, int OBF16, int OILV, int BATCH>
__global__ __launch_bounds__(256, 4) void k_gemm64(
    const void* __restrict__ Xv, const void* __restrict__ Gv,
    const float* __restrict__ W, const float* __restrict__ bias,
    const int* __restrict__ deg, void* __restrict__ outv,
    const void* __restrict__ Xv2, const float* __restrict__ W2,
    void* __restrict__ outv2, int gb, int M) {
    __shared__ float As[64][33];
    __shared__ float Bs[32][128];
    int tid = threadIdx.x;
    int tx = tid & 15, ty = tid >> 4;

    int bid = blockIdx.x;
    const void* Xp = Xv;
    const float* Wp = W;
    void* outp = outv;
    if (BATCH && bid >= gb) { bid -= gb; Xp = Xv2; Wp = W2; outp = outv2; }
    int row0 = bid * 64;

    float acc[4][8];
#pragma unroll
    for (int i = 0; i < 4; i++)
#pragma unroll
        for (int j = 0; j < 8; j++) acc[i][j] = 0.f;

    for (int h = 0; h < 4; h++) {
#pragma unroll
        for (int p = 0; p < 4; p++) {
            int idx = p * 256 + tid;
            int kk = idx >> 5, cg = idx & 31;
            float4 w = *reinterpret_cast<const float4*>(Wp + (h * 32 + kk) * 128 + cg * 4);
            *reinterpret_cast<float4*>(&Bs[kk][cg * 4]) = w;
        }
        int kg = tid & 7, rr = tid >> 3;
#pragma unroll
        for (int p = 0; p < 2; p++) {
            int r = p * 32 + rr;
            int grow = row0 + r;
            float4 av;
            if (grow < M) {
                float x0, x1, x2, x3;
                if (IBF16) {
                    const uint_t* Xb = (const uint_t*)Xp;
                    uint2 xu = *reinterpret_cast<const uint2*>(
                        Xb + (size_t)grow * 64 + h * 16 + kg * 2);
                    x0 = bflo(xu.x); x1 = bfhi(xu.x); x2 = bflo(xu.y); x3 = bfhi(xu.y);
                } else {
                    const float* Xf = (const float*)Xp;
                    float4 xv = *reinterpret_cast<const float4*>(
                        Xf + (size_t)grow * 128 + h * 32 + kg * 4);
                    x0 = xv.x; x1 = xv.y; x2 = xv.z; x3 = xv.w;
                }
                if (GATED) {
                    const uint_t* Gb = (const uint_t*)Gv;
                    uint2 gu = *reinterpret_cast<const uint2*>(
                        Gb + (size_t)grow * 64 + h * 16 + kg * 2);
                    av.x = eluf(x0 * bflo(gu.x)); av.y = eluf(x1 * bfhi(gu.x));
                    av.z = eluf(x2 * bflo(gu.y)); av.w = eluf(x3 * bfhi(gu.y));
                } else {
                    av = make_float4(x0, x1, x2, x3);
                }
            } else av = make_float4(0.f, 0.f, 0.f, 0.f);
            As[r][kg * 4 + 0] = av.x; As[r][kg * 4 + 1] = av.y;
            As[r][kg * 4 + 2] = av.z; As[r][kg * 4 + 3] = av.w;
        }
        __syncthreads();
#pragma unroll 8
        for (int k = 0; k < 32; k++) {
            float a[4], b[8];
#pragma unroll
            for (int i = 0; i < 4; i++) a[i] = As[ty * 4 + i][k];
            float4 b0 = *reinterpret_cast<const float4*>(&Bs[k][tx * 4]);
            float4 b1 = *reinterpret_cast<const float4*>(&Bs[k][64 + tx * 4]);
            b[0] = b0.x; b[1] = b0.y; b[2] = b0.z; b[3] = b0.w;
            b[4] = b1.x; b[5] = b1.y; b[6] = b1.z; b[7] = b1.w;
#pragma unroll
            for (int i = 0; i < 4; i++)
#pragma unroll
                for (int j = 0; j < 8; j++) acc[i][j] = fmaf(a[i], b[j], acc[i][j]);
        }
        __syncthreads();
    }
#pragma unroll
    for (int i = 0; i < 4; i++) {
        int r = row0 + ty * 4 + i;
        if (r < M) {
            float o[8];
            if (EPI == 0) {
                float sc = rsqrtf((float)deg[r] + 1.0f);
#pragma unroll
                for (int j = 0; j < 8; j++) o[j] = acc[i][j] * sc;
            } else {
                float dg = (float)deg[r];
                float4 ba = *reinterpret_cast<const float4*>(bias + tx * 4);
                float4 bb = *reinterpret_cast<const float4*>(bias + 64 + tx * 4);
                o[0] = acc[i][0] + dg * ba.x; o[1] = acc[i][1] + dg * ba.y;
                o[2] = acc[i][2] + dg * ba.z; o[3] = acc[i][3] + dg * ba.w;
                o[4] = acc[i][4] + dg * bb.x; o[5] = acc[i][5] + dg * bb.y;
                o[6] = acc[i][6] + dg * bb.z; o[7] = acc[i][7] + dg * bb.w;
            }
            if (OBF16) {
                uint_t* ob = (uint_t*)outp;
                uint2 q0, q1;
                q0.x = packbf(o[0], o[1]); q0.y = packbf(o[2], o[3]);
                q1.x = packbf(o[4], o[5]); q1.y = packbf(o[6], o[7]);
                if (OILV) {
                    *reinterpret_cast<uint2*>(ob + (size_t)r * 128 + tx * 4) = q0;
                    *reinterpret_cast<uint2*>(ob + (size_t)r * 128 + 64 + tx * 4) = q1;
                } else {
                    *reinterpret_cast<uint2*>(ob + (size_t)r * 64 + tx * 2) = q0;
                    *reinterpret_cast<uint2*>(ob + (size_t)r * 64 + 32 + tx * 2) = q1;
                }
            } else {
                float* out = (float*)outp;
                *reinterpret_cast<float4*>(out + (size_t)r * 128 + tx * 4) =
                    make_float4(o[0], o[1], o[2], o[3]);
                *reinterpret_cast<float4*>(out + (size_t)r * 128 + 64 + tx * 4) =
                    make_float4(o[4], o[5], o[6], o[7]);
            }
        }
    }
}

// ---------------- node aggregations on interleaved m01 ----------------
// m01 layout: uint4 at [node*128 + c*4]: .xy = m0 dims 4c..4c+3, .zw = m1 same.
__global__ void k_agg_dual(const int* __restrict__ ptr, const int* __restrict__ nbr,
                           const uint_t* __restrict__ m01,
                           const float* __restrict__ b0, const float* __restrict__ b1,
                           const int* __restrict__ deg, uint_t* __restrict__ h0,
                           uint_t* __restrict__ h1, int n) {
    int c = threadIdx.x & 31, li = threadIdx.x >> 5;
    int node = blockIdx.x * 8 + li;
    if (node >= n) return;
    int p0 = ptr[node], p1 = ptr[node + 1];
    uint4 s = *reinterpret_cast<const uint4*>(m01 + (size_t)node * 128 + c * 4);
    float a00 = bflo(s.x), a01 = bfhi(s.x), a02 = bflo(s.y), a03 = bfhi(s.y);
    float a10 = bflo(s.z), a11 = bfhi(s.z), a12 = bflo(s.w), a13 = bfhi(s.w);
    int p = p0;
    for (; p + 4 <= p1; p += 4) {
        int i0 = nbr[p], i1 = nbr[p + 1], i2 = nbr[p + 2], i3 = nbr[p + 3];
        uint4 v0 = *reinterpret_cast<const uint4*>(m01 + (size_t)i0 * 128 + c * 4);
        uint4 v1 = *reinterpret_cast<const uint4*>(m01 + (size_t)i1 * 128 + c * 4);
        uint4 v2 = *reinterpret_cast<const uint4*>(m01 + (size_t)i2 * 128 + c * 4);
        uint4 v3 = *reinterpret_cast<const uint4*>(m01 + (size_t)i3 * 128 + c * 4);
        a00 += bflo(v0.x) + bflo(v1.x) + bflo(v2.x) + bflo(v3.x);
        a01 += bfhi(v0.x) + bfhi(v1.x) + bfhi(v2.x) + bfhi(v3.x);
        a02 += bflo(v0.y) + bflo(v1.y) + bflo(v2.y) + bflo(v3.y);
        a03 += bfhi(v0.y) + bfhi(v1.y) + bfhi(v2.y) + bfhi(v3.y);
        a10 += bflo(v0.z) + bflo(v1.z) + bflo(v2.z) + bflo(v3.z);
        a11 += bfhi(v0.z) + bfhi(v1.z) + bfhi(v2.z) + bfhi(v3.z);
        a12 += bflo(v0.w) + bflo(v1.w) + bflo(v2.w) + bflo(v3.w);
        a13 += bfhi(v0.w) + bfhi(v1.w) + bfhi(v2.w) + bfhi(v3.w);
    }
    for (; p < p1; p++) {
        uint4 v = *reinterpret_cast<const uint4*>(m01 + (size_t)nbr[p] * 128 + c * 4);
        a00 += bflo(v.x); a01 += bfhi(v.x); a02 += bflo(v.y); a03 += bfhi(v.y);
        a10 += bflo(v.z); a11 += bfhi(v.z); a12 += bflo(v.w); a13 += bfhi(v.w);
    }
    float sc = rsqrtf((float)deg[node] + 1.f);
    float4 bb0 = *reinterpret_cast<const float4*>(b0 + c * 4);
    float4 bb1 = *reinterpret_cast<const float4*>(b1 + c * 4);
    uint2 o0, o1;
    o0.x = packbf(sc * a00 + bb0.x, sc * a01 + bb0.y);
    o0.y = packbf(sc * a02 + bb0.z, sc * a03 + bb0.w);
    o1.x = packbf(sc * a10 + bb1.x, sc * a11 + bb1.y);
    o1.y = packbf(sc * a12 + bb1.z, sc * a13 + bb1.w);
    size_t idx = (size_t)node * 64 + c * 2;
    *reinterpret_cast<uint2*>(h0 + idx) = o0;
    *reinterpret_cast<uint2*>(h1 + idx) = o1;
}

// final agg: m01 slot0 = org (out_org), slot1 = meta (out_meta), + pr scale
__global__ void k_agg_hat(const int* __restrict__ ptr, const int* __restrict__ nbr,
                          const uint_t* __restrict__ m01,
                          const float* __restrict__ b_org, const float* __restrict__ b_meta,
                          const int* __restrict__ deg, const float* __restrict__ c_pr,
                          float* __restrict__ out_meta, float* __restrict__ out_org, int n) {
    int c = threadIdx.x & 31, li = threadIdx.x >> 5;
    int node = blockIdx.x * 8 + li;
    if (node >= n) return;
    int p0 = ptr[node], p1 = ptr[node + 1];
    uint4 s = *reinterpret_cast<const uint4*>(m01 + (size_t)node * 128 + c * 4);
    float a00 = bflo(s.x), a01 = bfhi(s.x), a02 = bflo(s.y), a03 = bfhi(s.y);
    float a10 = bflo(s.z), a11 = bfhi(s.z), a12 = bflo(s.w), a13 = bfhi(s.w);
    int p = p0;
    for (; p + 4 <= p1; p += 4) {
        int i0 = nbr[p], i1 = nbr[p + 1], i2 = nbr[p + 2], i3 = nbr[p + 3];
        uint4 v0 = *reinterpret_cast<const uint4*>(m01 + (size_t)i0 * 128 + c * 4);
        uint4 v1 = *reinterpret_cast<const uint4*>(m01 + (size_t)i1 * 128 + c * 4);
        uint4 v2 = *reinterpret_cast<const uint4*>(m01 + (size_t)i2 * 128 + c * 4);
        uint4 v3 = *reinterpret_cast<const uint4*>(m01 + (size_t)i3 * 128 + c * 4);
        a00 += bflo(v0.x) + bflo(v1.x) + bflo(v2.x) + bflo(v3.x);
        a01 += bfhi(v0.x) + bfhi(v1.x) + bfhi(v2.x) + bfhi(v3.x);
        a02 += bflo(v0.y) + bflo(v1.y) + bflo(v2.y) + bflo(v3.y);
        a03 += bfhi(v0.y) + bfhi(v1.y) + bfhi(v2.y) + bfhi(v3.y);
        a10 += bflo(v0.z) + bflo(v1.z) + bflo(v2.z) + bflo(v3.z);
        a11 += bfhi(v0.z) + bfhi(v1.z) + bfhi(v2.z) + bfhi(v3.z);
        a12 += bflo(v0.w) + bflo(v1.w) + bflo(v2.w) + bflo(v3.w);
        a13 += bfhi(v0.w) + bfhi(v1.w) + bfhi(v2.w) + bfhi(v3.w);
    }
    for (; p < p1; p++) {
        uint4 v = *reinterpret_cast<const uint4*>(m01 + (size_t)nbr[p] * 128 + c * 4);
        a00 += bflo(v.x); a01 += bfhi(v.x); a02 += bflo(v.y); a03 += bfhi(v.y);
        a10 += bflo(v.z); a11 += bfhi(v.z); a12 += bflo(v.w); a13 += bfhi(v.w);
    }
    int dg = deg[node];
    float sc = rsqrtf((float)dg + 1.f);
    float pr = c_pr[node] * fmaxf((float)dg, 1.f);
    float4 bo = *reinterpret_cast<const float4*>(b_org + c * 4);
    float4 bm = *reinterpret_cast<const float4*>(b_meta + c * 4);
    size_t o = (size_t)node * 128 + c * 4;
    *reinterpret_cast<float4*>(out_org + o) =
        make_float4((sc * a00 + bo.x) * pr, (sc * a01 + bo.y) * pr,
                    (sc * a02 + bo.z) * pr, (sc * a03 + bo.w) * pr);
    *reinterpret_cast<float4*>(out_meta + o) =
        make_float4((sc * a10 + bm.x) * pr, (sc * a11 + bm.y) * pr,
                    (sc * a12 + bm.z) * pr, (sc * a13 + bm.w) * pr);
}

// ---------------- line-graph path ----------------
// One wave per TWO consecutive edges per iteration (R15: doubles gather
// MLP; R14 showed k_ef is gather-latency bound). u[e] = dinv_e *
// elu(bond[at] * (nf0[s]+nf0[d]) * (mf0f[s]+mf0f[d])); mf0f fp32 from
// k_encoder via g0f.
__global__ __launch_bounds__(256) void k_ef(
    const int* __restrict__ src, const int* __restrict__ dst,
    const int* __restrict__ eattr, const int* __restrict__ x,
    const float* __restrict__ atom_emb, const float* __restrict__ bond_emb,
    const float* __restrict__ mf0f, const int* __restrict__ deg_lg,
    ushort_t* __restrict__ u, int E) {
    __shared__ float bond[8 * 128];
    for (int i = threadIdx.x; i < 8 * 128; i += 256) bond[i] = bond_emb[i];
    __syncthreads();

    int l = threadIdx.x & 63;
    int j0 = l * 2;
    int wv = __builtin_amdgcn_readfirstlane(threadIdx.x >> 6);  // wave id in block (SGPR)
    int estep = gridDim.x * 8;

    for (int e = blockIdx.x * 8 + wv * 2; e < E; e += estep) {
        int eB = e + 1;
        bool hasB = (eB < E);
        int eBs = hasB ? eB : e;
        int sA = src[e], dA = dst[e], atA = eattr[e];
        int sB = src[eBs], dB = dst[eBs], atB = eattr[eBs];
        int xsA = x[sA], xdA = x[dA];
        int xsB = x[sB], xdB = x[dB];
        float2 avA = *reinterpret_cast<const float2*>(atom_emb + (size_t)xsA * 128 + j0);
        float2 bvA = *reinterpret_cast<const float2*>(atom_emb + (size_t)xdA * 128 + j0);
        float2 msA = *reinterpret_cast<const float2*>(mf0f + (size_t)sA * 128 + j0);
        float2 mdA = *reinterpret_cast<const float2*>(mf0f + (size_t)dA * 128 + j0);
        float2 avB = *reinterpret_cast<const float2*>(atom_emb + (size_t)xsB * 128 + j0);
        float2 bvB = *reinterpret_cast<const float2*>(atom_emb + (size_t)xdB * 128 + j0);
        float2 msB = *reinterpret_cast<const float2*>(mf0f + (size_t)sB * 128 + j0);
        float2 mdB = *reinterpret_cast<const float2*>(mf0f + (size_t)dB * 128 + j0);
        float scA = rsqrtf((float)deg_lg[e] + 1.f);
        float scB = rsqrtf((float)deg_lg[eBs] + 1.f);

        float n0A = avA.x + bvA.x, n1A = avA.y + bvA.y;
        float m0A = msA.x + mdA.x, m1A = msA.y + mdA.y;
        float2 boA = *reinterpret_cast<const float2*>(&bond[atA * 128 + j0]);
        float v0A = scA * eluf_fast(boA.x * n0A * m0A);
        float v1A = scA * eluf_fast(boA.y * n1A * m1A);
        *reinterpret_cast<uint_t*>(u + (size_t)e * 128 + j0) = packbf(v0A, v1A);

        if (hasB) {
            float n0B = avB.x + bvB.x, n1B = avB.y + bvB.y;
            float m0B = msB.x + mdB.x, m1B = msB.y + mdB.y;
            float2 boB = *reinterpret_cast<const float2*>(&bond[atB * 128 + j0]);
            float v0B = scB * eluf_fast(boB.x * n0B * m0B);
            float v1B = scB * eluf_fast(boB.y * n1B * m1B);
            *reinterpret_cast<uint_t*>(u + (size_t)eB * 128 + j0) = packbf(v0B, v1B);
        }
    }
}

// v[e] = sc_e*(u[e] + sum u[e']) bf16, chunk [e0,e1) -> vout (row e-e0)
__global__ void k_lg_v(const int* __restrict__ ptr_lg, const int* __restrict__ adj_lg,
                       const int* __restrict__ deg_lg, const uint_t* __restrict__ u32,
                       uint_t* __restrict__ vout, int e0, int e1) {
    int l = threadIdx.x & 63, li = threadIdx.x >> 6;
    int e = e0 + blockIdx.x * 4 + li;
    if (e >= e1) return;
    int p0 = ptr_lg[e], p1 = ptr_lg[e + 1];
    uint_t self = u32[(size_t)e * 64 + l];
    float s0 = bflo(self), s1 = bfhi(self);
    int p = p0;
    for (; p + 4 <= p1; p += 4) {
        int i0 = adj_lg[p], i1 = adj_lg[p + 1], i2 = adj_lg[p + 2], i3 = adj_lg[p + 3];
        uint_t w0 = u32[(size_t)i0 * 64 + l];
        uint_t w1 = u32[(size_t)i1 * 64 + l];
        uint_t w2 = u32[(size_t)i2 * 64 + l];
        uint_t w3 = u32[(size_t)i3 * 64 + l];
        s0 += bflo(w0) + bflo(w1) + bflo(w2) + bflo(w3);
        s1 += bfhi(w0) + bfhi(w1) + bfhi(w2) + bfhi(w3);
    }
    for (; p < p1; p++) {
        uint_t w = u32[(size_t)adj_lg[p] * 64 + l];
        s0 += bflo(w); s1 += bfhi(w);
    }
    float sc = rsqrtf((float)deg_lg[e] + 1.f);
    vout[(size_t)(e - e0) * 64 + l] = packbf(sc * s0, sc * s1);
}

// g0f[n] (+)= sum over incident eids in [e0,e1) of v[eid-e0]; wave-uniform branch
template <int FIRST>
__global__ void k_gate_pass(const int* __restrict__ ptr, const int* __restrict__ eid,
                            const uint_t* __restrict__ v32, float* __restrict__ g0f,
                            int n, int e0, int e1) {
    int l = threadIdx.x & 63, li = threadIdx.x >> 6;
    int node = blockIdx.x * 4 + li;
    if (node >= n) return;
    int p0 = ptr[node], p1 = ptr[node + 1];
    float s0 = 0.f, s1 = 0.f;
    for (int p = p0; p < p1; p++) {
        int e = eid[p];
        if (e >= e0 && e < e1) {
            uint_t w = v32[(size_t)(e - e0) * 64 + l];
            s0 += bflo(w); s1 += bfhi(w);
        }
    }
    float2* out = reinterpret_cast<float2*>(g0f + (size_t)node * 128 + l * 2);
    if (FIRST) {
        *out = make_float2(s0, s1);
    } else {
        float2 c = *out;
        *out = make_float2(c.x + s0, c.y + s1);
    }
}

// ---------------- pagerank: ELL, 4 lanes/node ----------------
__global__ void k_pr_init(const int* __restrict__ deg, float* __restrict__ c,
                          float* __restrict__ invdeg, int n, float invN) {
    int i = blockIdx.x * blockDim.x + threadIdx.x;
    if (i < n) {
        float iv = 1.f / fmaxf((float)deg[i], 1.f);
        invdeg[i] = iv;
        c[i] = invN * iv;
    }
}

__global__ void k_ell_build(const int* __restrict__ ptr, const int* __restrict__ nbr,
                            int* __restrict__ ell, int N) {
    int tid = blockIdx.x * blockDim.x + threadIdx.x;
    int node = tid >> 2, t = tid & 3;
    if (node >= N) return;
    int p0 = ptr[node];
    int dg = ptr[node + 1] - p0;
    if (dg > ELL_CAP) dg = ELL_CAP;
    int stride = N * 4;
    for (int k = 0; 4 * k + t < dg; k++)
        ell[k * stride + tid] = nbr[p0 + 4 * k + t];
}

__global__ void k_pr_ell(const int* __restrict__ ell, const int* __restrict__ ptr,
                         const int* __restrict__ nbr, const float* __restrict__ invdeg,
                         const float* __restrict__ cin, float* __restrict__ cout,
                         int N, float base, float damp) {
    int tid = blockIdx.x * blockDim.x + threadIdx.x;
    int node = tid >> 2, t = tid & 3;
    if (node >= N) return;
    int p0 = ptr[node], p1 = ptr[node + 1];
    int dg = p1 - p0;
    int dgc = dg > ELL_CAP ? ELL_CAP : dg;
    int stride = N * 4;
    float s = 0.f;
    for (int k = 0; 4 * k + t < dgc; k++) s += cin[ell[k * stride + tid]];
    for (int p = p0 + ELL_CAP + t; p < p1; p += 4) s += cin[nbr[p]];
    s += __shfl_xor(s, 1);
    s += __shfl_xor(s, 2);
    if (t == 0) cout[node] = (base + damp * s) * invdeg[node];
}

// ---------------- pooling + heads ----------------
__global__ void k_pool(const float* __restrict__ out_meta, const float* __restrict__ out_org,
                       float* __restrict__ partial, int n) {
    int tid = threadIdx.x;
    const float* basep = (tid < 128) ? out_meta : out_org;
    int dim = tid & 127;
    float acc = 0.f;
    for (int i = blockIdx.x; i < n; i += gridDim.x) acc += basep[(size_t)i * 128 + dim];
    partial[blockIdx.x * 256 + tid] = acc;
}

// R15: 1024 threads, all reduction/GEMV phases split across waves.
__global__ __launch_bounds__(1024) void k_final(
    const float* __restrict__ partial, int nblocks,
    const float* __restrict__ cat2_W, const float* __restrict__ cat2_b,
    const float* __restrict__ pred_W, const float* __restrict__ pred_b,
    float* __restrict__ out) {
    __shared__ float zp[4][256];
    __shared__ float z[256];
    __shared__ float Zp[8][128];
    __shared__ float Z[128];
    __shared__ float Pp[12][16];
    int tid = threadIdx.x;
    {
        int g = tid >> 8, t = tid & 255;
        float acc = 0.f;
        for (int p = g; p < nblocks; p += 4) acc += partial[p * 256 + t];
        zp[g][t] = acc;
    }
    __syncthreads();
    if (tid < 256) z[tid] = zp[0][tid] + zp[1][tid] + zp[2][tid] + zp[3][tid];
    __syncthreads();
    {
        int j = tid & 127, seg = tid >> 7;   // seg 0..7, 32 k's each
        float s = 0.f;
        int k0 = seg * 32;
#pragma unroll 8
        for (int k = k0; k < k0 + 32; k++) s = fmaf(z[k], cat2_W[k * 128 + j], s);
        Zp[seg][j] = s;
    }
    __syncthreads();
    if (tid < 128) {
        float s = cat2_b[tid];
#pragma unroll
        for (int seg = 0; seg < 8; seg++) s += Zp[seg][tid];
        Z[tid] = s;
    }
    __syncthreads();
    if (tid < 192) {
        int j = tid >> 4, part = tid & 15;   // 12 outputs x 16 parts, 8 k's each
        float s = 0.f;
        int k0 = part * 8;
#pragma unroll
        for (int k = k0; k < k0 + 8; k++) s = fmaf(Z[k], pred_W[k * 12 + j], s);
        Pp[j][part] = s;
    }
    __syncthreads();
    if (tid < 12) {
        float s = pred_b[tid];
#pragma unroll
        for (int p = 0; p < 16; p++) s += Pp[tid][p];
        out[tid] = s;
    }
}

// ---------------------------------------------------------------------------
extern "C" void kernel_launch(void* const* d_in, const int* in_sizes, int n_in,
                              void* d_out, int out_size, void* d_ws, size_t ws_size,
                              hipStream_t stream) {
    const int* x            = (const int*)d_in[0];
    const float* metafeat   = (const float*)d_in[1];
    const int* edge_attr    = (const int*)d_in[2];
    const int* edge_index   = (const int*)d_in[3];
    const int* lg_edge_index= (const int*)d_in[4];
    const float* atom_emb   = (const float*)d_in[5];
    const float* bond_emb   = (const float*)d_in[6];
    const float* meta_W     = (const float*)d_in[7];
    const float* meta_b     = (const float*)d_in[8];
    const float* org_W      = (const float*)d_in[9];
    const float* org_b      = (const float*)d_in[10];
    const float* org1_W     = (const float*)d_in[11];
    const float* org1_b     = (const float*)d_in[12];
    const float* mconv_W    = (const float*)d_in[13];
    const float* mconv_b    = (const float*)d_in[14];
    const float* mconv1_W   = (const float*)d_in[15];
    const float* mconv1_b   = (const float*)d_in[16];
    const float* lg_W       = (const float*)d_in[17];
    const float* lg_b       = (const float*)d_in[18];
    const float* cat2_W     = (const float*)d_in[21];
    const float* cat2_b     = (const float*)d_in[22];
    const float* pred_W     = (const float*)d_in[23];
    const float* pred_b     = (const float*)d_in[24];

    const int N = in_sizes[0];
    const int E = in_sizes[2];
    const int ELG = in_sizes[4] / 2;
    const int* src = edge_index;
    const int* dst = edge_index + E;
    const int* ls = lg_edge_index;
    const int* ld = lg_edge_index + ELG;

    // ---- workspace carve (~194 MB, proven footprint) ----
    char* w = (char*)d_ws;
    auto alloc = [&](size_t bytes) -> void* {
        void* p = (void*)w;
        w += (bytes + 255) & ~(size_t)255;
        return p;
    };
    int* deg_n   = (int*)alloc((size_t)N * 4);
    int* ptr_n   = (int*)alloc((size_t)(N + 1) * 4);
    int* cur_n   = (int*)alloc((size_t)N * 4);
    int* adj_nbr = (int*)alloc((size_t)2 * E * 4);
    int* adj_eid = (int*)alloc((size_t)2 * E * 4);
    int* deg_lg  = (int*)alloc((size_t)E * 4);
    int* ptr_lg  = (int*)alloc((size_t)(E + 1) * 4);
    int* cur_lg  = (int*)alloc((size_t)E * 4);
    int* adj_lg  = (int*)alloc((size_t)2 * ELG * 4);
    int* bsum    = (int*)alloc((size_t)SCAN_NB * 4);
    float* c_a   = (float*)alloc((size_t)N * 4);
    float* c_b   = (float*)alloc((size_t)N * 4);
    float* invdg = (float*)alloc((size_t)N * 4);
    float* partial = (float*)alloc((size_t)POOL_BLOCKS * 256 * 4);
    uint_t* gateA = (uint_t*)alloc((size_t)N * 64 * 4);   // bf16: gate_n then gate_l
    float* g0f   = (float*)alloc((size_t)N * 128 * 4);    // fp32: mf0f copy, then gate acc
    uint_t* h_orgb  = (uint_t*)alloc((size_t)N * 64 * 4); // bf16
    uint_t* h_metab = (uint_t*)alloc((size_t)N * 64 * 4); // bf16
    size_t nodeB = (size_t)N * 64;                         // uints per bf16 node array
    size_t u_bytes = (size_t)E * 64 * 4;                   // E x 128 bf16
    size_t reg_bytes = 4 * nodeB * 4;
    uint_t* reg = (uint_t*)alloc(reg_bytes > u_bytes ? reg_bytes : u_bytes);
    uint_t* nf0b = reg;
    uint_t* mf0b = reg + nodeB;
    uint_t* m01  = reg + 2 * nodeB;  // interleaved m0/m1, pitch 128 uints/node
    ushort_t* u  = (ushort_t*)reg;   // overlays nf0b..m01 (all dead by then)
    int* ell     = (int*)reg;        // overlays nf0b quarter after u dies
    (void)n_in; (void)ws_size;

    float* out_pred = (float*)d_out;
    float* out_meta = out_pred + 12;
    float* out_org  = out_pred + 12 + (size_t)N * 128;
    // d_out doubles as the v-chunk scratch during the lg path (dead until agg_hat)
    uint_t* vhalf = (uint_t*)d_out;   // capacity: out_size*4 >= (E/2)*256 bytes
    (void)out_size;

    // ---- binned-fill scratch: overlays reg (dead until encoders) ----
    const int SH_N = 8, SH_LG = 10;
    const int NC_N = 128, CAP_N = 80;     // mean pairs/cell ~32, cap ~8.5 sigma
    const int NC_LG = 256, CAP_LG = 80;   // mean pairs/cell ~32, cap ~8.5 sigma
    int B_N  = (N + (1 << SH_N) - 1) >> SH_N;
    int B_LG = (E + (1 << SH_LG) - 1) >> SH_LG;
    bool binOK = (N <= 65535) && (B_N <= 512) && (B_LG <= 512);
    char* rw = (char*)reg;
    auto ralloc = [&](size_t bytes) -> void* {
        void* p = (void*)rw;
        rw += (bytes + 255) & ~(size_t)255;
        return p;
    };
    uint2* seg_lg = (uint2*)ralloc((size_t)NC_LG * B_LG * CAP_LG * 8);
    int*  cnt_lg  = (int*)ralloc((size_t)NC_LG * B_LG * 4);
    uint2* seg_n  = (uint2*)ralloc((size_t)NC_N * B_N * CAP_N * 8);
    int*  cnt_n   = (int*)ralloc((size_t)NC_N * B_N * 4);
    uint2* ovf_lg = (uint2*)ralloc((size_t)OVF_CAP * 8);
    uint2* ovf_n  = (uint2*)ralloc((size_t)OVF_CAP * 8);
    int* ovf_curs = (int*)ralloc(256);

    // ---- CSR build ----
    if (binOK) {
        hipMemsetAsync(ovf_curs, 0, 8, stream);
        // node graph: bin -> binned count -> scan -> place
        k_bin<1><<<NC_N, 256, 0, stream>>>(src, dst, E, seg_n, cnt_n, ovf_n,
                                           ovf_curs + 0, NC_N, B_N, SH_N, CAP_N);
        k_bcount<1><<<B_N, 256, 0, stream>>>(seg_n, cnt_n, deg_n, NC_N, B_N, SH_N, CAP_N, N);
        k_ovf_count<1><<<4, 256, 0, stream>>>(ovf_n, ovf_curs + 0, deg_n);
        {
            int C = (N + SCAN_NB - 1) / SCAN_NB;
            k_scan1<<<SCAN_NB, 256, 0, stream>>>(deg_n, N, C, bsum);
            k_scan2<<<1, 256, 0, stream>>>(bsum, SCAN_NB, ptr_n + N);
            k_scan3<<<SCAN_NB, 256, 0, stream>>>(deg_n, bsum, N, C, ptr_n, cur_n);
        }
        k_place<1><<<B_N, 256, 0, stream>>>(seg_n, cnt_n, ptr_n, adj_nbr, adj_eid,
                                            cur_n, NC_N, B_N, SH_N, CAP_N, N);
        k_ovf_fix<1><<<16, 256, 0, stream>>>(ovf_n, ovf_curs + 0, cur_n, adj_nbr, adj_eid);
        // lg graph
        k_bin<0><<<NC_LG, 256, 0, stream>>>(ls, ld, ELG, seg_lg, cnt_lg, ovf_lg,
                                            ovf_curs + 1, NC_LG, B_LG, SH_LG, CAP_LG);
        k_bcount<0><<<B_LG, 256, 0, stream>>>(seg_lg, cnt_lg, deg_lg, NC_LG, B_LG,
                                              SH_LG, CAP_LG, E);
        k_ovf_count<0><<<4, 256, 0, stream>>>(ovf_lg, ovf_curs + 1, deg_lg);
        {
            int C = (E + SCAN_NB - 1) / SCAN_NB;
            k_scan1<<<SCAN_NB, 256, 0, stream>>>(deg_lg, E, C, bsum);
            k_scan2<<<1, 256, 0, stream>>>(bsum, SCAN_NB, ptr_lg + E);
            k_scan3<<<SCAN_NB, 256, 0, stream>>>(deg_lg, bsum, E, C, ptr_lg, cur_lg);
        }
        k_place<0><<<B_LG, 256, 0, stream>>>(seg_lg, cnt_lg, ptr_lg, adj_lg, nullptr,
                                             cur_lg, NC_LG, B_LG, SH_LG, CAP_LG, E);
        k_ovf_fix<0><<<16, 256, 0, stream>>>(ovf_lg, ovf_curs + 1, cur_lg, adj_lg, nullptr);
    } else {
        hipMemsetAsync(deg_n, 0, (size_t)N * 4, stream);
        hipMemsetAsync(deg_lg, 0, (size_t)E * 4, stream);
        k_count<<<(E + 255) / 256, 256, 0, stream>>>(src, dst, E, deg_n);
        {
            int C = (N + SCAN_NB - 1) / SCAN_NB;
            k_scan1<<<SCAN_NB, 256, 0, stream>>>(deg_n, N, C, bsum);
            k_scan2<<<1, 256, 0, stream>>>(bsum, SCAN_NB, ptr_n + N);
            k_scan3<<<SCAN_NB, 256, 0, stream>>>(deg_n, bsum, N, C, ptr_n, cur_n);
        }
        int rngN = (N + FILL_NR - 1) / FILL_NR;
        k_fill_part<1><<<FILL_NR * 96, 256, 0, stream>>>(src, dst, E, cur_n,
                                                         adj_nbr, adj_eid, rngN, 96);
        k_count<<<(ELG + 255) / 256, 256, 0, stream>>>(ls, ld, ELG, deg_lg);
        {
            int C = (E + SCAN_NB - 1) / SCAN_NB;
            k_scan1<<<SCAN_NB, 256, 0, stream>>>(deg_lg, E, C, bsum);
            k_scan2<<<1, 256, 0, stream>>>(bsum, SCAN_NB, ptr_lg + E);
            k_scan3<<<SCAN_NB, 256, 0, stream>>>(deg_lg, bsum, E, C, ptr_lg, cur_lg);
        }
        int rngE = (E + FILL_NR - 1) / FILL_NR;
        k_fill_part<0><<<FILL_NR * 192, 256, 0, stream>>>(ls, ld, ELG, cur_lg,
                                                          adj_lg, nullptr, rngE, 192);
    }

    // ---- encoders + gate_n (bf16; mf0 also in fp32 -> g0f for k_ef) ----
    k_encoder<<<(N * 64 + 255) / 256, 256, 0, stream>>>(x, metafeat, atom_emb, meta_W, meta_b,
                                                        nf0b, mf0b, g0f, N);
    k_gate_node<<<(N + 3) / 4, 256, 0, stream>>>(ptr_n, adj_eid, edge_attr, bond_emb, gateA, N);

    const int gb64 = (N + 63) / 64;

    // ---- GCN layer 1 (bf16 in, interleaved bf16 out; org+meta batched) ----
    k_gemm64<1, 0, 1, 1, 1, 1><<<2 * gb64, 256, 0, stream>>>(
        nf0b, gateA, org_W, nullptr, deg_n, m01 + 0,
        mf0b, mconv_W, m01 + 2, gb64, N);
    k_agg_dual<<<(N + 7) / 8, 256, 0, stream>>>(ptr_n, adj_nbr, m01, org_b, mconv_b,
                                                deg_n, h_orgb, h_metab, N);
    // reg region becomes u (bf16)

    // ---- line-graph path: u -> v (2 chunks via d_out scratch) -> g0f fp32 ----
    k_ef<<<EF_BLOCKS, 256, 0, stream>>>(src, dst, edge_attr, x, atom_emb, bond_emb,
                                        g0f, deg_lg, u, E);
    {
        int eh = (E + 1) / 2;
        k_lg_v<<<(eh + 3) / 4, 256, 0, stream>>>(ptr_lg, adj_lg, deg_lg, (const uint_t*)u,
                                                 vhalf, 0, eh);
        k_gate_pass<1><<<(N + 3) / 4, 256, 0, stream>>>(ptr_n, adj_eid, vhalf, g0f, N, 0, eh);
        k_lg_v<<<(E - eh + 3) / 4, 256, 0, stream>>>(ptr_lg, adj_lg, deg_lg, (const uint_t*)u,
                                                     vhalf, eh, E);
        k_gate_pass<0><<<(N + 3) / 4, 256, 0, stream>>>(ptr_n, adj_eid, vhalf, g0f, N, eh, E);
    }
    k_gemm64<0, 1, 0, 1, 0, 0><<<gb64, 256, 0, stream>>>(
        g0f, nullptr, lg_W, lg_b, deg_n, gateA,
        nullptr, nullptr, nullptr, 0, N);   // gate_l bf16

    // ---- GCN layer 2 (gated, bf16 in, interleaved out; org+meta batched) ----
    k_gemm64<1, 0, 1, 1, 1, 1><<<2 * gb64, 256, 0, stream>>>(
        h_orgb, gateA, org1_W, nullptr, deg_n, m01 + 0,
        h_metab, mconv1_W, m01 + 2, gb64, N);
    // u dead; nf0b quarter free -> ELL

    // ---- pagerank: ELL build + PR_ITERS graph-captured launches ----
    float invN = (float)(1.0 / (double)N);
    float base = (float)((1.0 - 0.85) / (double)N);
    k_pr_init<<<(N + 255) / 256, 256, 0, stream>>>(deg_n, c_a, invdg, N, invN);
    int prb = (4 * N + 255) / 256;
    k_ell_build<<<prb, 256, 0, stream>>>(ptr_n, adj_nbr, ell, N);
    float* pin = c_a;
    float* pout = c_b;
    for (int it = 0; it < PR_ITERS; ++it) {
        k_pr_ell<<<prb, 256, 0, stream>>>(ell, ptr_n, adj_nbr, invdg, pin, pout, N,
                                          base, 0.85f);
        float* t = pin; pin = pout; pout = t;
    }

    // ---- final agg + pagerank scale -> d_out (vhalf scratch now dead) ----
    k_agg_hat<<<(N + 7) / 8, 256, 0, stream>>>(ptr_n, adj_nbr, m01, org1_b, mconv1_b,
                                               deg_n, pin, out_meta, out_org, N);
    k_pool<<<POOL_BLOCKS, 256, 0, stream>>>(out_meta, out_org, partial, N);
    k_final<<<1, 1024, 0, stream>>>(partial, POOL_BLOCKS, cat2_W, cat2_b, pred_W, pred_b, out_pred);
}